// Round 16
// baseline (373.298 us; speedup 1.0000x reference)
//
#include <hip/hip_runtime.h>
#include <hip/hip_fp16.h>
#include <math.h>

namespace {

constexpr int NN = 4096;
constexpr int EE = 131072;
constexpr int E2 = EE + NN;      // 135168 pool edges (orig + self loops)
constexpr int HH = 128;
constexpr int KC = 3277;         // ceil(0.8*4096)
constexpr int UP = 3584;         // U row stride (8*448)
constexpr int A2P = 3328;        // A2 row/col padded dim

typedef _Float16 f16x8 __attribute__((ext_vector_type(8)));
typedef _Float16 f16x4 __attribute__((ext_vector_type(4)));
typedef float f32x4 __attribute__((ext_vector_type(4)));

constexpr int A2B_RT = (KC + 3) / 4;   // 820 row-groups (4 waves x 1 row)
constexpr int KQ = A2P / 4;             // 832 K-quarter for k_mm

__device__ __forceinline__ float lrelu02(float x){ return x > 0.f ? x : 0.2f * x; }

__device__ __forceinline__ float redSum128(float* red, int t, float v){
  red[t] = v; __syncthreads();
  #pragma unroll
  for (int s = 64; s > 0; s >>= 1){ if (t < s) red[t] += red[t + s]; __syncthreads(); }
  float r = red[0]; __syncthreads();
  return r;
}
__device__ __forceinline__ float redMax128(float* red, int t, float v){
  red[t] = v; __syncthreads();
  #pragma unroll
  for (int s = 64; s > 0; s >>= 1){ if (t < s) red[t] = fmaxf(red[t], red[t + s]); __syncthreads(); }
  float r = red[0]; __syncthreads();
  return r;
}

__global__ void k_zero_init(int* cntD, int* cntS, int* deg, float* out){
  int i = blockIdx.x * blockDim.x + threadIdx.x;
  if (i < NN){ cntD[i] = 0; cntS[i] = 0; }
  if (i < KC) deg[i] = 0;
  if (i < 512) out[i] = 0.f;
}

__global__ void k_count(const int* __restrict__ ei, int* cntD, int* cntS){
  int e = blockIdx.x * blockDim.x + threadIdx.x;
  if (e >= E2) return;
  int u, v;
  if (e < EE){ u = ei[e]; v = ei[EE + e]; } else { u = e - EE; v = u; }
  atomicAdd(&cntD[v], 1);
  atomicAdd(&cntS[u], 1);
}

__global__ void k_scan(const int* cntD, const int* cntS, int* rowD, int* rowS, int* curD, int* curS){
  __shared__ int sc[1024];
  int t = threadIdx.x;
  for (int pass = 0; pass < 2; ++pass){
    const int* cnt = pass ? cntS : cntD;
    int* row = pass ? rowS : rowD;
    int* cur = pass ? curS : curD;
    int c0 = cnt[t*4+0], c1 = cnt[t*4+1], c2 = cnt[t*4+2], c3 = cnt[t*4+3];
    int tot = c0 + c1 + c2 + c3;
    sc[t] = tot; __syncthreads();
    for (int offs = 1; offs < 1024; offs <<= 1){
      int v = (t >= offs) ? sc[t - offs] : 0;
      __syncthreads();
      sc[t] += v;
      __syncthreads();
    }
    int excl = sc[t] - tot;
    int r0 = excl, r1 = r0 + c0, r2 = r1 + c1, r3 = r2 + c2;
    row[t*4+0] = r0; row[t*4+1] = r1; row[t*4+2] = r2; row[t*4+3] = r3;
    cur[t*4+0] = r0; cur[t*4+1] = r1; cur[t*4+2] = r2; cur[t*4+3] = r3;
    if (t == 1023) row[NN] = r3 + c3;
    __syncthreads();
  }
}

// scatter; also emits dst-ordered U byte-offsets (colD known here)
__global__ void k_scatter(const int* __restrict__ ei, int* curD, int* curS,
                          int* colD, int* dstS, int* mapSD, unsigned* offsD){
  int e = blockIdx.x * blockDim.x + threadIdx.x;
  if (e >= E2) return;
  int u, v;
  if (e < EE){ u = ei[e]; v = ei[EE + e]; } else { u = e - EE; v = u; }
  int p = atomicAdd(&curD[v], 1); colD[p] = u; offsD[p] = (unsigned)u * (UP*2);
  int q = atomicAdd(&curS[u], 1); dstS[q] = v; mapSD[q] = p;
}

// prep: xh = f16(x); WH = f16 weights [W0rel|W0root|W1rel|W1root]; wprep (last block).
__global__ void k_prep(const float* __restrict__ x,
                       const float* __restrict__ W0rel, const float* __restrict__ W0root,
                       const float* __restrict__ W1rel, const float* __restrict__ W1root,
                       const float* __restrict__ Wlin, const float* __restrict__ blin,
                       const float* __restrict__ Watt,
                       __half* __restrict__ xh, __half* __restrict__ WH, float* __restrict__ wA2){
  int b = blockIdx.x;
  if (b < 2048){
    int i = b*256 + threadIdx.x;
    xh[i] = __float2half(x[i]);
  } else if (b < 2048 + 256){
    int i = (b - 2048)*256 + threadIdx.x;
    int m = i >> 14, o = i & 16383;
    const float* src = (m == 0) ? W0rel : (m == 1) ? W0root : (m == 2) ? W1rel : W1root;
    WH[i] = __float2half(src[o]);
  } else {
    int c = threadIdx.x;
    if (c < 128){
      float s = 0.f;
      for (int hh = 0; hh < HH; ++hh) s += Watt[hh] * Wlin[hh*HH + c];
      wA2[c] = s;
      if (c == 0){
        float q = 0.f;
        for (int hh = 0; hh < HH; ++hh) q += blin[hh] * Watt[hh];
        wA2[HH] = q;
      }
    }
  }
}

// mean over in-neighbors, f16 input rows, f16 output (f32 accumulate).
__global__ void k_edge_meanH(const __half* __restrict__ xinh, const int* __restrict__ rowD,
                             const int* __restrict__ colD, __half* __restrict__ meanbh){
  int v = blockIdx.x, t = threadIdx.x;
  int beg = rowD[v], end = rowD[v+1];
  float acc = 0.f;
  int p = beg;
  for (; p + 8 <= end; p += 8){
    int u0 = colD[p],   u1 = colD[p+1], u2 = colD[p+2], u3 = colD[p+3];
    int u4 = colD[p+4], u5 = colD[p+5], u6 = colD[p+6], u7 = colD[p+7];
    float a0 = __half2float(xinh[(size_t)u0*HH + t]);
    float a1 = __half2float(xinh[(size_t)u1*HH + t]);
    float a2 = __half2float(xinh[(size_t)u2*HH + t]);
    float a3 = __half2float(xinh[(size_t)u3*HH + t]);
    float a4 = __half2float(xinh[(size_t)u4*HH + t]);
    float a5 = __half2float(xinh[(size_t)u5*HH + t]);
    float a6 = __half2float(xinh[(size_t)u6*HH + t]);
    float a7 = __half2float(xinh[(size_t)u7*HH + t]);
    if (u0 != v) acc += a0;
    if (u1 != v) acc += a1;
    if (u2 != v) acc += a2;
    if (u3 != v) acc += a3;
    if (u4 != v) acc += a4;
    if (u5 != v) acc += a5;
    if (u6 != v) acc += a6;
    if (u7 != v) acc += a7;
  }
  for (; p < end; ++p){ int u = colD[p]; if (u != v) acc += __half2float(xinh[(size_t)u*HH + t]); }
  float dg = (float)(end - beg - 1);
  meanbh[(size_t)v*HH + t] = __float2half(acc / fmaxf(dg, 1.f));
}

// MFMA GraphConv linear: xout = relu([meanbh|xinh] @ [Wrel|Wroot]^T + brel).
// Fused colmean; optional fused xdot (= sum_h out*Watt[HH+h], for ASAP attention).
__global__ void k_linM(const __half* __restrict__ mh, const __half* __restrict__ xinh,
                       const __half* __restrict__ WHh, int woff,
                       const float* __restrict__ brel,
                       float* __restrict__ xout, __half* __restrict__ xouth,
                       float* __restrict__ cmout,
                       const float* __restrict__ WattFull, float* __restrict__ xdotp){
  __shared__ float sx[16][4];
  int t = threadIdx.x, lane = t & 63, w = t >> 6;
  int r0 = blockIdx.x * 16;
  int l15 = lane & 15, lk = (lane >> 4) * 8;
  const _Float16* WH = (const _Float16*)WHh;
  const _Float16* Am = (const _Float16*)mh + (size_t)(r0 + l15)*HH + lk;
  const _Float16* Ax = (const _Float16*)xinh + (size_t)(r0 + l15)*HH + lk;
  const _Float16* Brel0 = WH + woff + (size_t)(w*32 + l15)*HH + lk;
  const _Float16* Brel1 = Brel0 + (size_t)16*HH;
  const _Float16* Broot0 = Brel0 + 16384;
  const _Float16* Broot1 = Brel1 + 16384;
  f32x4 acc0 = (f32x4)0.f, acc1 = (f32x4)0.f;
  #pragma unroll
  for (int kk = 0; kk < HH; kk += 32){
    f16x8 a = *(const f16x8*)(Am + kk);
    f16x8 b0 = *(const f16x8*)(Brel0 + kk);
    f16x8 b1 = *(const f16x8*)(Brel1 + kk);
    acc0 = __builtin_amdgcn_mfma_f32_16x16x32_f16(a, b0, acc0, 0, 0, 0);
    acc1 = __builtin_amdgcn_mfma_f32_16x16x32_f16(a, b1, acc1, 0, 0, 0);
  }
  #pragma unroll
  for (int kk = 0; kk < HH; kk += 32){
    f16x8 a = *(const f16x8*)(Ax + kk);
    f16x8 b0 = *(const f16x8*)(Broot0 + kk);
    f16x8 b1 = *(const f16x8*)(Broot1 + kk);
    acc0 = __builtin_amdgcn_mfma_f32_16x16x32_f16(a, b0, acc0, 0, 0, 0);
    acc1 = __builtin_amdgcn_mfma_f32_16x16x32_f16(a, b1, acc1, 0, 0, 0);
  }
  int rbase = (lane >> 4) * 4;
  int h0 = w*32 + l15, h1 = h0 + 16;
  float bb0 = brel[h0], bb1 = brel[h1];
  float wt0 = 0.f, wt1 = 0.f;
  if (xdotp){ wt0 = WattFull[HH + h0]; wt1 = WattFull[HH + h1]; }
  float cs0 = 0.f, cs1 = 0.f;
  #pragma unroll
  for (int r = 0; r < 4; ++r){
    int row = r0 + rbase + r;
    float v0 = fmaxf(acc0[r] + bb0, 0.f);
    float v1 = fmaxf(acc1[r] + bb1, 0.f);
    xout[(size_t)row*HH + h0] = v0;
    xout[(size_t)row*HH + h1] = v1;
    xouth[(size_t)row*HH + h0] = __float2half(v0);
    xouth[(size_t)row*HH + h1] = __float2half(v1);
    cs0 += v0; cs1 += v1;
    if (xdotp){
      float ds = v0*wt0 + v1*wt1;
      ds += __shfl_xor(ds, 1); ds += __shfl_xor(ds, 2);
      ds += __shfl_xor(ds, 4); ds += __shfl_xor(ds, 8);
      if (l15 == 0) sx[rbase + r][w] = ds;
    }
  }
  cs0 += __shfl_xor(cs0, 16); cs0 += __shfl_xor(cs0, 32);
  cs1 += __shfl_xor(cs1, 16); cs1 += __shfl_xor(cs1, 32);
  if (lane < 16){
    atomicAdd(&cmout[h0], cs0 / (float)NN);
    atomicAdd(&cmout[h1], cs1 / (float)NN);
  }
  if (xdotp){
    __syncthreads();
    if (t < 16) xdotp[r0 + t] = sx[t][0] + sx[t][1] + sx[t][2] + sx[t][3];
  }
}

// dense-conv linear: mean from 4 f16 K-quarter partials / deg; optional xout; fused colmean.
__global__ void k_lin2(const __half* __restrict__ part, const int* __restrict__ deg,
                       const float* __restrict__ xin,
                       const float* __restrict__ Wrel, const float* __restrict__ brel,
                       const float* __restrict__ Wroot, float* __restrict__ xout, int rows,
                       float* __restrict__ cmout){
  __shared__ float ms[16][HH];
  __shared__ float xs[16][HH];
  __shared__ float cmred[256];
  const __half* p0 = part;
  const __half* p1 = part + (size_t)KC*HH;
  const __half* p2 = part + (size_t)2*KC*HH;
  const __half* p3 = part + (size_t)3*KC*HH;
  int tid = threadIdx.x;
  int r0 = blockIdx.x * 16;
  for (int l = tid; l < 16*HH; l += 256){
    int r = l >> 7, c = l & 127; int gr = r0 + r;
    float mv = 0.f, xv = 0.f;
    if (gr < rows){
      size_t idx = (size_t)gr*HH + c;
      float d = fmaxf((float)deg[gr], 1.f);
      mv = ((__half2float(p0[idx]) + __half2float(p1[idx]))
          + (__half2float(p2[idx]) + __half2float(p3[idx]))) / d;
      xv = xin[idx];
    }
    ms[r][c] = mv; xs[r][c] = xv;
  }
  __syncthreads();
  int h = tid & 127, hgrp = tid >> 7;
  float acc[8] = {0.f,0.f,0.f,0.f,0.f,0.f,0.f,0.f};
  for (int c = 0; c < HH; ++c){
    float wr = Wrel[h*HH + c], wo = Wroot[h*HH + c];
    #pragma unroll
    for (int r = 0; r < 8; ++r) acc[r] += ms[hgrp*8 + r][c]*wr + xs[hgrp*8 + r][c]*wo;
  }
  float bb = brel[h];
  float csum = 0.f;
  #pragma unroll
  for (int r = 0; r < 8; ++r){
    int gr = r0 + hgrp*8 + r;
    if (gr < rows){
      float val = fmaxf(acc[r] + bb, 0.f);
      if (xout) xout[(size_t)gr*HH + h] = val;
      csum += val;
    }
  }
  cmred[tid] = csum; __syncthreads();
  if (tid < 128) atomicAdd(&cmout[h], (cmred[tid] + cmred[tid + 128]) / (float)rows);
}

// per dst node v (f16 gathers, f32 accumulate): xq max -> qdot; edge-softmax stats;
// x_new; wD (+f16 copy wHD); fused LEConv partials.
__global__ void k_pool(const __half* __restrict__ x2h, const int* __restrict__ rowD, const int* __restrict__ colD,
                       const float* __restrict__ xdotA, const float* __restrict__ wA2, const float* __restrict__ battp,
                       const float* __restrict__ W1, const float* __restrict__ b1,
                       const float* __restrict__ W2, const float* __restrict__ W3, const float* __restrict__ b3,
                       float* qdotA, float* mA, float* sA, float* __restrict__ xnew, float* __restrict__ wD,
                       __half* __restrict__ wHD,
                       float* aA, float* bA, float* cA){
  __shared__ float red[128];
  __shared__ float wmem[128];
  __shared__ int uc[128];
  int v = blockIdx.x, t = threadIdx.x;
  int beg = rowD[v], end = rowD[v+1];
  float batt = battp[0];
  float mx = -3.402823466e38f;
  int p = beg;
  for (; p + 4 <= end; p += 4){
    float a0 = __half2float(x2h[(size_t)colD[p]*HH + t]);
    float a1 = __half2float(x2h[(size_t)colD[p+1]*HH + t]);
    float a2 = __half2float(x2h[(size_t)colD[p+2]*HH + t]);
    float a3 = __half2float(x2h[(size_t)colD[p+3]*HH + t]);
    mx = fmaxf(fmaxf(fmaxf(fmaxf(mx, a0), a1), a2), a3);
  }
  for (; p < end; ++p) mx = fmaxf(mx, __half2float(x2h[(size_t)colD[p]*HH + t]));
  float qd = redSum128(red, t, mx * wA2[t]) + wA2[HH];
  float lm = -3.402823466e38f;
  for (p = beg + t; p < end; p += 128) lm = fmaxf(lm, lrelu02(qd + xdotA[colD[p]] + batt));
  float mm = redMax128(red, t, lm);
  float ls = 0.f;
  for (p = beg + t; p < end; p += 128) ls += expf(lrelu02(qd + xdotA[colD[p]] + batt) - mm);
  float ss = redSum128(red, t, ls);
  float acc = 0.f;
  for (int basep = beg; basep < end; basep += 128){
    int cnt = min(128, end - basep);
    if (t < cnt){
      int u = colD[basep + t];
      uc[t] = u;
      float w = expf(lrelu02(qd + xdotA[u] + batt) - mm) / ss;
      wmem[t] = w;
      wD[basep + t] = w;
      wHD[basep + t] = __float2half(w);
    }
    __syncthreads();
    int i = 0;
    for (; i + 4 <= cnt; i += 4){
      float a0 = __half2float(x2h[(size_t)uc[i]*HH + t]);
      float a1 = __half2float(x2h[(size_t)uc[i+1]*HH + t]);
      float a2 = __half2float(x2h[(size_t)uc[i+2]*HH + t]);
      float a3 = __half2float(x2h[(size_t)uc[i+3]*HH + t]);
      acc += wmem[i]*a0 + wmem[i+1]*a1 + wmem[i+2]*a2 + wmem[i+3]*a3;
    }
    for (; i < cnt; ++i) acc += wmem[i] * __half2float(x2h[(size_t)uc[i]*HH + t]);
    __syncthreads();
  }
  xnew[(size_t)v*HH + t] = acc;
  float s1 = redSum128(red, t, acc * W1[t]);
  float s2 = redSum128(red, t, acc * W2[t]);
  float s3 = redSum128(red, t, acc * W3[t]);
  if (t == 0){
    qdotA[v] = qd; mA[v] = mm; sA[v] = ss;
    aA[v] = s1 + b1[0]; bA[v] = s2; cA[v] = s3 + b3[0];
  }
}

__global__ void k_fit(const int* __restrict__ rowD, const int* __restrict__ colD,
                      const float* __restrict__ aA, const float* __restrict__ bA, const float* __restrict__ cA,
                      float* __restrict__ fitA){
  __shared__ float red[128];
  int v = blockIdx.x, t = threadIdx.x;
  int beg = rowD[v], end = rowD[v+1];
  float la = 0.f;
  for (int p = beg + t; p < end; p += 128) la += aA[colD[p]];
  float s = redSum128(red, t, la);
  if (t == 0){
    float g = s - (float)(end - beg) * bA[v] + cA[v];
    fitA[v] = 1.f / (1.f + expf(-g));
  }
}

// Exact top-K SET selection via radix-select (1 block, 1024 threads).
__global__ void k_sel(const float* __restrict__ fitA, int* perm, float* fitk, int* kcol){
  __shared__ unsigned keys[NN];
  __shared__ int hist[256];
  __shared__ int sc[1024];
  __shared__ int bc[2];
  int t = threadIdx.x;
  #pragma unroll
  for (int r = 0; r < 4; ++r){
    int i = t + r*1024;
    unsigned b = __float_as_uint(fitA[i]);
    keys[i] = (b & 0x80000000u) ? ~b : (b ^ 0x80000000u);
  }
  __syncthreads();
  unsigned prefix = 0;
  int kneed = KC;
  #pragma unroll
  for (int round = 0; round < 4; ++round){
    int shift = 24 - round*8;
    unsigned pmask = (round == 0) ? 0u : (0xFFFFFFFFu << (shift + 8));
    if (t < 256) hist[t] = 0;
    __syncthreads();
    #pragma unroll
    for (int r = 0; r < 4; ++r){
      unsigned kv = keys[t + r*1024];
      if ((kv & pmask) == prefix)
        atomicAdd(&hist[(kv >> shift) & 0xFF], 1);
    }
    __syncthreads();
    if (t == 0){
      int acc = 0, chosen = 0, rem = kneed;
      for (int bkt = 255; bkt >= 0; --bkt){
        int c = hist[bkt];
        if (acc + c >= kneed){ chosen = bkt; rem = kneed - acc; break; }
        acc += c;
      }
      bc[0] = chosen; bc[1] = rem;
    }
    __syncthreads();
    prefix |= ((unsigned)bc[0]) << shift;
    kneed = bc[1];
    __syncthreads();
  }
  unsigned T = prefix;
  int need_eq = kneed;
  int cnt[4]; int tot = 0;
  #pragma unroll
  for (int r = 0; r < 4; ++r){
    unsigned kv = keys[t*4 + r];
    int g = (kv > T) ? 1 : 0;
    int e = (kv == T) ? 1 : 0;
    cnt[r] = (g << 16) | e;
    tot += cnt[r];
  }
  sc[t] = tot; __syncthreads();
  for (int offs = 1; offs < 1024; offs <<= 1){
    int v = (t >= offs) ? sc[t - offs] : 0;
    __syncthreads();
    sc[t] += v;
    __syncthreads();
  }
  int gtot = sc[1023] >> 16;
  int run = sc[t] - tot;
  #pragma unroll
  for (int r = 0; r < 4; ++r){
    int i = t*4 + r;
    int g = cnt[r] >> 16, e = cnt[r] & 0xFFFF;
    int gpos = run >> 16, epos = run & 0xFFFF;
    int pos = -1;
    if (g) pos = gpos;
    else if (e && epos < need_eq) pos = gtot + epos;
    if (pos >= 0){ perm[pos] = i; fitk[pos] = fitA[i]; kcol[i] = pos; }
    else kcol[i] = -1;
    run += cnt[r];
  }
}

// fused: xp[j,:] = xnew[perm[j],:]*fitk[j]  AND  Xt[h][j] = f16(xp[j][h])
__global__ void k_xpt(const float* __restrict__ xnew, const int* __restrict__ perm,
                      const float* __restrict__ fitk, float* __restrict__ xp,
                      __half* __restrict__ Xt){
  __shared__ float T2[64][129];
  int t = threadIdx.x;
  int j0 = blockIdx.x * 64;
  for (int l = t; l < 64*32; l += 256){
    int jl = l >> 5, hg = (l & 31) * 4;
    int j = j0 + jl;
    float4 v = make_float4(0.f, 0.f, 0.f, 0.f);
    if (j < KC){
      float f = fitk[j];
      const float* src = xnew + (size_t)perm[j]*HH + hg;
      v.x = src[0]*f; v.y = src[1]*f; v.z = src[2]*f; v.w = src[3]*f;
      *(float4*)(xp + (size_t)j*HH + hg) = v;
    }
    T2[jl][hg] = v.x; T2[jl][hg+1] = v.y; T2[jl][hg+2] = v.z; T2[jl][hg+3] = v.w;
  }
  __syncthreads();
  for (int idx = t; idx < 128*64; idx += 256){
    int h = idx >> 6, jl = idx & 63;
    Xt[(size_t)h*A2P + j0 + jl] = __float2half(T2[jl][h]);
  }
}

// src-ordered packed (kcol, w) for k_U
__global__ void k_wS(const int* __restrict__ mapSD, const int* __restrict__ dstS,
                     const int* __restrict__ kcol, const float* __restrict__ wD,
                     int2* __restrict__ kwS){
  int q = blockIdx.x * blockDim.x + threadIdx.x;
  if (q >= E2) return;
  float w = wD[mapSD[q]];
  int k = kcol[dstS[q]];
  kwS[q] = make_int2(k, __float_as_int(w));
}

// U[n,:] = (A @ S)[n,:]. Flattened 2-hop edge list per block; parallel prefix scan.
__global__ void k_U(const int* __restrict__ rowS, const int* __restrict__ dstS,
                    const int2* __restrict__ kwS, __half* __restrict__ U){
  __shared__ float acc[UP];   // 14 KB
  __shared__ int pref[129];
  __shared__ int nbase[128];
  int t = threadIdx.x, n = blockIdx.x;
  for (int i = t; i < UP; i += 256) acc[i] = 0.f;
  int b = rowS[n], e = rowS[n+1];
  __syncthreads();
  for (int cb = b; cb < e; cb += 128){
    int cnt = min(128, e - cb);
    if (t < cnt){
      int j = dstS[cb + t];
      int b2 = rowS[j];
      nbase[t] = b2;
      pref[t+1] = rowS[j+1] - b2;
    }
    if (t == 0) pref[0] = 0;
    __syncthreads();
    for (int offs = 1; offs < 128; offs <<= 1){
      int val = 0;
      if (t < cnt && t + 1 > offs) val = pref[t + 1 - offs];
      __syncthreads();
      if (t < cnt) pref[t + 1] += val;
      __syncthreads();
    }
    int total = pref[cnt];
    for (int idx = t; idx < total; idx += 256){
      int lo = 0, hi = cnt - 1;
      while (lo < hi){
        int mid = (lo + hi + 1) >> 1;
        if (pref[mid] <= idx) lo = mid; else hi = mid - 1;
      }
      int q = nbase[lo] + (idx - pref[lo]);
      int2 kw = kwS[q];
      if (kw.x >= 0) atomicAdd(&acc[kw.x], __int_as_float(kw.y));
    }
    __syncthreads();
  }
  __half2* Ur = (__half2*)(U + (size_t)n * UP);
  for (int i = t; i < UP/2; i += 256)
    Ur[i] = __halves2half2(__float2half(acc[2*i]), __float2half(acc[2*i+1]));
}

// A2[k1, cc*448 .. +447] (single-row, 8-deep ILP, NT row-major writes).
__global__ void k_A2B(const int* __restrict__ rowD,
                      const unsigned* __restrict__ offsD, const __half* __restrict__ wHDh,
                      const int* __restrict__ perm,
                      const __half* __restrict__ Uh, __half* __restrict__ A2,
                      int* __restrict__ deg){
  int cc = blockIdx.x & 7;
  int rt = blockIdx.x >> 3;
  int t = threadIdx.x;
  int w = t >> 6, lane = t & 63;
  int k1 = rt*4 + w;
  if (k1 >= KC) return;
  bool act = lane < 56;
  unsigned laneoff = (unsigned)(cc*448*2 + lane*16);
  const char* Ub = (const char*)Uh;
  const _Float16* wHD = (const _Float16*)wHDh;

  f16x8 accA = (f16x8)(_Float16)0, accB = (f16x8)(_Float16)0;
  f16x8 accC = (f16x8)(_Float16)0, accD = (f16x8)(_Float16)0;
  int v1 = perm[k1];
  int p = rowD[v1], end = rowD[v1+1];

  int pre = (8 - (p & 7)) & 7;
  if (pre > end - p) pre = end - p;
  for (int z = 0; z < pre; ++z, ++p){
    unsigned off = offsD[p];
    _Float16 w0 = wHD[p];
    if (act){
      f16x8 u = *(const f16x8*)(Ub + (size_t)(off + laneoff));
      accA += u * w0;
    }
  }
  for (; p + 8 <= end; p += 8){
    uint4 oA = *(const uint4*)(offsD + p);
    uint4 oB = *(const uint4*)(offsD + p + 4);
    f16x8 wv = *(const f16x8*)(wHD + p);
    if (act){
      f16x8 u0 = *(const f16x8*)(Ub + (size_t)(oA.x + laneoff));
      f16x8 u1 = *(const f16x8*)(Ub + (size_t)(oA.y + laneoff));
      f16x8 u2 = *(const f16x8*)(Ub + (size_t)(oA.z + laneoff));
      f16x8 u3 = *(const f16x8*)(Ub + (size_t)(oA.w + laneoff));
      f16x8 u4 = *(const f16x8*)(Ub + (size_t)(oB.x + laneoff));
      f16x8 u5 = *(const f16x8*)(Ub + (size_t)(oB.y + laneoff));
      f16x8 u6 = *(const f16x8*)(Ub + (size_t)(oB.z + laneoff));
      f16x8 u7 = *(const f16x8*)(Ub + (size_t)(oB.w + laneoff));
      accA += u0 * wv[0];
      accB += u1 * wv[1];
      accC += u2 * wv[2];
      accD += u3 * wv[3];
      accA += u4 * wv[4];
      accB += u5 * wv[5];
      accC += u6 * wv[6];
      accD += u7 * wv[7];
    }
  }
  for (; p < end; ++p){
    unsigned off = offsD[p];
    _Float16 w0 = wHD[p];
    if (act){
      f16x8 u = *(const f16x8*)(Ub + (size_t)(off + laneoff));
      accB += u * w0;
    }
  }
  f16x8 acc = (accA + accB) + (accC + accD);

  int col0 = cc*448 + lane * 8;
  f16x8 o = (f16x8)(_Float16)0;
  int c = 0;
  if (act){
    #pragma unroll
    for (int e = 0; e < 8; ++e){
      int col = col0 + e;
      _Float16 hv = (col == k1 || col >= KC) ? (_Float16)0 : acc[e];
      o[e] = hv;
      c += (hv != (_Float16)0) ? 1 : 0;
    }
  }
  #pragma unroll
  for (int s = 32; s > 0; s >>= 1) c += __shfl_down(c, s);
  if (lane == 0) atomicAdd(&deg[k1], c);
  if (act && col0 + 8 <= A2P)
    __builtin_nontemporal_store(o, (f16x8*)(A2 + (size_t)k1 * A2P + col0));
}

// LDS-tiled transpose: A2T[i][j] = A2[j][i]; rows j >= KC read as zero. NT load/store.
__global__ void k_tr(const __half* __restrict__ A2, __half* __restrict__ A2T){
  __shared__ float tile[64][65];
  int t = threadIdx.x;
  int i0 = blockIdx.x * 64, j0 = blockIdx.y * 64;
  int sl = t & 7;
  #pragma unroll
  for (int p = 0; p < 2; ++p){
    int jl = (t >> 3) + p*32;
    int j = j0 + jl;
    f16x8 v;
    if (j < KC) v = __builtin_nontemporal_load((const f16x8*)(A2 + (size_t)j*A2P + i0 + sl*8));
    else v = (f16x8)(_Float16)0;
    #pragma unroll
    for (int e = 0; e < 8; ++e) tile[jl][sl*8 + e] = (float)v[e];
  }
  __syncthreads();
  #pragma unroll
  for (int p = 0; p < 2; ++p){
    int il = (t >> 3) + p*32;
    int i = i0 + il;
    f16x8 o;
    #pragma unroll
    for (int e = 0; e < 8; ++e) o[e] = (_Float16)tile[sl*8 + e][il];
    __builtin_nontemporal_store(o, (f16x8*)(A2T + (size_t)i*A2P + j0 + sl*8));
  }
}

// Xt[h][j] = (f16) X[j][h], zero-padded for j >= KC.
__global__ void k_xt(const float* __restrict__ X, __half* __restrict__ Xt){
  __shared__ float T2[64][129];
  int t = threadIdx.x;
  int j0 = blockIdx.x * 64;
  for (int l = t; l < 64*32; l += 256){
    int jl = l >> 5, hg = (l & 31) * 4;
    int j = j0 + jl;
    float4 v = make_float4(0.f, 0.f, 0.f, 0.f);
    if (j < KC) v = *(const float4*)(X + (size_t)j*HH + hg);
    T2[jl][hg] = v.x; T2[jl][hg+1] = v.y; T2[jl][hg+2] = v.z; T2[jl][hg+3] = v.w;
  }
  __syncthreads();
  for (int idx = t; idx < 128*64; idx += 256){
    int h = idx >> 6, jl = idx & 63;
    Xt[(size_t)h*A2P + j0 + jl] = __float2half(T2[jl][h]);
  }
}

// MFMA dagg: 32i x 128h per block, K-split 4, atomic-free; f16 NT partial writes
// (via _Float16* view: NT builtin accepts float-typed pointers, not __half*).
__global__ void k_mm(const __half* __restrict__ A2Th, const __half* __restrict__ Xth,
                     __half* __restrict__ parth){
  const _Float16* A2T = (const _Float16*)A2Th;
  const _Float16* Xt  = (const _Float16*)Xth;
  _Float16* part = (_Float16*)parth;
  int t = threadIdx.x;
  int lane = t & 63, w = t >> 6;
  int i0 = (blockIdx.x >> 2) * 32;
  int kq = blockIdx.x & 3;
  int kbeg = kq * KQ;
  _Float16* po = part + (size_t)kq * KC * HH;
  int l15 = lane & 15, lk = (lane >> 4) * 8;
  const _Float16* Ar0 = A2T + (size_t)(i0 + l15) * A2P + lk + kbeg;
  const _Float16* Ar1 = Ar0 + (size_t)16 * A2P;
  const _Float16* B0 = Xt + (size_t)(w*32 + l15) * A2P + lk + kbeg;
  const _Float16* B1 = B0 + (size_t)16 * A2P;
  f32x4 acc00 = (f32x4)0.f, acc01 = (f32x4)0.f;
  f32x4 acc10 = (f32x4)0.f, acc11 = (f32x4)0.f;
  for (int kk = 0; kk < KQ; kk += 64){
    f16x8 a00 = *(const f16x8*)(Ar0 + kk);
    f16x8 a01 = *(const f16x8*)(Ar0 + kk + 32);
    f16x8 a10 = *(const f16x8*)(Ar1 + kk);
    f16x8 a11 = *(const f16x8*)(Ar1 + kk + 32);
    f16x8 b00 = *(const f16x8*)(B0 + kk);
    f16x8 b01 = *(const f16x8*)(B1 + kk);
    f16x8 b10 = *(const f16x8*)(B0 + kk + 32);
    f16x8 b11 = *(const f16x8*)(B1 + kk + 32);
    acc00 = __builtin_amdgcn_mfma_f32_16x16x32_f16(a00, b00, acc00, 0, 0, 0);
    acc01 = __builtin_amdgcn_mfma_f32_16x16x32_f16(a00, b01, acc01, 0, 0, 0);
    acc10 = __builtin_amdgcn_mfma_f32_16x16x32_f16(a10, b00, acc10, 0, 0, 0);
    acc11 = __builtin_amdgcn_mfma_f32_16x16x32_f16(a10, b01, acc11, 0, 0, 0);
    acc00 = __builtin_amdgcn_mfma_f32_16x16x32_f16(a01, b10, acc00, 0, 0, 0);
    acc01 = __builtin_amdgcn_mfma_f32_16x16x32_f16(a01, b11, acc01, 0, 0, 0);
    acc10 = __builtin_amdgcn_mfma_f32_16x16x32_f16(a11, b10, acc10, 0, 0, 0);
    acc11 = __builtin_amdgcn_mfma_f32_16x16x32_f16(a11, b11, acc11, 0, 0, 0);
  }
  int rbase = (lane >> 4) * 4;
  #pragma unroll
  for (int r = 0; r < 4; ++r){
    int ia = i0 + rbase + r;
    int ib = ia + 16;
    if (ia < KC){
      __builtin_nontemporal_store((_Float16)acc00[r], &po[(size_t)ia*HH + w*32 + l15]);
      __builtin_nontemporal_store((_Float16)acc01[r], &po[(size_t)ia*HH + w*32 + 16 + l15]);
    }
    if (ib < KC){
      __builtin_nontemporal_store((_Float16)acc10[r], &po[(size_t)ib*HH + w*32 + l15]);
      __builtin_nontemporal_store((_Float16)acc11[r], &po[(size_t)ib*HH + w*32 + 16 + l15]);
    }
  }
}

} // namespace

extern "C" void kernel_launch(void* const* d_in, const int* in_sizes, int n_in,
                              void* d_out, int out_size, void* d_ws, size_t ws_size,
                              hipStream_t stream){
  (void)in_sizes; (void)n_in; (void)out_size; (void)ws_size;
  const float* x      = (const float*)d_in[0];
  const int*   ei     = (const int*)d_in[1];
  const float* c0Wrel = (const float*)d_in[2];
  const float* c0brel = (const float*)d_in[3];
  const float* c0Wroot= (const float*)d_in[4];
  const float* c1Wrel = (const float*)d_in[5];
  const float* c1brel = (const float*)d_in[6];
  const float* c1Wroot= (const float*)d_in[7];
  const float* c2Wrel = (const float*)d_in[8];
  const float* c2brel = (const float*)d_in[9];
  const float* c2Wroot= (const float*)d_in[10];
  const float* c3Wrel = (const float*)d_in[11];
  const float* c3brel = (const float*)d_in[12];
  const float* c3Wroot= (const float*)d_in[13];
  const float* Wlin   = (const float*)d_in[14];
  const float* blin   = (const float*)d_in[15];
  const float* Watt   = (const float*)d_in[16];
  const float* batt   = (const float*)d_in[17];
  const float* W1     = (const float*)d_in[18];
  const float* b1     = (const float*)d_in[19];
  const float* W2     = (const float*)d_in[20];
  const float* W3     = (const float*)d_in[21];
  const float* b3     = (const float*)d_in[22];
  float* out = (float*)d_out;

  char* base = (char*)d_ws;
  size_t off = 0;
  auto carve = [&](size_t bytes) -> void* {
    void* p = base + off;
    off += (bytes + 255) & ~(size_t)255;
    return p;
  };
  float* x1    = (float*)carve((size_t)NN*HH*4);
  float* x2b   = (float*)carve((size_t)NN*HH*4);
  float* xnew  = (float*)carve((size_t)NN*HH*4);
  float* xp    = (float*)carve((size_t)KC*HH*4);
  float* x3    = (float*)carve((size_t)KC*HH*4);
  __half* part = (__half*)carve((size_t)4*KC*HH*2);  // 4 f16 K-quarter partials
  __half* A2   = (__half*)carve((size_t)KC*A2P*2);   // ~22 MB
  __half* U    = (__half*)carve((size_t)NN*UP*2);    // ~29 MB; dead after k_A2B -> reused as A2T
  __half* A2T  = U;
  __half* Xt   = (__half*)carve((size_t)HH*A2P*2);
  __half* xh   = (__half*)carve((size_t)NN*HH*2);
  __half* x1h  = (__half*)carve((size_t)NN*HH*2);
  __half* x2bh = (__half*)carve((size_t)NN*HH*2);
  __half* mbh  = (__half*)carve((size_t)NN*HH*2);
  __half* WH   = (__half*)carve((size_t)4*HH*HH*2);
  float* xdot  = (float*)carve(NN*4);
  float* qdot  = (float*)carve(NN*4);
  float* mmaxA = (float*)carve(NN*4);
  float* ssumA = (float*)carve(NN*4);
  float* aA    = (float*)carve(NN*4);
  float* bA    = (float*)carve(NN*4);
  float* cA    = (float*)carve(NN*4);
  float* fitA  = (float*)carve(NN*4);
  float* fitk  = (float*)carve(KC*4);
  float* wA2   = (float*)carve((HH+1)*4);
  float* wD    = (float*)carve((size_t)E2*4);
  int* rowD = (int*)carve((NN+1)*4);
  int* rowS = (int*)carve((NN+1)*4);
  int* cntD = (int*)carve(NN*4);
  int* cntS = (int*)carve(NN*4);
  int* curD = (int*)carve(NN*4);
  int* curS = (int*)carve(NN*4);
  int* colD = (int*)carve((size_t)E2*4);
  int* dstS = (int*)carve((size_t)E2*4);
  int* mapSD= (int*)carve((size_t)E2*4);
  int2* kwS = (int2*)carve((size_t)E2*8);
  unsigned* offsD = (unsigned*)carve((size_t)E2*4);
  __half* wHD = (__half*)carve((size_t)E2*2);
  int* perm = (int*)carve(KC*4);
  int* kcol = (int*)carve(NN*4);
  int* deg3 = (int*)carve(KC*4);

  k_zero_init<<<NN/256, 256, 0, stream>>>(cntD, cntS, deg3, out);
  k_count<<<(E2+255)/256, 256, 0, stream>>>(ei, cntD, cntS);
  k_scan<<<1, 1024, 0, stream>>>(cntD, cntS, rowD, rowS, curD, curS);
  k_scatter<<<(E2+255)/256, 256, 0, stream>>>(ei, curD, curS, colD, dstS, mapSD, offsD);
  k_prep<<<2048 + 256 + 1, 256, 0, stream>>>(x, c0Wrel, c0Wroot, c1Wrel, c1Wroot,
                                             Wlin, blin, Watt, xh, WH, wA2);

  // conv0 (MFMA linear; colmean fused)
  k_edge_meanH<<<NN, 128, 0, stream>>>(xh, rowD, colD, mbh);
  k_linM<<<NN/16, 256, 0, stream>>>(mbh, xh, WH, 0, c0brel, x1, x1h, out + 0,
                                    nullptr, nullptr);

  // conv1 (fused xdot for ASAP attention)
  k_edge_meanH<<<NN, 128, 0, stream>>>(x1h, rowD, colD, mbh);
  k_linM<<<NN/16, 256, 0, stream>>>(mbh, x1h, WH, 32768, c1brel, x2b, x2bh, out + 128,
                                    Watt, xdot);

  // ASAP pool (gathers from f16 x2bh; emits wD + f16 wHD)
  k_pool<<<NN, 128, 0, stream>>>(x2bh, rowD, colD, xdot, wA2, batt,
                                 W1, b1, W2, W3, b3,
                                 qdot, mmaxA, ssumA, xnew, wD, wHD, aA, bA, cA);
  k_fit<<<NN, 128, 0, stream>>>(rowD, colD, aA, bA, cA, fitA);
  k_sel<<<1, 1024, 0, stream>>>(fitA, perm, fitk, kcol);
  k_wS<<<(E2+255)/256, 256, 0, stream>>>(mapSD, dstS, kcol, wD, kwS);
  k_U<<<NN, 256, 0, stream>>>(rowS, dstS, kwS, U);
  k_A2B<<<A2B_RT*8, 256, 0, stream>>>(rowD, offsD, wHD, perm, U, A2, deg3);

  // transpose A2 -> A2T (U is dead now; A2T aliases it)
  k_tr<<<dim3(A2P/64, A2P/64), 256, 0, stream>>>(A2, A2T);

  // conv2 (MFMA K-split 4; partial-sum + deg-mean + colmean fused into k_lin2)
  k_xpt<<<A2P/64, 256, 0, stream>>>(xnew, perm, fitk, xp, Xt);
  k_mm<<<(A2P/32)*4, 256, 0, stream>>>(A2T, Xt, part);
  k_lin2<<<(KC+15)/16, 256, 0, stream>>>(part, deg3, xp,
                                         c2Wrel, c2brel, c2Wroot, x3, KC, out + 256);

  // conv3 (x4 never materialized; only its column-mean is needed)
  k_xt<<<A2P/64, 256, 0, stream>>>(x3, Xt);
  k_mm<<<(A2P/32)*4, 256, 0, stream>>>(A2T, Xt, part);
  k_lin2<<<(KC+15)/16, 256, 0, stream>>>(part, deg3, x3,
                                         c3Wrel, c3brel, c3Wroot, nullptr, KC, out + 384);
}

// Round 17
// 308.863 us; speedup vs baseline: 1.2086x; 1.2086x over previous
//
#include <hip/hip_runtime.h>
#include <hip/hip_fp16.h>
#include <math.h>

namespace {

constexpr int NN = 4096;
constexpr int EE = 131072;
constexpr int E2 = EE + NN;      // 135168 pool edges (orig + self loops)
constexpr int HH = 128;
constexpr int KC = 3277;         // ceil(0.8*4096)
constexpr int UPW = 104;         // bitmap words per row (104*32 = 3328 >= KC)

typedef _Float16 f16x8 __attribute__((ext_vector_type(8)));
typedef float f32x4 __attribute__((ext_vector_type(4)));

__device__ __forceinline__ float lrelu02(float x){ return x > 0.f ? x : 0.2f * x; }

__device__ __forceinline__ float redSum128(float* red, int t, float v){
  red[t] = v; __syncthreads();
  #pragma unroll
  for (int s = 64; s > 0; s >>= 1){ if (t < s) red[t] += red[t + s]; __syncthreads(); }
  float r = red[0]; __syncthreads();
  return r;
}
__device__ __forceinline__ float redMax128(float* red, int t, float v){
  red[t] = v; __syncthreads();
  #pragma unroll
  for (int s = 64; s > 0; s >>= 1){ if (t < s) red[t] = fmaxf(red[t], red[t + s]); __syncthreads(); }
  float r = red[0]; __syncthreads();
  return r;
}

__global__ void k_zero_init(int* cntD, int* cntS, float* out){
  int i = blockIdx.x * blockDim.x + threadIdx.x;
  if (i < NN){ cntD[i] = 0; cntS[i] = 0; }
  if (i < 512) out[i] = 0.f;
}

__global__ void k_count(const int* __restrict__ ei, int* cntD, int* cntS){
  int e = blockIdx.x * blockDim.x + threadIdx.x;
  if (e >= E2) return;
  int u, v;
  if (e < EE){ u = ei[e]; v = ei[EE + e]; } else { u = e - EE; v = u; }
  atomicAdd(&cntD[v], 1);
  atomicAdd(&cntS[u], 1);
}

__global__ void k_scan(const int* cntD, const int* cntS, int* rowD, int* rowS, int* curD, int* curS){
  __shared__ int sc[1024];
  int t = threadIdx.x;
  for (int pass = 0; pass < 2; ++pass){
    const int* cnt = pass ? cntS : cntD;
    int* row = pass ? rowS : rowD;
    int* cur = pass ? curS : curD;
    int c0 = cnt[t*4+0], c1 = cnt[t*4+1], c2 = cnt[t*4+2], c3 = cnt[t*4+3];
    int tot = c0 + c1 + c2 + c3;
    sc[t] = tot; __syncthreads();
    for (int offs = 1; offs < 1024; offs <<= 1){
      int v = (t >= offs) ? sc[t - offs] : 0;
      __syncthreads();
      sc[t] += v;
      __syncthreads();
    }
    int excl = sc[t] - tot;
    int r0 = excl, r1 = r0 + c0, r2 = r1 + c1, r3 = r2 + c2;
    row[t*4+0] = r0; row[t*4+1] = r1; row[t*4+2] = r2; row[t*4+3] = r3;
    cur[t*4+0] = r0; cur[t*4+1] = r1; cur[t*4+2] = r2; cur[t*4+3] = r3;
    if (t == 1023) row[NN] = r3 + c3;
    __syncthreads();
  }
}

__global__ void k_scatter(const int* __restrict__ ei, int* curD, int* curS,
                          int* colD, int* dstS, int* mapSD){
  int e = blockIdx.x * blockDim.x + threadIdx.x;
  if (e >= E2) return;
  int u, v;
  if (e < EE){ u = ei[e]; v = ei[EE + e]; } else { u = e - EE; v = u; }
  int p = atomicAdd(&curD[v], 1); colD[p] = u;
  int q = atomicAdd(&curS[u], 1); dstS[q] = v; mapSD[q] = p;
}

// prep: xh = f16(x); WH = f16 weights [W0rel|W0root|W1rel|W1root]; wprep (last block).
__global__ void k_prep(const float* __restrict__ x,
                       const float* __restrict__ W0rel, const float* __restrict__ W0root,
                       const float* __restrict__ W1rel, const float* __restrict__ W1root,
                       const float* __restrict__ Wlin, const float* __restrict__ blin,
                       const float* __restrict__ Watt,
                       __half* __restrict__ xh, __half* __restrict__ WH, float* __restrict__ wA2){
  int b = blockIdx.x;
  if (b < 2048){
    int i = b*256 + threadIdx.x;
    xh[i] = __float2half(x[i]);
  } else if (b < 2048 + 256){
    int i = (b - 2048)*256 + threadIdx.x;
    int m = i >> 14, o = i & 16383;
    const float* src = (m == 0) ? W0rel : (m == 1) ? W0root : (m == 2) ? W1rel : W1root;
    WH[i] = __float2half(src[o]);
  } else {
    int c = threadIdx.x;
    if (c < 128){
      float s = 0.f;
      for (int hh = 0; hh < HH; ++hh) s += Watt[hh] * Wlin[hh*HH + c];
      wA2[c] = s;
      if (c == 0){
        float q = 0.f;
        for (int hh = 0; hh < HH; ++hh) q += blin[hh] * Watt[hh];
        wA2[HH] = q;
      }
    }
  }
}

// mean over in-neighbors, f16 input rows, f16 output (f32 accumulate).
__global__ void k_edge_meanH(const __half* __restrict__ xinh, const int* __restrict__ rowD,
                             const int* __restrict__ colD, __half* __restrict__ meanbh){
  int v = blockIdx.x, t = threadIdx.x;
  int beg = rowD[v], end = rowD[v+1];
  float acc = 0.f;
  int p = beg;
  for (; p + 8 <= end; p += 8){
    int u0 = colD[p],   u1 = colD[p+1], u2 = colD[p+2], u3 = colD[p+3];
    int u4 = colD[p+4], u5 = colD[p+5], u6 = colD[p+6], u7 = colD[p+7];
    float a0 = __half2float(xinh[(size_t)u0*HH + t]);
    float a1 = __half2float(xinh[(size_t)u1*HH + t]);
    float a2 = __half2float(xinh[(size_t)u2*HH + t]);
    float a3 = __half2float(xinh[(size_t)u3*HH + t]);
    float a4 = __half2float(xinh[(size_t)u4*HH + t]);
    float a5 = __half2float(xinh[(size_t)u5*HH + t]);
    float a6 = __half2float(xinh[(size_t)u6*HH + t]);
    float a7 = __half2float(xinh[(size_t)u7*HH + t]);
    if (u0 != v) acc += a0;
    if (u1 != v) acc += a1;
    if (u2 != v) acc += a2;
    if (u3 != v) acc += a3;
    if (u4 != v) acc += a4;
    if (u5 != v) acc += a5;
    if (u6 != v) acc += a6;
    if (u7 != v) acc += a7;
  }
  for (; p < end; ++p){ int u = colD[p]; if (u != v) acc += __half2float(xinh[(size_t)u*HH + t]); }
  float dg = (float)(end - beg - 1);
  meanbh[(size_t)v*HH + t] = __float2half(acc / fmaxf(dg, 1.f));
}

// MFMA GraphConv linear: xout = relu([meanbh|xinh] @ [Wrel|Wroot]^T + brel).
// Fused colmean; optional fused xdot (ASAP attention dot).
__global__ void k_linM(const __half* __restrict__ mh, const __half* __restrict__ xinh,
                       const __half* __restrict__ WHh, int woff,
                       const float* __restrict__ brel,
                       float* __restrict__ xout, __half* __restrict__ xouth,
                       float* __restrict__ cmout,
                       const float* __restrict__ WattFull, float* __restrict__ xdotp){
  __shared__ float sx[16][4];
  int t = threadIdx.x, lane = t & 63, w = t >> 6;
  int r0 = blockIdx.x * 16;
  int l15 = lane & 15, lk = (lane >> 4) * 8;
  const _Float16* WH = (const _Float16*)WHh;
  const _Float16* Am = (const _Float16*)mh + (size_t)(r0 + l15)*HH + lk;
  const _Float16* Ax = (const _Float16*)xinh + (size_t)(r0 + l15)*HH + lk;
  const _Float16* Brel0 = WH + woff + (size_t)(w*32 + l15)*HH + lk;
  const _Float16* Brel1 = Brel0 + (size_t)16*HH;
  const _Float16* Broot0 = Brel0 + 16384;
  const _Float16* Broot1 = Brel1 + 16384;
  f32x4 acc0 = (f32x4)0.f, acc1 = (f32x4)0.f;
  #pragma unroll
  for (int kk = 0; kk < HH; kk += 32){
    f16x8 a = *(const f16x8*)(Am + kk);
    f16x8 b0 = *(const f16x8*)(Brel0 + kk);
    f16x8 b1 = *(const f16x8*)(Brel1 + kk);
    acc0 = __builtin_amdgcn_mfma_f32_16x16x32_f16(a, b0, acc0, 0, 0, 0);
    acc1 = __builtin_amdgcn_mfma_f32_16x16x32_f16(a, b1, acc1, 0, 0, 0);
  }
  #pragma unroll
  for (int kk = 0; kk < HH; kk += 32){
    f16x8 a = *(const f16x8*)(Ax + kk);
    f16x8 b0 = *(const f16x8*)(Broot0 + kk);
    f16x8 b1 = *(const f16x8*)(Broot1 + kk);
    acc0 = __builtin_amdgcn_mfma_f32_16x16x32_f16(a, b0, acc0, 0, 0, 0);
    acc1 = __builtin_amdgcn_mfma_f32_16x16x32_f16(a, b1, acc1, 0, 0, 0);
  }
  int rbase = (lane >> 4) * 4;
  int h0 = w*32 + l15, h1 = h0 + 16;
  float bb0 = brel[h0], bb1 = brel[h1];
  float wt0 = 0.f, wt1 = 0.f;
  if (xdotp){ wt0 = WattFull[HH + h0]; wt1 = WattFull[HH + h1]; }
  float cs0 = 0.f, cs1 = 0.f;
  #pragma unroll
  for (int r = 0; r < 4; ++r){
    int row = r0 + rbase + r;
    float v0 = fmaxf(acc0[r] + bb0, 0.f);
    float v1 = fmaxf(acc1[r] + bb1, 0.f);
    xout[(size_t)row*HH + h0] = v0;
    xout[(size_t)row*HH + h1] = v1;
    xouth[(size_t)row*HH + h0] = __float2half(v0);
    xouth[(size_t)row*HH + h1] = __float2half(v1);
    cs0 += v0; cs1 += v1;
    if (xdotp){
      float ds = v0*wt0 + v1*wt1;
      ds += __shfl_xor(ds, 1); ds += __shfl_xor(ds, 2);
      ds += __shfl_xor(ds, 4); ds += __shfl_xor(ds, 8);
      if (l15 == 0) sx[rbase + r][w] = ds;
    }
  }
  cs0 += __shfl_xor(cs0, 16); cs0 += __shfl_xor(cs0, 32);
  cs1 += __shfl_xor(cs1, 16); cs1 += __shfl_xor(cs1, 32);
  if (lane < 16){
    atomicAdd(&cmout[h0], cs0 / (float)NN);
    atomicAdd(&cmout[h1], cs1 / (float)NN);
  }
  if (xdotp){
    __syncthreads();
    if (t < 16) xdotp[r0 + t] = sx[t][0] + sx[t][1] + sx[t][2] + sx[t][3];
  }
}

// dense-conv linear from precomputed mean: xout = relu(meanb@Wrel^T + brel + xin@Wroot^T).
// Optional f32/f16 outputs; fused column-mean.
__global__ void k_lin2(const float* __restrict__ meanb, const float* __restrict__ xin,
                       const float* __restrict__ Wrel, const float* __restrict__ brel,
                       const float* __restrict__ Wroot,
                       float* __restrict__ xout, __half* __restrict__ xouth, int rows,
                       float* __restrict__ cmout){
  __shared__ float ms[16][HH];
  __shared__ float xs[16][HH];
  __shared__ float cmred[256];
  int tid = threadIdx.x;
  int r0 = blockIdx.x * 16;
  for (int l = tid; l < 16*HH; l += 256){
    int r = l >> 7, c = l & 127; int gr = r0 + r;
    float mv = 0.f, xv = 0.f;
    if (gr < rows){
      size_t idx = (size_t)gr*HH + c;
      mv = meanb[idx];
      xv = xin[idx];
    }
    ms[r][c] = mv; xs[r][c] = xv;
  }
  __syncthreads();
  int h = tid & 127, hgrp = tid >> 7;
  float acc[8] = {0.f,0.f,0.f,0.f,0.f,0.f,0.f,0.f};
  for (int c = 0; c < HH; ++c){
    float wr = Wrel[h*HH + c], wo = Wroot[h*HH + c];
    #pragma unroll
    for (int r = 0; r < 8; ++r) acc[r] += ms[hgrp*8 + r][c]*wr + xs[hgrp*8 + r][c]*wo;
  }
  float bb = brel[h];
  float csum = 0.f;
  #pragma unroll
  for (int r = 0; r < 8; ++r){
    int gr = r0 + hgrp*8 + r;
    if (gr < rows){
      float val = fmaxf(acc[r] + bb, 0.f);
      if (xout) xout[(size_t)gr*HH + h] = val;
      if (xouth) xouth[(size_t)gr*HH + h] = __float2half(val);
      csum += val;
    }
  }
  cmred[tid] = csum; __syncthreads();
  if (tid < 128) atomicAdd(&cmout[h], (cmred[tid] + cmred[tid + 128]) / (float)rows);
}

// per dst node v (f16 gathers, f32 accumulate): xq max -> qdot; edge-softmax stats;
// x_new; wD; fused LEConv partials; fused diag2[v] = sum_n S[n,v]^2 (same-src pair sum).
__global__ void k_pool(const __half* __restrict__ x2h, const int* __restrict__ rowD, const int* __restrict__ colD,
                       const float* __restrict__ xdotA, const float* __restrict__ wA2, const float* __restrict__ battp,
                       const float* __restrict__ W1, const float* __restrict__ b1,
                       const float* __restrict__ W2, const float* __restrict__ W3, const float* __restrict__ b3,
                       float* qdotA, float* mA, float* sA, float* __restrict__ xnew, float* __restrict__ wD,
                       float* aA, float* bA, float* cA, float* __restrict__ diag2){
  __shared__ float red[128];
  __shared__ float wmem[128];
  __shared__ int uc[128];
  __shared__ int srcL[1024];
  __shared__ float wL[1024];
  int v = blockIdx.x, t = threadIdx.x;
  int beg = rowD[v], end = rowD[v+1];
  float batt = battp[0];
  float mx = -3.402823466e38f;
  int p = beg;
  for (; p + 4 <= end; p += 4){
    float a0 = __half2float(x2h[(size_t)colD[p]*HH + t]);
    float a1 = __half2float(x2h[(size_t)colD[p+1]*HH + t]);
    float a2 = __half2float(x2h[(size_t)colD[p+2]*HH + t]);
    float a3 = __half2float(x2h[(size_t)colD[p+3]*HH + t]);
    mx = fmaxf(fmaxf(fmaxf(fmaxf(mx, a0), a1), a2), a3);
  }
  for (; p < end; ++p) mx = fmaxf(mx, __half2float(x2h[(size_t)colD[p]*HH + t]));
  float qd = redSum128(red, t, mx * wA2[t]) + wA2[HH];
  float lm = -3.402823466e38f;
  for (p = beg + t; p < end; p += 128) lm = fmaxf(lm, lrelu02(qd + xdotA[colD[p]] + batt));
  float mm = redMax128(red, t, lm);
  float ls = 0.f;
  for (p = beg + t; p < end; p += 128) ls += expf(lrelu02(qd + xdotA[colD[p]] + batt) - mm);
  float ss = redSum128(red, t, ls);
  float acc = 0.f;
  for (int basep = beg; basep < end; basep += 128){
    int cnt = min(128, end - basep);
    if (t < cnt){
      int u = colD[basep + t];
      uc[t] = u;
      float w = expf(lrelu02(qd + xdotA[u] + batt) - mm) / ss;
      wmem[t] = w;
      wD[basep + t] = w;
      int o = basep - beg + t;
      if (o < 1024){ srcL[o] = u; wL[o] = w; }
    }
    __syncthreads();
    int i = 0;
    for (; i + 4 <= cnt; i += 4){
      float a0 = __half2float(x2h[(size_t)uc[i]*HH + t]);
      float a1 = __half2float(x2h[(size_t)uc[i+1]*HH + t]);
      float a2 = __half2float(x2h[(size_t)uc[i+2]*HH + t]);
      float a3 = __half2float(x2h[(size_t)uc[i+3]*HH + t]);
      acc += wmem[i]*a0 + wmem[i+1]*a1 + wmem[i+2]*a2 + wmem[i+3]*a3;
    }
    for (; i < cnt; ++i) acc += wmem[i] * __half2float(x2h[(size_t)uc[i]*HH + t]);
    __syncthreads();
  }
  xnew[(size_t)v*HH + t] = acc;
  float s1 = redSum128(red, t, acc * W1[t]);
  float s2 = redSum128(red, t, acc * W2[t]);
  float s3 = redSum128(red, t, acc * W3[t]);
  // diag2: sum over same-source pairs of in-edge weights
  int d = end - beg; if (d > 1024) d = 1024;
  float dpart = 0.f;
  for (int pp = t; pp < d; pp += 128){
    int s = srcL[pp];
    float sp = 0.f;
    for (int q = 0; q < d; ++q) if (srcL[q] == s) sp += wL[q];
    dpart += wL[pp] * sp;
  }
  float d2 = redSum128(red, t, dpart);
  if (t == 0){
    qdotA[v] = qd; mA[v] = mm; sA[v] = ss;
    aA[v] = s1 + b1[0]; bA[v] = s2; cA[v] = s3 + b3[0];
    diag2[v] = d2;
  }
}

__global__ void k_fit(const int* __restrict__ rowD, const int* __restrict__ colD,
                      const float* __restrict__ aA, const float* __restrict__ bA, const float* __restrict__ cA,
                      float* __restrict__ fitA){
  __shared__ float red[128];
  int v = blockIdx.x, t = threadIdx.x;
  int beg = rowD[v], end = rowD[v+1];
  float la = 0.f;
  for (int p = beg + t; p < end; p += 128) la += aA[colD[p]];
  float s = redSum128(red, t, la);
  if (t == 0){
    float g = s - (float)(end - beg) * bA[v] + cA[v];
    fitA[v] = 1.f / (1.f + expf(-g));
  }
}

// Exact top-K SET selection via radix-select (1 block, 1024 threads).
__global__ void k_sel(const float* __restrict__ fitA, int* perm, float* fitk, int* kcol){
  __shared__ unsigned keys[NN];
  __shared__ int hist[256];
  __shared__ int sc[1024];
  __shared__ int bc[2];
  int t = threadIdx.x;
  #pragma unroll
  for (int r = 0; r < 4; ++r){
    int i = t + r*1024;
    unsigned b = __float_as_uint(fitA[i]);
    keys[i] = (b & 0x80000000u) ? ~b : (b ^ 0x80000000u);
  }
  __syncthreads();
  unsigned prefix = 0;
  int kneed = KC;
  #pragma unroll
  for (int round = 0; round < 4; ++round){
    int shift = 24 - round*8;
    unsigned pmask = (round == 0) ? 0u : (0xFFFFFFFFu << (shift + 8));
    if (t < 256) hist[t] = 0;
    __syncthreads();
    #pragma unroll
    for (int r = 0; r < 4; ++r){
      unsigned kv = keys[t + r*1024];
      if ((kv & pmask) == prefix)
        atomicAdd(&hist[(kv >> shift) & 0xFF], 1);
    }
    __syncthreads();
    if (t == 0){
      int acc = 0, chosen = 0, rem = kneed;
      for (int bkt = 255; bkt >= 0; --bkt){
        int c = hist[bkt];
        if (acc + c >= kneed){ chosen = bkt; rem = kneed - acc; break; }
        acc += c;
      }
      bc[0] = chosen; bc[1] = rem;
    }
    __syncthreads();
    prefix |= ((unsigned)bc[0]) << shift;
    kneed = bc[1];
    __syncthreads();
  }
  unsigned T = prefix;
  int need_eq = kneed;
  int cnt[4]; int tot = 0;
  #pragma unroll
  for (int r = 0; r < 4; ++r){
    unsigned kv = keys[t*4 + r];
    int g = (kv > T) ? 1 : 0;
    int e = (kv == T) ? 1 : 0;
    cnt[r] = (g << 16) | e;
    tot += cnt[r];
  }
  sc[t] = tot; __syncthreads();
  for (int offs = 1; offs < 1024; offs <<= 1){
    int v = (t >= offs) ? sc[t - offs] : 0;
    __syncthreads();
    sc[t] += v;
    __syncthreads();
  }
  int gtot = sc[1023] >> 16;
  int run = sc[t] - tot;
  #pragma unroll
  for (int r = 0; r < 4; ++r){
    int i = t*4 + r;
    int g = cnt[r] >> 16, e = cnt[r] & 0xFFFF;
    int gpos = run >> 16, epos = run & 0xFFFF;
    int pos = -1;
    if (g) pos = gpos;
    else if (e && epos < need_eq) pos = gtot + epos;
    if (pos >= 0){ perm[pos] = i; fitk[pos] = fitA[i]; kcol[i] = pos; }
    else kcol[i] = -1;
    run += cnt[r];
  }
}

// xp[j,:] = xnew[perm[j],:]*fitk[j] (f32 + f16 copies)
__global__ void k_xpt(const float* __restrict__ xnew, const int* __restrict__ perm,
                      const float* __restrict__ fitk, float* __restrict__ xp,
                      __half* __restrict__ xph){
  int idx = blockIdx.x * 256 + threadIdx.x;
  if (idx >= KC*HH) return;
  int j = idx >> 7;
  float v = xnew[(size_t)perm[j]*HH + (idx & 127)] * fitk[j];
  xp[idx] = v;
  xph[idx] = __float2half(v);
}

// src-ordered packed (kcol, w) per pool edge
__global__ void k_wS(const int* __restrict__ mapSD, const int* __restrict__ dstS,
                     const int* __restrict__ kcol, const float* __restrict__ wD,
                     int2* __restrict__ kwS){
  int q = blockIdx.x * blockDim.x + threadIdx.x;
  if (q >= E2) return;
  float w = wD[mapSD[q]];
  int k = kcol[dstS[q]];
  kwS[q] = make_int2(k, __float_as_int(w));
}

// Y1[n,:] = (S @ X)[n,:] over n's out pool edges; optional UP bitmap emission.
__global__ void k_y1(const int* __restrict__ rowS, const int2* __restrict__ kwS,
                     const __half* __restrict__ Xh, __half* __restrict__ Y1h,
                     unsigned* __restrict__ UP, int emitUP){
  __shared__ int kArr[128];
  __shared__ float wArr[128];
  __shared__ unsigned upw[UPW];
  int n = blockIdx.x, t = threadIdx.x;
  if (emitUP && t < UPW) upw[t] = 0u;
  int beg = rowS[n], end = rowS[n+1];
  float acc = 0.f;
  for (int basep = beg; basep < end; basep += 128){
    int cnt = min(128, end - basep);
    if (t < cnt){
      int2 kw = kwS[basep + t];
      kArr[t] = kw.x;
      wArr[t] = __int_as_float(kw.y);
      if (emitUP && kw.x >= 0) atomicOr(&upw[kw.x >> 5], 1u << (kw.x & 31));
    }
    __syncthreads();
    for (int i = 0; i < cnt; ++i){
      int k = kArr[i];
      if (k >= 0) acc += wArr[i] * __half2float(Xh[(size_t)k*HH + t]);
    }
    __syncthreads();
  }
  Y1h[(size_t)n*HH + t] = __float2half(acc);
  if (emitUP){
    __syncthreads();
    if (t < UPW) UP[(size_t)n*UPW + t] = upw[t];
  }
}

// Y2[m,:] = sum over in-edge instances (pool edges incl self loops) of Y1[src,:]
__global__ void k_y2(const int* __restrict__ rowD, const int* __restrict__ colD,
                     const __half* __restrict__ Y1h, __half* __restrict__ Y2h){
  int m = blockIdx.x, t = threadIdx.x;
  int beg = rowD[m], end = rowD[m+1];
  float acc = 0.f;
  int p = beg;
  for (; p + 8 <= end; p += 8){
    float a0 = __half2float(Y1h[(size_t)colD[p]*HH + t]);
    float a1 = __half2float(Y1h[(size_t)colD[p+1]*HH + t]);
    float a2 = __half2float(Y1h[(size_t)colD[p+2]*HH + t]);
    float a3 = __half2float(Y1h[(size_t)colD[p+3]*HH + t]);
    float a4 = __half2float(Y1h[(size_t)colD[p+4]*HH + t]);
    float a5 = __half2float(Y1h[(size_t)colD[p+5]*HH + t]);
    float a6 = __half2float(Y1h[(size_t)colD[p+6]*HH + t]);
    float a7 = __half2float(Y1h[(size_t)colD[p+7]*HH + t]);
    acc += ((a0 + a1) + (a2 + a3)) + ((a4 + a5) + (a6 + a7));
  }
  for (; p < end; ++p) acc += __half2float(Y1h[(size_t)colD[p]*HH + t]);
  Y2h[(size_t)m*HH + t] = __float2half(acc);
}

// Z[k,:] = sum over in-edges of v_k of w * Y2[src,:]; meanb = (Z - diag2*X)/max(deg,1)
__global__ void k_z(const int* __restrict__ rowD, const int* __restrict__ colD,
                    const float* __restrict__ wD, const int* __restrict__ perm,
                    const __half* __restrict__ Y2h, const float* __restrict__ Xf,
                    const float* __restrict__ diag2, const int* __restrict__ degN,
                    float* __restrict__ meanb){
  __shared__ int uc[128];
  __shared__ float wm[128];
  int k = blockIdx.x, t = threadIdx.x;
  int v = perm[k];
  int beg = rowD[v], end = rowD[v+1];
  float acc = 0.f;
  for (int basep = beg; basep < end; basep += 128){
    int cnt = min(128, end - basep);
    if (t < cnt){ uc[t] = colD[basep + t]; wm[t] = wD[basep + t]; }
    __syncthreads();
    int i = 0;
    for (; i + 4 <= cnt; i += 4){
      float a0 = __half2float(Y2h[(size_t)uc[i]*HH + t]);
      float a1 = __half2float(Y2h[(size_t)uc[i+1]*HH + t]);
      float a2 = __half2float(Y2h[(size_t)uc[i+2]*HH + t]);
      float a3 = __half2float(Y2h[(size_t)uc[i+3]*HH + t]);
      acc += wm[i]*a0 + wm[i+1]*a1 + wm[i+2]*a2 + wm[i+3]*a3;
    }
    for (; i < cnt; ++i) acc += wm[i] * __half2float(Y2h[(size_t)uc[i]*HH + t]);
    __syncthreads();
  }
  float d = fmaxf((float)degN[k], 1.f);
  meanb[(size_t)k*HH + t] = (acc - diag2[v] * Xf[(size_t)k*HH + t]) / d;
}

// PAT[k1,:] = OR over in-neighbors n of v_{k1} of UP[n,:]
__global__ void k_degp(const int* __restrict__ rowD, const int* __restrict__ colD,
                       const int* __restrict__ perm, const unsigned* __restrict__ UP,
                       unsigned* __restrict__ PAT){
  int k1 = blockIdx.x, t = threadIdx.x;
  if (t >= UPW) return;
  int v = perm[k1];
  int beg = rowD[v], end = rowD[v+1];
  unsigned pw = 0u;
  for (int p = beg; p < end; ++p) pw |= UP[(size_t)colD[p]*UPW + t];
  PAT[(size_t)k1*UPW + t] = pw;
}

// degN[i] = (# rows k1 with PAT bit i set) - 1  (diag always structurally set)
__global__ void k_degc(const unsigned* __restrict__ PAT, int* __restrict__ degN){
  __shared__ int red[256];
  int w = blockIdx.x, t = threadIdx.x;
  int c[32];
  #pragma unroll
  for (int j = 0; j < 32; ++j) c[j] = 0;
  for (int r = t; r < KC; r += 256){
    unsigned b = PAT[(size_t)r*UPW + w];
    #pragma unroll
    for (int j = 0; j < 32; ++j) c[j] += (b >> j) & 1;
  }
  for (int j = 0; j < 32; ++j){
    red[t] = c[j]; __syncthreads();
    #pragma unroll
    for (int s = 128; s > 0; s >>= 1){ if (t < s) red[t] += red[t + s]; __syncthreads(); }
    if (t == 0) degN[w*32 + j] = red[0] - 1;
    __syncthreads();
  }
}

} // namespace

extern "C" void kernel_launch(void* const* d_in, const int* in_sizes, int n_in,
                              void* d_out, int out_size, void* d_ws, size_t ws_size,
                              hipStream_t stream){
  (void)in_sizes; (void)n_in; (void)out_size; (void)ws_size;
  const float* x      = (const float*)d_in[0];
  const int*   ei     = (const int*)d_in[1];
  const float* c0Wrel = (const float*)d_in[2];
  const float* c0brel = (const float*)d_in[3];
  const float* c0Wroot= (const float*)d_in[4];
  const float* c1Wrel = (const float*)d_in[5];
  const float* c1brel = (const float*)d_in[6];
  const float* c1Wroot= (const float*)d_in[7];
  const float* c2Wrel = (const float*)d_in[8];
  const float* c2brel = (const float*)d_in[9];
  const float* c2Wroot= (const float*)d_in[10];
  const float* c3Wrel = (const float*)d_in[11];
  const float* c3brel = (const float*)d_in[12];
  const float* c3Wroot= (const float*)d_in[13];
  const float* Wlin   = (const float*)d_in[14];
  const float* blin   = (const float*)d_in[15];
  const float* Watt   = (const float*)d_in[16];
  const float* batt   = (const float*)d_in[17];
  const float* W1     = (const float*)d_in[18];
  const float* b1     = (const float*)d_in[19];
  const float* W2     = (const float*)d_in[20];
  const float* W3     = (const float*)d_in[21];
  const float* b3     = (const float*)d_in[22];
  float* out = (float*)d_out;

  char* base = (char*)d_ws;
  size_t off = 0;
  auto carve = [&](size_t bytes) -> void* {
    void* p = base + off;
    off += (bytes + 255) & ~(size_t)255;
    return p;
  };
  float* x1    = (float*)carve((size_t)NN*HH*4);
  float* x2b   = (float*)carve((size_t)NN*HH*4);
  float* xnew  = (float*)carve((size_t)NN*HH*4);
  float* xp    = (float*)carve((size_t)KC*HH*4);
  float* x3    = (float*)carve((size_t)KC*HH*4);
  float* meanb = (float*)carve((size_t)KC*HH*4);
  __half* xh   = (__half*)carve((size_t)NN*HH*2);
  __half* x1h  = (__half*)carve((size_t)NN*HH*2);
  __half* x2bh = (__half*)carve((size_t)NN*HH*2);
  __half* mbh  = (__half*)carve((size_t)NN*HH*2);
  __half* xph  = (__half*)carve((size_t)KC*HH*2);
  __half* x3h  = (__half*)carve((size_t)KC*HH*2);
  __half* Y1h  = (__half*)carve((size_t)NN*HH*2);
  __half* Y2h  = (__half*)carve((size_t)NN*HH*2);
  __half* WH   = (__half*)carve((size_t)4*HH*HH*2);
  unsigned* UP  = (unsigned*)carve((size_t)NN*UPW*4);   // 1.7 MB
  unsigned* PAT = (unsigned*)carve((size_t)KC*UPW*4);   // 1.4 MB
  float* xdot  = (float*)carve(NN*4);
  float* qdot  = (float*)carve(NN*4);
  float* mmaxA = (float*)carve(NN*4);
  float* ssumA = (float*)carve(NN*4);
  float* aA    = (float*)carve(NN*4);
  float* bA    = (float*)carve(NN*4);
  float* cA    = (float*)carve(NN*4);
  float* fitA  = (float*)carve(NN*4);
  float* fitk  = (float*)carve(KC*4);
  float* wA2   = (float*)carve((HH+1)*4);
  float* wD    = (float*)carve((size_t)E2*4);
  float* diag2 = (float*)carve(NN*4);
  int* rowD = (int*)carve((NN+1)*4);
  int* rowS = (int*)carve((NN+1)*4);
  int* cntD = (int*)carve(NN*4);
  int* cntS = (int*)carve(NN*4);
  int* curD = (int*)carve(NN*4);
  int* curS = (int*)carve(NN*4);
  int* colD = (int*)carve((size_t)E2*4);
  int* dstS = (int*)carve((size_t)E2*4);
  int* mapSD= (int*)carve((size_t)E2*4);
  int2* kwS = (int2*)carve((size_t)E2*8);
  int* perm = (int*)carve(KC*4);
  int* kcol = (int*)carve(NN*4);
  int* degN = (int*)carve((size_t)UPW*32*4);

  k_zero_init<<<NN/256, 256, 0, stream>>>(cntD, cntS, out);
  k_count<<<(E2+255)/256, 256, 0, stream>>>(ei, cntD, cntS);
  k_scan<<<1, 1024, 0, stream>>>(cntD, cntS, rowD, rowS, curD, curS);
  k_scatter<<<(E2+255)/256, 256, 0, stream>>>(ei, curD, curS, colD, dstS, mapSD);
  k_prep<<<2048 + 256 + 1, 256, 0, stream>>>(x, c0Wrel, c0Wroot, c1Wrel, c1Wroot,
                                             Wlin, blin, Watt, xh, WH, wA2);

  // conv0 (MFMA linear; colmean fused)
  k_edge_meanH<<<NN, 128, 0, stream>>>(xh, rowD, colD, mbh);
  k_linM<<<NN/16, 256, 0, stream>>>(mbh, xh, WH, 0, c0brel, x1, x1h, out + 0,
                                    nullptr, nullptr);

  // conv1 (fused xdot)
  k_edge_meanH<<<NN, 128, 0, stream>>>(x1h, rowD, colD, mbh);
  k_linM<<<NN/16, 256, 0, stream>>>(mbh, x1h, WH, 32768, c1brel, x2b, x2bh, out + 128,
                                    Watt, xdot);

  // ASAP pool (f16 gathers; fused LEConv partials + diag2)
  k_pool<<<NN, 128, 0, stream>>>(x2bh, rowD, colD, xdot, wA2, batt,
                                 W1, b1, W2, W3, b3,
                                 qdot, mmaxA, ssumA, xnew, wD, aA, bA, cA, diag2);
  k_fit<<<NN, 128, 0, stream>>>(rowD, colD, aA, bA, cA, fitA);
  k_sel<<<1, 1024, 0, stream>>>(fitA, perm, fitk, kcol);
  k_wS<<<(E2+255)/256, 256, 0, stream>>>(mapSD, dstS, kcol, wD, kwS);

  // conv2 via sparse chain: meanb = (S^T A^T S xp - diag2*xp) / deg
  k_xpt<<<(KC*HH+255)/256, 256, 0, stream>>>(xnew, perm, fitk, xp, xph);
  k_y1<<<NN, 128, 0, stream>>>(rowS, kwS, xph, Y1h, UP, 1);
  k_degp<<<KC, 128, 0, stream>>>(rowD, colD, perm, UP, PAT);
  k_degc<<<UPW, 256, 0, stream>>>(PAT, degN);
  k_y2<<<NN, 128, 0, stream>>>(rowD, colD, Y1h, Y2h);
  k_z<<<KC, 128, 0, stream>>>(rowD, colD, wD, perm, Y2h, xp, diag2, degN, meanb);
  k_lin2<<<(KC+15)/16, 256, 0, stream>>>(meanb, xp, c2Wrel, c2brel, c2Wroot,
                                         x3, x3h, KC, out + 256);

  // conv3 via sparse chain (deg/diag2 reused)
  k_y1<<<NN, 128, 0, stream>>>(rowS, kwS, x3h, Y1h, UP, 0);
  k_y2<<<NN, 128, 0, stream>>>(rowD, colD, Y1h, Y2h);
  k_z<<<KC, 128, 0, stream>>>(rowD, colD, wD, perm, Y2h, x3, diag2, degN, meanb);
  k_lin2<<<(KC+15)/16, 256, 0, stream>>>(meanb, x3, c3Wrel, c3brel, c3Wroot,
                                         nullptr, nullptr, KC, out + 384);
}

// Round 18
// 283.857 us; speedup vs baseline: 1.3151x; 1.0881x over previous
//
#include <hip/hip_runtime.h>
#include <hip/hip_fp16.h>
#include <math.h>

namespace {

constexpr int NN = 4096;
constexpr int EE = 131072;
constexpr int E2 = EE + NN;      // 135168 pool edges (orig + self loops)
constexpr int HH = 128;
constexpr int KC = 3277;         // ceil(0.8*4096)
constexpr int UPW = 104;         // bitmap words per row (104*32 = 3328 >= KC)

typedef _Float16 f16x8 __attribute__((ext_vector_type(8)));
typedef float f32x4 __attribute__((ext_vector_type(4)));

__device__ __forceinline__ float lrelu02(float x){ return x > 0.f ? x : 0.2f * x; }

__device__ __forceinline__ float redSum128(float* red, int t, float v){
  red[t] = v; __syncthreads();
  #pragma unroll
  for (int s = 64; s > 0; s >>= 1){ if (t < s) red[t] += red[t + s]; __syncthreads(); }
  float r = red[0]; __syncthreads();
  return r;
}
__device__ __forceinline__ float redMax128(float* red, int t, float v){
  red[t] = v; __syncthreads();
  #pragma unroll
  for (int s = 64; s > 0; s >>= 1){ if (t < s) red[t] = fmaxf(red[t], red[t + s]); __syncthreads(); }
  float r = red[0]; __syncthreads();
  return r;
}

__global__ void k_zero_init(int* cntD, int* cntS, float* out){
  int i = blockIdx.x * blockDim.x + threadIdx.x;
  if (i < NN){ cntD[i] = 0; cntS[i] = 0; }
  if (i < 512) out[i] = 0.f;
}

__global__ void k_count(const int* __restrict__ ei, int* cntD, int* cntS){
  int e = blockIdx.x * blockDim.x + threadIdx.x;
  if (e >= E2) return;
  int u, v;
  if (e < EE){ u = ei[e]; v = ei[EE + e]; } else { u = e - EE; v = u; }
  atomicAdd(&cntD[v], 1);
  atomicAdd(&cntS[u], 1);
}

__global__ void k_scan(const int* cntD, const int* cntS, int* rowD, int* rowS, int* curD, int* curS){
  __shared__ int sc[1024];
  int t = threadIdx.x;
  for (int pass = 0; pass < 2; ++pass){
    const int* cnt = pass ? cntS : cntD;
    int* row = pass ? rowS : rowD;
    int* cur = pass ? curS : curD;
    int c0 = cnt[t*4+0], c1 = cnt[t*4+1], c2 = cnt[t*4+2], c3 = cnt[t*4+3];
    int tot = c0 + c1 + c2 + c3;
    sc[t] = tot; __syncthreads();
    for (int offs = 1; offs < 1024; offs <<= 1){
      int v = (t >= offs) ? sc[t - offs] : 0;
      __syncthreads();
      sc[t] += v;
      __syncthreads();
    }
    int excl = sc[t] - tot;
    int r0 = excl, r1 = r0 + c0, r2 = r1 + c1, r3 = r2 + c2;
    row[t*4+0] = r0; row[t*4+1] = r1; row[t*4+2] = r2; row[t*4+3] = r3;
    cur[t*4+0] = r0; cur[t*4+1] = r1; cur[t*4+2] = r2; cur[t*4+3] = r3;
    if (t == 1023) row[NN] = r3 + c3;
    __syncthreads();
  }
}

__global__ void k_scatter(const int* __restrict__ ei, int* curD, int* curS,
                          int* colD, int* dstS, int* mapSD){
  int e = blockIdx.x * blockDim.x + threadIdx.x;
  if (e >= E2) return;
  int u, v;
  if (e < EE){ u = ei[e]; v = ei[EE + e]; } else { u = e - EE; v = u; }
  int p = atomicAdd(&curD[v], 1); colD[p] = u;
  int q = atomicAdd(&curS[u], 1); dstS[q] = v; mapSD[q] = p;
}

// prep: xh = f16(x); WH = f16 weights [W0rel|W0root|W1rel|W1root]; wprep (last block).
__global__ void k_prep(const float* __restrict__ x,
                       const float* __restrict__ W0rel, const float* __restrict__ W0root,
                       const float* __restrict__ W1rel, const float* __restrict__ W1root,
                       const float* __restrict__ Wlin, const float* __restrict__ blin,
                       const float* __restrict__ Watt,
                       __half* __restrict__ xh, __half* __restrict__ WH, float* __restrict__ wA2){
  int b = blockIdx.x;
  if (b < 2048){
    int i = b*256 + threadIdx.x;
    xh[i] = __float2half(x[i]);
  } else if (b < 2048 + 256){
    int i = (b - 2048)*256 + threadIdx.x;
    int m = i >> 14, o = i & 16383;
    const float* src = (m == 0) ? W0rel : (m == 1) ? W0root : (m == 2) ? W1rel : W1root;
    WH[i] = __float2half(src[o]);
  } else {
    int c = threadIdx.x;
    if (c < 128){
      float s = 0.f;
      for (int hh = 0; hh < HH; ++hh) s += Watt[hh] * Wlin[hh*HH + c];
      wA2[c] = s;
      if (c == 0){
        float q = 0.f;
        for (int hh = 0; hh < HH; ++hh) q += blin[hh] * Watt[hh];
        wA2[HH] = q;
      }
    }
  }
}

// mean over in-neighbors, f16 input rows, f16 output (f32 accumulate).
__global__ void k_edge_meanH(const __half* __restrict__ xinh, const int* __restrict__ rowD,
                             const int* __restrict__ colD, __half* __restrict__ meanbh){
  int v = blockIdx.x, t = threadIdx.x;
  int beg = rowD[v], end = rowD[v+1];
  float acc = 0.f;
  int p = beg;
  for (; p + 8 <= end; p += 8){
    int u0 = colD[p],   u1 = colD[p+1], u2 = colD[p+2], u3 = colD[p+3];
    int u4 = colD[p+4], u5 = colD[p+5], u6 = colD[p+6], u7 = colD[p+7];
    float a0 = __half2float(xinh[(size_t)u0*HH + t]);
    float a1 = __half2float(xinh[(size_t)u1*HH + t]);
    float a2 = __half2float(xinh[(size_t)u2*HH + t]);
    float a3 = __half2float(xinh[(size_t)u3*HH + t]);
    float a4 = __half2float(xinh[(size_t)u4*HH + t]);
    float a5 = __half2float(xinh[(size_t)u5*HH + t]);
    float a6 = __half2float(xinh[(size_t)u6*HH + t]);
    float a7 = __half2float(xinh[(size_t)u7*HH + t]);
    if (u0 != v) acc += a0;
    if (u1 != v) acc += a1;
    if (u2 != v) acc += a2;
    if (u3 != v) acc += a3;
    if (u4 != v) acc += a4;
    if (u5 != v) acc += a5;
    if (u6 != v) acc += a6;
    if (u7 != v) acc += a7;
  }
  for (; p < end; ++p){ int u = colD[p]; if (u != v) acc += __half2float(xinh[(size_t)u*HH + t]); }
  float dg = (float)(end - beg - 1);
  meanbh[(size_t)v*HH + t] = __float2half(acc / fmaxf(dg, 1.f));
}

// MFMA GraphConv linear: xout = relu([meanbh|xinh] @ [Wrel|Wroot]^T + brel).
// Fused colmean; optional fused xdot (ASAP attention dot).
__global__ void k_linM(const __half* __restrict__ mh, const __half* __restrict__ xinh,
                       const __half* __restrict__ WHh, int woff,
                       const float* __restrict__ brel,
                       float* __restrict__ xout, __half* __restrict__ xouth,
                       float* __restrict__ cmout,
                       const float* __restrict__ WattFull, float* __restrict__ xdotp){
  __shared__ float sx[16][4];
  int t = threadIdx.x, lane = t & 63, w = t >> 6;
  int r0 = blockIdx.x * 16;
  int l15 = lane & 15, lk = (lane >> 4) * 8;
  const _Float16* WH = (const _Float16*)WHh;
  const _Float16* Am = (const _Float16*)mh + (size_t)(r0 + l15)*HH + lk;
  const _Float16* Ax = (const _Float16*)xinh + (size_t)(r0 + l15)*HH + lk;
  const _Float16* Brel0 = WH + woff + (size_t)(w*32 + l15)*HH + lk;
  const _Float16* Brel1 = Brel0 + (size_t)16*HH;
  const _Float16* Broot0 = Brel0 + 16384;
  const _Float16* Broot1 = Brel1 + 16384;
  f32x4 acc0 = (f32x4)0.f, acc1 = (f32x4)0.f;
  #pragma unroll
  for (int kk = 0; kk < HH; kk += 32){
    f16x8 a = *(const f16x8*)(Am + kk);
    f16x8 b0 = *(const f16x8*)(Brel0 + kk);
    f16x8 b1 = *(const f16x8*)(Brel1 + kk);
    acc0 = __builtin_amdgcn_mfma_f32_16x16x32_f16(a, b0, acc0, 0, 0, 0);
    acc1 = __builtin_amdgcn_mfma_f32_16x16x32_f16(a, b1, acc1, 0, 0, 0);
  }
  #pragma unroll
  for (int kk = 0; kk < HH; kk += 32){
    f16x8 a = *(const f16x8*)(Ax + kk);
    f16x8 b0 = *(const f16x8*)(Broot0 + kk);
    f16x8 b1 = *(const f16x8*)(Broot1 + kk);
    acc0 = __builtin_amdgcn_mfma_f32_16x16x32_f16(a, b0, acc0, 0, 0, 0);
    acc1 = __builtin_amdgcn_mfma_f32_16x16x32_f16(a, b1, acc1, 0, 0, 0);
  }
  int rbase = (lane >> 4) * 4;
  int h0 = w*32 + l15, h1 = h0 + 16;
  float bb0 = brel[h0], bb1 = brel[h1];
  float wt0 = 0.f, wt1 = 0.f;
  if (xdotp){ wt0 = WattFull[HH + h0]; wt1 = WattFull[HH + h1]; }
  float cs0 = 0.f, cs1 = 0.f;
  #pragma unroll
  for (int r = 0; r < 4; ++r){
    int row = r0 + rbase + r;
    float v0 = fmaxf(acc0[r] + bb0, 0.f);
    float v1 = fmaxf(acc1[r] + bb1, 0.f);
    xout[(size_t)row*HH + h0] = v0;
    xout[(size_t)row*HH + h1] = v1;
    xouth[(size_t)row*HH + h0] = __float2half(v0);
    xouth[(size_t)row*HH + h1] = __float2half(v1);
    cs0 += v0; cs1 += v1;
    if (xdotp){
      float ds = v0*wt0 + v1*wt1;
      ds += __shfl_xor(ds, 1); ds += __shfl_xor(ds, 2);
      ds += __shfl_xor(ds, 4); ds += __shfl_xor(ds, 8);
      if (l15 == 0) sx[rbase + r][w] = ds;
    }
  }
  cs0 += __shfl_xor(cs0, 16); cs0 += __shfl_xor(cs0, 32);
  cs1 += __shfl_xor(cs1, 16); cs1 += __shfl_xor(cs1, 32);
  if (lane < 16){
    atomicAdd(&cmout[h0], cs0 / (float)NN);
    atomicAdd(&cmout[h1], cs1 / (float)NN);
  }
  if (xdotp){
    __syncthreads();
    if (t < 16) xdotp[r0 + t] = sx[t][0] + sx[t][1] + sx[t][2] + sx[t][3];
  }
}

// dense-conv linear from precomputed mean: xout = relu(meanb@Wrel^T + brel + xin@Wroot^T).
__global__ void k_lin2(const float* __restrict__ meanb, const float* __restrict__ xin,
                       const float* __restrict__ Wrel, const float* __restrict__ brel,
                       const float* __restrict__ Wroot,
                       float* __restrict__ xout, __half* __restrict__ xouth, int rows,
                       float* __restrict__ cmout){
  __shared__ float ms[16][HH];
  __shared__ float xs[16][HH];
  __shared__ float cmred[256];
  int tid = threadIdx.x;
  int r0 = blockIdx.x * 16;
  for (int l = tid; l < 16*HH; l += 256){
    int r = l >> 7, c = l & 127; int gr = r0 + r;
    float mv = 0.f, xv = 0.f;
    if (gr < rows){
      size_t idx = (size_t)gr*HH + c;
      mv = meanb[idx];
      xv = xin[idx];
    }
    ms[r][c] = mv; xs[r][c] = xv;
  }
  __syncthreads();
  int h = tid & 127, hgrp = tid >> 7;
  float acc[8] = {0.f,0.f,0.f,0.f,0.f,0.f,0.f,0.f};
  for (int c = 0; c < HH; ++c){
    float wr = Wrel[h*HH + c], wo = Wroot[h*HH + c];
    #pragma unroll
    for (int r = 0; r < 8; ++r) acc[r] += ms[hgrp*8 + r][c]*wr + xs[hgrp*8 + r][c]*wo;
  }
  float bb = brel[h];
  float csum = 0.f;
  #pragma unroll
  for (int r = 0; r < 8; ++r){
    int gr = r0 + hgrp*8 + r;
    if (gr < rows){
      float val = fmaxf(acc[r] + bb, 0.f);
      if (xout) xout[(size_t)gr*HH + h] = val;
      if (xouth) xouth[(size_t)gr*HH + h] = __float2half(val);
      csum += val;
    }
  }
  cmred[tid] = csum; __syncthreads();
  if (tid < 128) atomicAdd(&cmout[h], (cmred[tid] + cmred[tid + 128]) / (float)rows);
}

// per dst node v (f16 gathers, f32 accumulate): xq max -> qdot; edge-softmax stats;
// x_new; wD; fused LEConv partials; fused diag2[v] = sum_n S[n,v]^2.
__global__ void k_pool(const __half* __restrict__ x2h, const int* __restrict__ rowD, const int* __restrict__ colD,
                       const float* __restrict__ xdotA, const float* __restrict__ wA2, const float* __restrict__ battp,
                       const float* __restrict__ W1, const float* __restrict__ b1,
                       const float* __restrict__ W2, const float* __restrict__ W3, const float* __restrict__ b3,
                       float* qdotA, float* mA, float* sA, float* __restrict__ xnew, float* __restrict__ wD,
                       float* aA, float* bA, float* cA, float* __restrict__ diag2){
  __shared__ float red[128];
  __shared__ float wmem[128];
  __shared__ int uc[128];
  __shared__ int srcL[1024];
  __shared__ float wL[1024];
  int v = blockIdx.x, t = threadIdx.x;
  int beg = rowD[v], end = rowD[v+1];
  float batt = battp[0];
  float mx = -3.402823466e38f;
  int p = beg;
  for (; p + 4 <= end; p += 4){
    float a0 = __half2float(x2h[(size_t)colD[p]*HH + t]);
    float a1 = __half2float(x2h[(size_t)colD[p+1]*HH + t]);
    float a2 = __half2float(x2h[(size_t)colD[p+2]*HH + t]);
    float a3 = __half2float(x2h[(size_t)colD[p+3]*HH + t]);
    mx = fmaxf(fmaxf(fmaxf(fmaxf(mx, a0), a1), a2), a3);
  }
  for (; p < end; ++p) mx = fmaxf(mx, __half2float(x2h[(size_t)colD[p]*HH + t]));
  float qd = redSum128(red, t, mx * wA2[t]) + wA2[HH];
  float lm = -3.402823466e38f;
  for (p = beg + t; p < end; p += 128) lm = fmaxf(lm, lrelu02(qd + xdotA[colD[p]] + batt));
  float mm = redMax128(red, t, lm);
  float ls = 0.f;
  for (p = beg + t; p < end; p += 128) ls += expf(lrelu02(qd + xdotA[colD[p]] + batt) - mm);
  float ss = redSum128(red, t, ls);
  float acc = 0.f;
  for (int basep = beg; basep < end; basep += 128){
    int cnt = min(128, end - basep);
    if (t < cnt){
      int u = colD[basep + t];
      uc[t] = u;
      float w = expf(lrelu02(qd + xdotA[u] + batt) - mm) / ss;
      wmem[t] = w;
      wD[basep + t] = w;
      int o = basep - beg + t;
      if (o < 1024){ srcL[o] = u; wL[o] = w; }
    }
    __syncthreads();
    int i = 0;
    for (; i + 4 <= cnt; i += 4){
      float a0 = __half2float(x2h[(size_t)uc[i]*HH + t]);
      float a1 = __half2float(x2h[(size_t)uc[i+1]*HH + t]);
      float a2 = __half2float(x2h[(size_t)uc[i+2]*HH + t]);
      float a3 = __half2float(x2h[(size_t)uc[i+3]*HH + t]);
      acc += wmem[i]*a0 + wmem[i+1]*a1 + wmem[i+2]*a2 + wmem[i+3]*a3;
    }
    for (; i < cnt; ++i) acc += wmem[i] * __half2float(x2h[(size_t)uc[i]*HH + t]);
    __syncthreads();
  }
  xnew[(size_t)v*HH + t] = acc;
  float s1 = redSum128(red, t, acc * W1[t]);
  float s2 = redSum128(red, t, acc * W2[t]);
  float s3 = redSum128(red, t, acc * W3[t]);
  int d = end - beg; if (d > 1024) d = 1024;
  float dpart = 0.f;
  for (int pp = t; pp < d; pp += 128){
    int s = srcL[pp];
    float sp = 0.f;
    for (int q = 0; q < d; ++q) if (srcL[q] == s) sp += wL[q];
    dpart += wL[pp] * sp;
  }
  float d2 = redSum128(red, t, dpart);
  if (t == 0){
    qdotA[v] = qd; mA[v] = mm; sA[v] = ss;
    aA[v] = s1 + b1[0]; bA[v] = s2; cA[v] = s3 + b3[0];
    diag2[v] = d2;
  }
}

__global__ void k_fit(const int* __restrict__ rowD, const int* __restrict__ colD,
                      const float* __restrict__ aA, const float* __restrict__ bA, const float* __restrict__ cA,
                      float* __restrict__ fitA){
  __shared__ float red[128];
  int v = blockIdx.x, t = threadIdx.x;
  int beg = rowD[v], end = rowD[v+1];
  float la = 0.f;
  for (int p = beg + t; p < end; p += 128) la += aA[colD[p]];
  float s = redSum128(red, t, la);
  if (t == 0){
    float g = s - (float)(end - beg) * bA[v] + cA[v];
    fitA[v] = 1.f / (1.f + expf(-g));
  }
}

// Exact top-K SET selection via radix-select (1 block, 1024 threads).
// Bucket choice via parallel 256-wide suffix-sum (was serial t==0 scan: 44us -> ~5us).
__global__ void k_sel(const float* __restrict__ fitA, int* perm, float* fitk, int* kcol){
  __shared__ unsigned keys[NN];
  __shared__ int hist[256];
  __shared__ int suf[256];
  __shared__ int sc[1024];
  __shared__ int bc[2];
  int t = threadIdx.x;
  #pragma unroll
  for (int r = 0; r < 4; ++r){
    int i = t + r*1024;
    unsigned b = __float_as_uint(fitA[i]);
    keys[i] = (b & 0x80000000u) ? ~b : (b ^ 0x80000000u);
  }
  __syncthreads();
  unsigned prefix = 0;
  int kneed = KC;
  #pragma unroll
  for (int round = 0; round < 4; ++round){
    int shift = 24 - round*8;
    unsigned pmask = (round == 0) ? 0u : (0xFFFFFFFFu << (shift + 8));
    if (t < 256) hist[t] = 0;
    __syncthreads();
    #pragma unroll
    for (int r = 0; r < 4; ++r){
      unsigned kv = keys[t + r*1024];
      if ((kv & pmask) == prefix)
        atomicAdd(&hist[(kv >> shift) & 0xFF], 1);
    }
    __syncthreads();
    // suffix sum: suf[b] = sum_{b' >= b} hist[b']
    if (t < 256) suf[t] = hist[t];
    __syncthreads();
    for (int offs = 1; offs < 256; offs <<= 1){
      int val = (t < 256 && t + offs < 256) ? suf[t + offs] : 0;
      __syncthreads();
      if (t < 256) suf[t] += val;
      __syncthreads();
    }
    // chosen = largest b with suf[b] >= kneed; rem = kneed - suf[b+1]
    if (t < 256){
      int above = (t == 255) ? 0 : suf[t + 1];
      if (suf[t] >= kneed && above < kneed){ bc[0] = t; bc[1] = kneed - above; }
    }
    __syncthreads();
    prefix |= ((unsigned)bc[0]) << shift;
    kneed = bc[1];
    __syncthreads();
  }
  unsigned T = prefix;
  int need_eq = kneed;
  int cnt[4]; int tot = 0;
  #pragma unroll
  for (int r = 0; r < 4; ++r){
    unsigned kv = keys[t*4 + r];
    int g = (kv > T) ? 1 : 0;
    int e = (kv == T) ? 1 : 0;
    cnt[r] = (g << 16) | e;
    tot += cnt[r];
  }
  sc[t] = tot; __syncthreads();
  for (int offs = 1; offs < 1024; offs <<= 1){
    int v = (t >= offs) ? sc[t - offs] : 0;
    __syncthreads();
    sc[t] += v;
    __syncthreads();
  }
  int gtot = sc[1023] >> 16;
  int run = sc[t] - tot;
  #pragma unroll
  for (int r = 0; r < 4; ++r){
    int i = t*4 + r;
    int g = cnt[r] >> 16, e = cnt[r] & 0xFFFF;
    int gpos = run >> 16, epos = run & 0xFFFF;
    int pos = -1;
    if (g) pos = gpos;
    else if (e && epos < need_eq) pos = gtot + epos;
    if (pos >= 0){ perm[pos] = i; fitk[pos] = fitA[i]; kcol[i] = pos; }
    else kcol[i] = -1;
    run += cnt[r];
  }
}

// xp[j,:] = xnew[perm[j],:]*fitk[j] (f32 + f16 copies)
__global__ void k_xpt(const float* __restrict__ xnew, const int* __restrict__ perm,
                      const float* __restrict__ fitk, float* __restrict__ xp,
                      __half* __restrict__ xph){
  int idx = blockIdx.x * 256 + threadIdx.x;
  if (idx >= KC*HH) return;
  int j = idx >> 7;
  float v = xnew[(size_t)perm[j]*HH + (idx & 127)] * fitk[j];
  xp[idx] = v;
  xph[idx] = __float2half(v);
}

// src-ordered packed (kcol, w) per pool edge
__global__ void k_wS(const int* __restrict__ mapSD, const int* __restrict__ dstS,
                     const int* __restrict__ kcol, const float* __restrict__ wD,
                     int2* __restrict__ kwS){
  int q = blockIdx.x * blockDim.x + threadIdx.x;
  if (q >= E2) return;
  float w = wD[mapSD[q]];
  int k = kcol[dstS[q]];
  kwS[q] = make_int2(k, __float_as_int(w));
}

// Y1[n,:] = (S @ X)[n,:] over n's out pool edges; optional UP bitmap emission.
__global__ void k_y1(const int* __restrict__ rowS, const int2* __restrict__ kwS,
                     const __half* __restrict__ Xh, __half* __restrict__ Y1h,
                     unsigned* __restrict__ UP, int emitUP){
  __shared__ int kArr[128];
  __shared__ float wArr[128];
  __shared__ unsigned upw[UPW];
  int n = blockIdx.x, t = threadIdx.x;
  if (emitUP && t < UPW) upw[t] = 0u;
  int beg = rowS[n], end = rowS[n+1];
  float acc = 0.f;
  for (int basep = beg; basep < end; basep += 128){
    int cnt = min(128, end - basep);
    if (t < cnt){
      int2 kw = kwS[basep + t];
      kArr[t] = kw.x;
      wArr[t] = __int_as_float(kw.y);
      if (emitUP && kw.x >= 0) atomicOr(&upw[kw.x >> 5], 1u << (kw.x & 31));
    }
    __syncthreads();
    for (int i = 0; i < cnt; ++i){
      int k = kArr[i];
      if (k >= 0) acc += wArr[i] * __half2float(Xh[(size_t)k*HH + t]);
    }
    __syncthreads();
  }
  Y1h[(size_t)n*HH + t] = __float2half(acc);
  if (emitUP){
    __syncthreads();
    if (t < UPW) UP[(size_t)n*UPW + t] = upw[t];
  }
}

// Y2[m,:] = sum over in-edge instances of Y1[src,:]
__global__ void k_y2(const int* __restrict__ rowD, const int* __restrict__ colD,
                     const __half* __restrict__ Y1h, __half* __restrict__ Y2h){
  int m = blockIdx.x, t = threadIdx.x;
  int beg = rowD[m], end = rowD[m+1];
  float acc = 0.f;
  int p = beg;
  for (; p + 8 <= end; p += 8){
    float a0 = __half2float(Y1h[(size_t)colD[p]*HH + t]);
    float a1 = __half2float(Y1h[(size_t)colD[p+1]*HH + t]);
    float a2 = __half2float(Y1h[(size_t)colD[p+2]*HH + t]);
    float a3 = __half2float(Y1h[(size_t)colD[p+3]*HH + t]);
    float a4 = __half2float(Y1h[(size_t)colD[p+4]*HH + t]);
    float a5 = __half2float(Y1h[(size_t)colD[p+5]*HH + t]);
    float a6 = __half2float(Y1h[(size_t)colD[p+6]*HH + t]);
    float a7 = __half2float(Y1h[(size_t)colD[p+7]*HH + t]);
    acc += ((a0 + a1) + (a2 + a3)) + ((a4 + a5) + (a6 + a7));
  }
  for (; p < end; ++p) acc += __half2float(Y1h[(size_t)colD[p]*HH + t]);
  Y2h[(size_t)m*HH + t] = __float2half(acc);
}

// Z[k,:] = sum over in-edges of v_k of w * Y2[src,:]; meanb = (Z - diag2*X)/max(deg,1)
__global__ void k_z(const int* __restrict__ rowD, const int* __restrict__ colD,
                    const float* __restrict__ wD, const int* __restrict__ perm,
                    const __half* __restrict__ Y2h, const float* __restrict__ Xf,
                    const float* __restrict__ diag2, const int* __restrict__ degN,
                    float* __restrict__ meanb){
  __shared__ int uc[128];
  __shared__ float wm[128];
  int k = blockIdx.x, t = threadIdx.x;
  int v = perm[k];
  int beg = rowD[v], end = rowD[v+1];
  float acc = 0.f;
  for (int basep = beg; basep < end; basep += 128){
    int cnt = min(128, end - basep);
    if (t < cnt){ uc[t] = colD[basep + t]; wm[t] = wD[basep + t]; }
    __syncthreads();
    int i = 0;
    for (; i + 4 <= cnt; i += 4){
      float a0 = __half2float(Y2h[(size_t)uc[i]*HH + t]);
      float a1 = __half2float(Y2h[(size_t)uc[i+1]*HH + t]);
      float a2 = __half2float(Y2h[(size_t)uc[i+2]*HH + t]);
      float a3 = __half2float(Y2h[(size_t)uc[i+3]*HH + t]);
      acc += wm[i]*a0 + wm[i+1]*a1 + wm[i+2]*a2 + wm[i+3]*a3;
    }
    for (; i < cnt; ++i) acc += wm[i] * __half2float(Y2h[(size_t)uc[i]*HH + t]);
    __syncthreads();
  }
  float d = fmaxf((float)degN[k], 1.f);
  meanb[(size_t)k*HH + t] = (acc - diag2[v] * Xf[(size_t)k*HH + t]) / d;
}

// PAT[k1,:] = OR over in-neighbors n of v_{k1} of UP[n,:]
__global__ void k_degp(const int* __restrict__ rowD, const int* __restrict__ colD,
                       const int* __restrict__ perm, const unsigned* __restrict__ UP,
                       unsigned* __restrict__ PAT){
  int k1 = blockIdx.x, t = threadIdx.x;
  if (t >= UPW) return;
  int v = perm[k1];
  int beg = rowD[v], end = rowD[v+1];
  unsigned pw = 0u;
  for (int p = beg; p < end; ++p) pw |= UP[(size_t)colD[p]*UPW + t];
  PAT[(size_t)k1*UPW + t] = pw;
}

// degN[i] = (# rows k1 with PAT bit i set) - 1
__global__ void k_degc(const unsigned* __restrict__ PAT, int* __restrict__ degN){
  __shared__ int red[256];
  int w = blockIdx.x, t = threadIdx.x;
  int c[32];
  #pragma unroll
  for (int j = 0; j < 32; ++j) c[j] = 0;
  for (int r = t; r < KC; r += 256){
    unsigned b = PAT[(size_t)r*UPW + w];
    #pragma unroll
    for (int j = 0; j < 32; ++j) c[j] += (b >> j) & 1;
  }
  for (int j = 0; j < 32; ++j){
    red[t] = c[j]; __syncthreads();
    #pragma unroll
    for (int s = 128; s > 0; s >>= 1){ if (t < s) red[t] += red[t + s]; __syncthreads(); }
    if (t == 0) degN[w*32 + j] = red[0] - 1;
    __syncthreads();
  }
}

} // namespace

extern "C" void kernel_launch(void* const* d_in, const int* in_sizes, int n_in,
                              void* d_out, int out_size, void* d_ws, size_t ws_size,
                              hipStream_t stream){
  (void)in_sizes; (void)n_in; (void)out_size; (void)ws_size;
  const float* x      = (const float*)d_in[0];
  const int*   ei     = (const int*)d_in[1];
  const float* c0Wrel = (const float*)d_in[2];
  const float* c0brel = (const float*)d_in[3];
  const float* c0Wroot= (const float*)d_in[4];
  const float* c1Wrel = (const float*)d_in[5];
  const float* c1brel = (const float*)d_in[6];
  const float* c1Wroot= (const float*)d_in[7];
  const float* c2Wrel = (const float*)d_in[8];
  const float* c2brel = (const float*)d_in[9];
  const float* c2Wroot= (const float*)d_in[10];
  const float* c3Wrel = (const float*)d_in[11];
  const float* c3brel = (const float*)d_in[12];
  const float* c3Wroot= (const float*)d_in[13];
  const float* Wlin   = (const float*)d_in[14];
  const float* blin   = (const float*)d_in[15];
  const float* Watt   = (const float*)d_in[16];
  const float* batt   = (const float*)d_in[17];
  const float* W1     = (const float*)d_in[18];
  const float* b1     = (const float*)d_in[19];
  const float* W2     = (const float*)d_in[20];
  const float* W3     = (const float*)d_in[21];
  const float* b3     = (const float*)d_in[22];
  float* out = (float*)d_out;

  char* base = (char*)d_ws;
  size_t off = 0;
  auto carve = [&](size_t bytes) -> void* {
    void* p = base + off;
    off += (bytes + 255) & ~(size_t)255;
    return p;
  };
  float* x1    = (float*)carve((size_t)NN*HH*4);
  float* x2b   = (float*)carve((size_t)NN*HH*4);
  float* xnew  = (float*)carve((size_t)NN*HH*4);
  float* xp    = (float*)carve((size_t)KC*HH*4);
  float* x3    = (float*)carve((size_t)KC*HH*4);
  float* meanb = (float*)carve((size_t)KC*HH*4);
  __half* xh   = (__half*)carve((size_t)NN*HH*2);
  __half* x1h  = (__half*)carve((size_t)NN*HH*2);
  __half* x2bh = (__half*)carve((size_t)NN*HH*2);
  __half* mbh  = (__half*)carve((size_t)NN*HH*2);
  __half* xph  = (__half*)carve((size_t)KC*HH*2);
  __half* x3h  = (__half*)carve((size_t)KC*HH*2);
  __half* Y1h  = (__half*)carve((size_t)NN*HH*2);
  __half* Y2h  = (__half*)carve((size_t)NN*HH*2);
  __half* WH   = (__half*)carve((size_t)4*HH*HH*2);
  unsigned* UP  = (unsigned*)carve((size_t)NN*UPW*4);
  unsigned* PAT = (unsigned*)carve((size_t)KC*UPW*4);
  float* xdot  = (float*)carve(NN*4);
  float* qdot  = (float*)carve(NN*4);
  float* mmaxA = (float*)carve(NN*4);
  float* ssumA = (float*)carve(NN*4);
  float* aA    = (float*)carve(NN*4);
  float* bA    = (float*)carve(NN*4);
  float* cA    = (float*)carve(NN*4);
  float* fitA  = (float*)carve(NN*4);
  float* fitk  = (float*)carve(KC*4);
  float* wA2   = (float*)carve((HH+1)*4);
  float* wD    = (float*)carve((size_t)E2*4);
  float* diag2 = (float*)carve(NN*4);
  int* rowD = (int*)carve((NN+1)*4);
  int* rowS = (int*)carve((NN+1)*4);
  int* cntD = (int*)carve(NN*4);
  int* cntS = (int*)carve(NN*4);
  int* curD = (int*)carve(NN*4);
  int* curS = (int*)carve(NN*4);
  int* colD = (int*)carve((size_t)E2*4);
  int* dstS = (int*)carve((size_t)E2*4);
  int* mapSD= (int*)carve((size_t)E2*4);
  int2* kwS = (int2*)carve((size_t)E2*8);
  int* perm = (int*)carve(KC*4);
  int* kcol = (int*)carve(NN*4);
  int* degN = (int*)carve((size_t)UPW*32*4);

  k_zero_init<<<NN/256, 256, 0, stream>>>(cntD, cntS, out);
  k_count<<<(E2+255)/256, 256, 0, stream>>>(ei, cntD, cntS);
  k_scan<<<1, 1024, 0, stream>>>(cntD, cntS, rowD, rowS, curD, curS);
  k_scatter<<<(E2+255)/256, 256, 0, stream>>>(ei, curD, curS, colD, dstS, mapSD);
  k_prep<<<2048 + 256 + 1, 256, 0, stream>>>(x, c0Wrel, c0Wroot, c1Wrel, c1Wroot,
                                             Wlin, blin, Watt, xh, WH, wA2);

  // conv0 (MFMA linear; colmean fused)
  k_edge_meanH<<<NN, 128, 0, stream>>>(xh, rowD, colD, mbh);
  k_linM<<<NN/16, 256, 0, stream>>>(mbh, xh, WH, 0, c0brel, x1, x1h, out + 0,
                                    nullptr, nullptr);

  // conv1 (fused xdot)
  k_edge_meanH<<<NN, 128, 0, stream>>>(x1h, rowD, colD, mbh);
  k_linM<<<NN/16, 256, 0, stream>>>(mbh, x1h, WH, 32768, c1brel, x2b, x2bh, out + 128,
                                    Watt, xdot);

  // ASAP pool (f16 gathers; fused LEConv partials + diag2)
  k_pool<<<NN, 128, 0, stream>>>(x2bh, rowD, colD, xdot, wA2, batt,
                                 W1, b1, W2, W3, b3,
                                 qdot, mmaxA, ssumA, xnew, wD, aA, bA, cA, diag2);
  k_fit<<<NN, 128, 0, stream>>>(rowD, colD, aA, bA, cA, fitA);
  k_sel<<<1, 1024, 0, stream>>>(fitA, perm, fitk, kcol);
  k_wS<<<(E2+255)/256, 256, 0, stream>>>(mapSD, dstS, kcol, wD, kwS);

  // conv2 via sparse chain: meanb = (S^T A^T S xp - diag2*xp) / deg
  k_xpt<<<(KC*HH+255)/256, 256, 0, stream>>>(xnew, perm, fitk, xp, xph);
  k_y1<<<NN, 128, 0, stream>>>(rowS, kwS, xph, Y1h, UP, 1);
  k_degp<<<KC, 128, 0, stream>>>(rowD, colD, perm, UP, PAT);
  k_degc<<<UPW, 256, 0, stream>>>(PAT, degN);
  k_y2<<<NN, 128, 0, stream>>>(rowD, colD, Y1h, Y2h);
  k_z<<<KC, 128, 0, stream>>>(rowD, colD, wD, perm, Y2h, xp, diag2, degN, meanb);
  k_lin2<<<(KC+15)/16, 256, 0, stream>>>(meanb, xp, c2Wrel, c2brel, c2Wroot,
                                         x3, x3h, KC, out + 256);

  // conv3 via sparse chain (deg/diag2 reused)
  k_y1<<<NN, 128, 0, stream>>>(rowS, kwS, x3h, Y1h, UP, 0);
  k_y2<<<NN, 128, 0, stream>>>(rowD, colD, Y1h, Y2h);
  k_z<<<KC, 128, 0, stream>>>(rowD, colD, wD, perm, Y2h, x3, diag2, degN, meanb);
  k_lin2<<<(KC+15)/16, 256, 0, stream>>>(meanb, x3, c3Wrel, c3brel, c3Wroot,
                                         nullptr, nullptr, KC, out + 384);
}

// Round 19
// 269.730 us; speedup vs baseline: 1.3840x; 1.0524x over previous
//
#include <hip/hip_runtime.h>
#include <hip/hip_fp16.h>
#include <math.h>

namespace {

constexpr int NN = 4096;
constexpr int EE = 131072;
constexpr int E2 = EE + NN;      // 135168 pool edges (orig + self loops)
constexpr int HH = 128;
constexpr int KC = 3277;         // ceil(0.8*4096)
constexpr int UPW = 104;         // bitmap words per row (104*32 = 3328 >= KC)
constexpr int WSB = (E2 + 255) / 256;      // 528 blocks for wS part of k_post
constexpr int XPB = (KC*HH + 255) / 256;   // 1639 blocks for xpt part

typedef _Float16 f16x8 __attribute__((ext_vector_type(8)));
typedef float f32x4 __attribute__((ext_vector_type(4)));

__device__ __forceinline__ float lrelu02(float x){ return x > 0.f ? x : 0.2f * x; }

__device__ __forceinline__ float redSum128(float* red, int t, float v){
  red[t] = v; __syncthreads();
  #pragma unroll
  for (int s = 64; s > 0; s >>= 1){ if (t < s) red[t] += red[t + s]; __syncthreads(); }
  float r = red[0]; __syncthreads();
  return r;
}
__device__ __forceinline__ float redMax128(float* red, int t, float v){
  red[t] = v; __syncthreads();
  #pragma unroll
  for (int s = 64; s > 0; s >>= 1){ if (t < s) red[t] = fmaxf(red[t], red[t + s]); __syncthreads(); }
  float r = red[0]; __syncthreads();
  return r;
}

__global__ void k_count(const int* __restrict__ ei, int* cntD, int* cntS){
  int e = blockIdx.x * blockDim.x + threadIdx.x;
  if (e >= E2) return;
  int u, v;
  if (e < EE){ u = ei[e]; v = ei[EE + e]; } else { u = e - EE; v = u; }
  atomicAdd(&cntD[v], 1);
  atomicAdd(&cntS[u], 1);
}

// dual CSR scan via packed u64 wave-shuffle scan (2 barriers total)
__global__ void k_scan(const int* cntD, const int* cntS, int* rowD, int* rowS, int* curD, int* curS){
  __shared__ unsigned long long wsum[16];
  int t = threadIdx.x, lane = t & 63, wid = t >> 6;
  int d0 = cntD[t*4], d1 = cntD[t*4+1], d2 = cntD[t*4+2], d3 = cntD[t*4+3];
  int s0 = cntS[t*4], s1 = cntS[t*4+1], s2 = cntS[t*4+2], s3 = cntS[t*4+3];
  int dT = d0 + d1 + d2 + d3, sT = s0 + s1 + s2 + s3;
  unsigned long long tot = ((unsigned long long)(unsigned)dT << 32) | (unsigned)sT;
  unsigned long long x = tot;
  #pragma unroll
  for (int offs = 1; offs < 64; offs <<= 1){
    unsigned long long v = __shfl_up(x, offs);
    if (lane >= offs) x += v;
  }
  if (lane == 63) wsum[wid] = x;
  __syncthreads();
  if (t == 0){
    unsigned long long acc = 0;
    for (int i = 0; i < 16; ++i){ unsigned long long tmp = wsum[i]; wsum[i] = acc; acc += tmp; }
  }
  __syncthreads();
  unsigned long long excl = x - tot + wsum[wid];
  int eD = (int)(excl >> 32), eS = (int)(excl & 0xFFFFFFFFull);
  int r0 = eD, r1 = r0 + d0, r2 = r1 + d1, r3 = r2 + d2;
  rowD[t*4] = r0; rowD[t*4+1] = r1; rowD[t*4+2] = r2; rowD[t*4+3] = r3;
  curD[t*4] = r0; curD[t*4+1] = r1; curD[t*4+2] = r2; curD[t*4+3] = r3;
  int q0 = eS, q1 = q0 + s0, q2 = q1 + s1, q3 = q2 + s2;
  rowS[t*4] = q0; rowS[t*4+1] = q1; rowS[t*4+2] = q2; rowS[t*4+3] = q3;
  curS[t*4] = q0; curS[t*4+1] = q1; curS[t*4+2] = q2; curS[t*4+3] = q3;
  if (t == 1023){ rowD[NN] = r3 + d3; rowS[NN] = q3 + s3; }
}

__global__ void k_scatter(const int* __restrict__ ei, int* curD, int* curS,
                          int* colD, int* dstS, int* mapSD){
  int e = blockIdx.x * blockDim.x + threadIdx.x;
  if (e >= E2) return;
  int u, v;
  if (e < EE){ u = ei[e]; v = ei[EE + e]; } else { u = e - EE; v = u; }
  int p = atomicAdd(&curD[v], 1); colD[p] = u;
  int q = atomicAdd(&curS[u], 1); dstS[q] = v; mapSD[q] = p;
}

// prep: xh = f16(x); WH = f16 weights; wprep; fused zero-init of cnt/out.
__global__ void k_prep(const float* __restrict__ x,
                       const float* __restrict__ W0rel, const float* __restrict__ W0root,
                       const float* __restrict__ W1rel, const float* __restrict__ W1root,
                       const float* __restrict__ Wlin, const float* __restrict__ blin,
                       const float* __restrict__ Watt,
                       __half* __restrict__ xh, __half* __restrict__ WH, float* __restrict__ wA2,
                       int* cntD, int* cntS, float* out){
  int b = blockIdx.x;
  if (b < 2048){
    int i = b*256 + threadIdx.x;
    xh[i] = __float2half(x[i]);
  } else if (b < 2048 + 256){
    int i = (b - 2048)*256 + threadIdx.x;
    int m = i >> 14, o = i & 16383;
    const float* src = (m == 0) ? W0rel : (m == 1) ? W0root : (m == 2) ? W1rel : W1root;
    WH[i] = __float2half(src[o]);
  } else if (b == 2304){
    int c = threadIdx.x;
    if (c < 128){
      float s = 0.f;
      for (int hh = 0; hh < HH; ++hh) s += Watt[hh] * Wlin[hh*HH + c];
      wA2[c] = s;
      if (c == 0){
        float q = 0.f;
        for (int hh = 0; hh < HH; ++hh) q += blin[hh] * Watt[hh];
        wA2[HH] = q;
      }
    }
  } else {
    int i = (b - 2305)*256 + threadIdx.x;
    cntD[i] = 0; cntS[i] = 0;
    if (i < 512) out[i] = 0.f;
  }
}

// mean over in-neighbors, f16 input rows, f16 output (f32 accumulate).
__global__ void k_edge_meanH(const __half* __restrict__ xinh, const int* __restrict__ rowD,
                             const int* __restrict__ colD, __half* __restrict__ meanbh){
  int v = blockIdx.x, t = threadIdx.x;
  int beg = rowD[v], end = rowD[v+1];
  float acc = 0.f;
  int p = beg;
  for (; p + 8 <= end; p += 8){
    int u0 = colD[p],   u1 = colD[p+1], u2 = colD[p+2], u3 = colD[p+3];
    int u4 = colD[p+4], u5 = colD[p+5], u6 = colD[p+6], u7 = colD[p+7];
    float a0 = __half2float(xinh[(size_t)u0*HH + t]);
    float a1 = __half2float(xinh[(size_t)u1*HH + t]);
    float a2 = __half2float(xinh[(size_t)u2*HH + t]);
    float a3 = __half2float(xinh[(size_t)u3*HH + t]);
    float a4 = __half2float(xinh[(size_t)u4*HH + t]);
    float a5 = __half2float(xinh[(size_t)u5*HH + t]);
    float a6 = __half2float(xinh[(size_t)u6*HH + t]);
    float a7 = __half2float(xinh[(size_t)u7*HH + t]);
    if (u0 != v) acc += a0;
    if (u1 != v) acc += a1;
    if (u2 != v) acc += a2;
    if (u3 != v) acc += a3;
    if (u4 != v) acc += a4;
    if (u5 != v) acc += a5;
    if (u6 != v) acc += a6;
    if (u7 != v) acc += a7;
  }
  for (; p < end; ++p){ int u = colD[p]; if (u != v) acc += __half2float(xinh[(size_t)u*HH + t]); }
  float dg = (float)(end - beg - 1);
  meanbh[(size_t)v*HH + t] = __float2half(acc / fmaxf(dg, 1.f));
}

// MFMA GraphConv linear; fused colmean; optional fused xdot.
__global__ void k_linM(const __half* __restrict__ mh, const __half* __restrict__ xinh,
                       const __half* __restrict__ WHh, int woff,
                       const float* __restrict__ brel,
                       float* __restrict__ xout, __half* __restrict__ xouth,
                       float* __restrict__ cmout,
                       const float* __restrict__ WattFull, float* __restrict__ xdotp){
  __shared__ float sx[16][4];
  int t = threadIdx.x, lane = t & 63, w = t >> 6;
  int r0 = blockIdx.x * 16;
  int l15 = lane & 15, lk = (lane >> 4) * 8;
  const _Float16* WH = (const _Float16*)WHh;
  const _Float16* Am = (const _Float16*)mh + (size_t)(r0 + l15)*HH + lk;
  const _Float16* Ax = (const _Float16*)xinh + (size_t)(r0 + l15)*HH + lk;
  const _Float16* Brel0 = WH + woff + (size_t)(w*32 + l15)*HH + lk;
  const _Float16* Brel1 = Brel0 + (size_t)16*HH;
  const _Float16* Broot0 = Brel0 + 16384;
  const _Float16* Broot1 = Brel1 + 16384;
  f32x4 acc0 = (f32x4)0.f, acc1 = (f32x4)0.f;
  #pragma unroll
  for (int kk = 0; kk < HH; kk += 32){
    f16x8 a = *(const f16x8*)(Am + kk);
    f16x8 b0 = *(const f16x8*)(Brel0 + kk);
    f16x8 b1 = *(const f16x8*)(Brel1 + kk);
    acc0 = __builtin_amdgcn_mfma_f32_16x16x32_f16(a, b0, acc0, 0, 0, 0);
    acc1 = __builtin_amdgcn_mfma_f32_16x16x32_f16(a, b1, acc1, 0, 0, 0);
  }
  #pragma unroll
  for (int kk = 0; kk < HH; kk += 32){
    f16x8 a = *(const f16x8*)(Ax + kk);
    f16x8 b0 = *(const f16x8*)(Broot0 + kk);
    f16x8 b1 = *(const f16x8*)(Broot1 + kk);
    acc0 = __builtin_amdgcn_mfma_f32_16x16x32_f16(a, b0, acc0, 0, 0, 0);
    acc1 = __builtin_amdgcn_mfma_f32_16x16x32_f16(a, b1, acc1, 0, 0, 0);
  }
  int rbase = (lane >> 4) * 4;
  int h0 = w*32 + l15, h1 = h0 + 16;
  float bb0 = brel[h0], bb1 = brel[h1];
  float wt0 = 0.f, wt1 = 0.f;
  if (xdotp){ wt0 = WattFull[HH + h0]; wt1 = WattFull[HH + h1]; }
  float cs0 = 0.f, cs1 = 0.f;
  #pragma unroll
  for (int r = 0; r < 4; ++r){
    int row = r0 + rbase + r;
    float v0 = fmaxf(acc0[r] + bb0, 0.f);
    float v1 = fmaxf(acc1[r] + bb1, 0.f);
    xout[(size_t)row*HH + h0] = v0;
    xout[(size_t)row*HH + h1] = v1;
    xouth[(size_t)row*HH + h0] = __float2half(v0);
    xouth[(size_t)row*HH + h1] = __float2half(v1);
    cs0 += v0; cs1 += v1;
    if (xdotp){
      float ds = v0*wt0 + v1*wt1;
      ds += __shfl_xor(ds, 1); ds += __shfl_xor(ds, 2);
      ds += __shfl_xor(ds, 4); ds += __shfl_xor(ds, 8);
      if (l15 == 0) sx[rbase + r][w] = ds;
    }
  }
  cs0 += __shfl_xor(cs0, 16); cs0 += __shfl_xor(cs0, 32);
  cs1 += __shfl_xor(cs1, 16); cs1 += __shfl_xor(cs1, 32);
  if (lane < 16){
    atomicAdd(&cmout[h0], cs0 / (float)NN);
    atomicAdd(&cmout[h1], cs1 / (float)NN);
  }
  if (xdotp){
    __syncthreads();
    if (t < 16) xdotp[r0 + t] = sx[t][0] + sx[t][1] + sx[t][2] + sx[t][3];
  }
}

// dense-conv linear from precomputed mean.
__global__ void k_lin2(const float* __restrict__ meanb, const float* __restrict__ xin,
                       const float* __restrict__ Wrel, const float* __restrict__ brel,
                       const float* __restrict__ Wroot,
                       float* __restrict__ xout, __half* __restrict__ xouth, int rows,
                       float* __restrict__ cmout){
  __shared__ float ms[16][HH];
  __shared__ float xs[16][HH];
  __shared__ float cmred[256];
  int tid = threadIdx.x;
  int r0 = blockIdx.x * 16;
  for (int l = tid; l < 16*HH; l += 256){
    int r = l >> 7, c = l & 127; int gr = r0 + r;
    float mv = 0.f, xv = 0.f;
    if (gr < rows){
      size_t idx = (size_t)gr*HH + c;
      mv = meanb[idx];
      xv = xin[idx];
    }
    ms[r][c] = mv; xs[r][c] = xv;
  }
  __syncthreads();
  int h = tid & 127, hgrp = tid >> 7;
  float acc[8] = {0.f,0.f,0.f,0.f,0.f,0.f,0.f,0.f};
  for (int c = 0; c < HH; ++c){
    float wr = Wrel[h*HH + c], wo = Wroot[h*HH + c];
    #pragma unroll
    for (int r = 0; r < 8; ++r) acc[r] += ms[hgrp*8 + r][c]*wr + xs[hgrp*8 + r][c]*wo;
  }
  float bb = brel[h];
  float csum = 0.f;
  #pragma unroll
  for (int r = 0; r < 8; ++r){
    int gr = r0 + hgrp*8 + r;
    if (gr < rows){
      float val = fmaxf(acc[r] + bb, 0.f);
      if (xout) xout[(size_t)gr*HH + h] = val;
      if (xouth) xouth[(size_t)gr*HH + h] = __float2half(val);
      csum += val;
    }
  }
  cmred[tid] = csum; __syncthreads();
  if (tid < 128) atomicAdd(&cmout[h], (cmred[tid] + cmred[tid + 128]) / (float)rows);
}

// per dst node v: pool stats + x_new + wD + LEConv partials + diag2.
__global__ void k_pool(const __half* __restrict__ x2h, const int* __restrict__ rowD, const int* __restrict__ colD,
                       const float* __restrict__ xdotA, const float* __restrict__ wA2, const float* __restrict__ battp,
                       const float* __restrict__ W1, const float* __restrict__ b1,
                       const float* __restrict__ W2, const float* __restrict__ W3, const float* __restrict__ b3,
                       float* qdotA, float* mA, float* sA, float* __restrict__ xnew, float* __restrict__ wD,
                       float* aA, float* bA, float* cA, float* __restrict__ diag2){
  __shared__ float red[128];
  __shared__ float wmem[128];
  __shared__ int uc[128];
  __shared__ int srcL[1024];
  __shared__ float wL[1024];
  int v = blockIdx.x, t = threadIdx.x;
  int beg = rowD[v], end = rowD[v+1];
  float batt = battp[0];
  float mx = -3.402823466e38f;
  int p = beg;
  for (; p + 4 <= end; p += 4){
    float a0 = __half2float(x2h[(size_t)colD[p]*HH + t]);
    float a1 = __half2float(x2h[(size_t)colD[p+1]*HH + t]);
    float a2 = __half2float(x2h[(size_t)colD[p+2]*HH + t]);
    float a3 = __half2float(x2h[(size_t)colD[p+3]*HH + t]);
    mx = fmaxf(fmaxf(fmaxf(fmaxf(mx, a0), a1), a2), a3);
  }
  for (; p < end; ++p) mx = fmaxf(mx, __half2float(x2h[(size_t)colD[p]*HH + t]));
  float qd = redSum128(red, t, mx * wA2[t]) + wA2[HH];
  float lm = -3.402823466e38f;
  for (p = beg + t; p < end; p += 128) lm = fmaxf(lm, lrelu02(qd + xdotA[colD[p]] + batt));
  float mm = redMax128(red, t, lm);
  float ls = 0.f;
  for (p = beg + t; p < end; p += 128) ls += expf(lrelu02(qd + xdotA[colD[p]] + batt) - mm);
  float ss = redSum128(red, t, ls);
  float acc = 0.f;
  for (int basep = beg; basep < end; basep += 128){
    int cnt = min(128, end - basep);
    if (t < cnt){
      int u = colD[basep + t];
      uc[t] = u;
      float w = expf(lrelu02(qd + xdotA[u] + batt) - mm) / ss;
      wmem[t] = w;
      wD[basep + t] = w;
      int o = basep - beg + t;
      if (o < 1024){ srcL[o] = u; wL[o] = w; }
    }
    __syncthreads();
    int i = 0;
    for (; i + 4 <= cnt; i += 4){
      float a0 = __half2float(x2h[(size_t)uc[i]*HH + t]);
      float a1 = __half2float(x2h[(size_t)uc[i+1]*HH + t]);
      float a2 = __half2float(x2h[(size_t)uc[i+2]*HH + t]);
      float a3 = __half2float(x2h[(size_t)uc[i+3]*HH + t]);
      acc += wmem[i]*a0 + wmem[i+1]*a1 + wmem[i+2]*a2 + wmem[i+3]*a3;
    }
    for (; i < cnt; ++i) acc += wmem[i] * __half2float(x2h[(size_t)uc[i]*HH + t]);
    __syncthreads();
  }
  xnew[(size_t)v*HH + t] = acc;
  float s1 = redSum128(red, t, acc * W1[t]);
  float s2 = redSum128(red, t, acc * W2[t]);
  float s3 = redSum128(red, t, acc * W3[t]);
  int d = end - beg; if (d > 1024) d = 1024;
  float dpart = 0.f;
  for (int pp = t; pp < d; pp += 128){
    int s = srcL[pp];
    float sp = 0.f;
    for (int q = 0; q < d; ++q) if (srcL[q] == s) sp += wL[q];
    dpart += wL[pp] * sp;
  }
  float d2 = redSum128(red, t, dpart);
  if (t == 0){
    qdotA[v] = qd; mA[v] = mm; sA[v] = ss;
    aA[v] = s1 + b1[0]; bA[v] = s2; cA[v] = s3 + b3[0];
    diag2[v] = d2;
  }
}

__global__ void k_fit(const int* __restrict__ rowD, const int* __restrict__ colD,
                      const float* __restrict__ aA, const float* __restrict__ bA, const float* __restrict__ cA,
                      float* __restrict__ fitA){
  __shared__ float red[128];
  int v = blockIdx.x, t = threadIdx.x;
  int beg = rowD[v], end = rowD[v+1];
  float la = 0.f;
  for (int p = beg + t; p < end; p += 128) la += aA[colD[p]];
  float s = redSum128(red, t, la);
  if (t == 0){
    float g = s - (float)(end - beg) * bA[v] + cA[v];
    fitA[v] = 1.f / (1.f + expf(-g));
  }
}

// Exact top-K SET selection via radix-select; wave-shuffle scans (few barriers).
__global__ void k_sel(const float* __restrict__ fitA, int* perm, float* fitk, int* kcol){
  __shared__ unsigned keys[NN];
  __shared__ int hist[256];
  __shared__ int sufA[257];
  __shared__ int wsum[16];
  __shared__ int bc[2];
  int t = threadIdx.x, lane = t & 63, wid = t >> 6;
  #pragma unroll
  for (int r = 0; r < 4; ++r){
    int i = t + r*1024;
    unsigned b = __float_as_uint(fitA[i]);
    keys[i] = (b & 0x80000000u) ? ~b : (b ^ 0x80000000u);
  }
  __syncthreads();
  unsigned prefix = 0;
  int kneed = KC;
  #pragma unroll
  for (int round = 0; round < 4; ++round){
    int shift = 24 - round*8;
    unsigned pmask = (round == 0) ? 0u : (0xFFFFFFFFu << (shift + 8));
    if (t < 256) hist[t] = 0;
    __syncthreads();
    #pragma unroll
    for (int r = 0; r < 4; ++r){
      unsigned kv = keys[t + r*1024];
      if ((kv & pmask) == prefix)
        atomicAdd(&hist[(kv >> shift) & 0xFF], 1);
    }
    __syncthreads();
    // suffix-scan of hist[0..255] via in-wave shfl_down (waves 0..3)
    int x = (t < 256) ? hist[t] : 0;
    #pragma unroll
    for (int offs = 1; offs < 64; offs <<= 1){
      int v = __shfl_down(x, offs);
      if (lane + offs < 64) x += v;
    }
    if (t < 256 && lane == 0) wsum[wid] = x;   // wave totals (wid 0..3)
    if (t == 0) sufA[256] = 0;
    __syncthreads();
    if (t < 256){
      int add = 0;
      #pragma unroll
      for (int w2 = 1; w2 < 4; ++w2) if (wid + w2 < 4) add += wsum[wid + w2];
      sufA[t] = x + add;
    }
    __syncthreads();
    if (t < 256){
      if (sufA[t] >= kneed && sufA[t+1] < kneed){ bc[0] = t; bc[1] = kneed - sufA[t+1]; }
    }
    __syncthreads();
    prefix |= ((unsigned)bc[0]) << shift;
    kneed = bc[1];
    __syncthreads();
  }
  unsigned T = prefix;
  int need_eq = kneed;
  int cnt[4]; int tot = 0;
  #pragma unroll
  for (int r = 0; r < 4; ++r){
    unsigned kv = keys[t*4 + r];
    int g = (kv > T) ? 1 : 0;
    int e = (kv == T) ? 1 : 0;
    cnt[r] = (g << 16) | e;
    tot += cnt[r];
  }
  // 1024-wide inclusive scan via wave shuffles + cross-wave step
  int x2 = tot;
  #pragma unroll
  for (int offs = 1; offs < 64; offs <<= 1){
    int v = __shfl_up(x2, offs);
    if (lane >= offs) x2 += v;
  }
  if (lane == 63) wsum[wid] = x2;
  __syncthreads();
  if (t < 16){
    int y = wsum[t];
    #pragma unroll
    for (int offs = 1; offs < 16; offs <<= 1){
      int v = __shfl_up(y, offs);
      if (t >= offs) y += v;
    }
    wsum[t] = y;
  }
  __syncthreads();
  int waveoff = (wid > 0) ? wsum[wid - 1] : 0;
  int inc = x2 + waveoff;
  int run = inc - tot;
  int gtot = wsum[15] >> 16;
  #pragma unroll
  for (int r = 0; r < 4; ++r){
    int i = t*4 + r;
    int g = cnt[r] >> 16, e = cnt[r] & 0xFFFF;
    int gpos = run >> 16, epos = run & 0xFFFF;
    int pos = -1;
    if (g) pos = gpos;
    else if (e && epos < need_eq) pos = gtot + epos;
    if (pos >= 0){ perm[pos] = i; fitk[pos] = fitA[i]; kcol[i] = pos; }
    else kcol[i] = -1;
    run += cnt[r];
  }
}

// merged: kwS packing (blocks [0,WSB)) + xp/xph build (blocks [WSB, WSB+XPB))
__global__ void k_post(const int* __restrict__ mapSD, const int* __restrict__ dstS,
                       const int* __restrict__ kcol, const float* __restrict__ wD,
                       int2* __restrict__ kwS,
                       const float* __restrict__ xnew, const int* __restrict__ perm,
                       const float* __restrict__ fitk,
                       float* __restrict__ xp, __half* __restrict__ xph){
  int b = blockIdx.x;
  if (b < WSB){
    int q = b*256 + threadIdx.x;
    if (q >= E2) return;
    float w = wD[mapSD[q]];
    int k = kcol[dstS[q]];
    kwS[q] = make_int2(k, __float_as_int(w));
  } else {
    int idx = (b - WSB)*256 + threadIdx.x;
    if (idx >= KC*HH) return;
    int j = idx >> 7;
    float v = xnew[(size_t)perm[j]*HH + (idx & 127)] * fitk[j];
    xp[idx] = v;
    xph[idx] = __float2half(v);
  }
}

// Y1[n,:] = (S @ X)[n,:]; optional UP bitmap emission.
__global__ void k_y1(const int* __restrict__ rowS, const int2* __restrict__ kwS,
                     const __half* __restrict__ Xh, __half* __restrict__ Y1h,
                     unsigned* __restrict__ UP, int emitUP){
  __shared__ int kArr[128];
  __shared__ float wArr[128];
  __shared__ unsigned upw[UPW];
  int n = blockIdx.x, t = threadIdx.x;
  if (emitUP && t < UPW) upw[t] = 0u;
  int beg = rowS[n], end = rowS[n+1];
  float acc = 0.f;
  for (int basep = beg; basep < end; basep += 128){
    int cnt = min(128, end - basep);
    if (t < cnt){
      int2 kw = kwS[basep + t];
      kArr[t] = kw.x;
      wArr[t] = __int_as_float(kw.y);
      if (emitUP && kw.x >= 0) atomicOr(&upw[kw.x >> 5], 1u << (kw.x & 31));
    }
    __syncthreads();
    for (int i = 0; i < cnt; ++i){
      int k = kArr[i];
      if (k >= 0) acc += wArr[i] * __half2float(Xh[(size_t)k*HH + t]);
    }
    __syncthreads();
  }
  Y1h[(size_t)n*HH + t] = __float2half(acc);
  if (emitUP){
    __syncthreads();
    if (t < UPW) UP[(size_t)n*UPW + t] = upw[t];
  }
}

// merged: Y2 (blocks [0,NN)) + PAT build (blocks [NN, NN+patBlocks))
__global__ void k_y2p(const int* __restrict__ rowD, const int* __restrict__ colD,
                      const __half* __restrict__ Y1h, __half* __restrict__ Y2h,
                      const int* __restrict__ perm, const unsigned* __restrict__ UP,
                      unsigned* __restrict__ PAT){
  int b = blockIdx.x, t = threadIdx.x;
  if (b < NN){
    int m = b;
    int beg = rowD[m], end = rowD[m+1];
    float acc = 0.f;
    int p = beg;
    for (; p + 8 <= end; p += 8){
      float a0 = __half2float(Y1h[(size_t)colD[p]*HH + t]);
      float a1 = __half2float(Y1h[(size_t)colD[p+1]*HH + t]);
      float a2 = __half2float(Y1h[(size_t)colD[p+2]*HH + t]);
      float a3 = __half2float(Y1h[(size_t)colD[p+3]*HH + t]);
      float a4 = __half2float(Y1h[(size_t)colD[p+4]*HH + t]);
      float a5 = __half2float(Y1h[(size_t)colD[p+5]*HH + t]);
      float a6 = __half2float(Y1h[(size_t)colD[p+6]*HH + t]);
      float a7 = __half2float(Y1h[(size_t)colD[p+7]*HH + t]);
      acc += ((a0 + a1) + (a2 + a3)) + ((a4 + a5) + (a6 + a7));
    }
    for (; p < end; ++p) acc += __half2float(Y1h[(size_t)colD[p]*HH + t]);
    Y2h[(size_t)m*HH + t] = __float2half(acc);
  } else {
    int k1 = b - NN;
    if (k1 >= KC || t >= UPW) return;
    int v = perm[k1];
    int beg = rowD[v], end = rowD[v+1];
    unsigned pw = 0u;
    for (int p = beg; p < end; ++p) pw |= UP[(size_t)colD[p]*UPW + t];
    PAT[(size_t)k1*UPW + t] = pw;
  }
}

// plain Y2 (conv3)
__global__ void k_y2(const int* __restrict__ rowD, const int* __restrict__ colD,
                     const __half* __restrict__ Y1h, __half* __restrict__ Y2h){
  int m = blockIdx.x, t = threadIdx.x;
  int beg = rowD[m], end = rowD[m+1];
  float acc = 0.f;
  int p = beg;
  for (; p + 8 <= end; p += 8){
    float a0 = __half2float(Y1h[(size_t)colD[p]*HH + t]);
    float a1 = __half2float(Y1h[(size_t)colD[p+1]*HH + t]);
    float a2 = __half2float(Y1h[(size_t)colD[p+2]*HH + t]);
    float a3 = __half2float(Y1h[(size_t)colD[p+3]*HH + t]);
    float a4 = __half2float(Y1h[(size_t)colD[p+4]*HH + t]);
    float a5 = __half2float(Y1h[(size_t)colD[p+5]*HH + t]);
    float a6 = __half2float(Y1h[(size_t)colD[p+6]*HH + t]);
    float a7 = __half2float(Y1h[(size_t)colD[p+7]*HH + t]);
    acc += ((a0 + a1) + (a2 + a3)) + ((a4 + a5) + (a6 + a7));
  }
  for (; p < end; ++p) acc += __half2float(Y1h[(size_t)colD[p]*HH + t]);
  Y2h[(size_t)m*HH + t] = __float2half(acc);
}

// Z + diag correction + deg divide -> meanb
__global__ void k_z(const int* __restrict__ rowD, const int* __restrict__ colD,
                    const float* __restrict__ wD, const int* __restrict__ perm,
                    const __half* __restrict__ Y2h, const float* __restrict__ Xf,
                    const float* __restrict__ diag2, const int* __restrict__ degN,
                    float* __restrict__ meanb){
  __shared__ int uc[128];
  __shared__ float wm[128];
  int k = blockIdx.x, t = threadIdx.x;
  int v = perm[k];
  int beg = rowD[v], end = rowD[v+1];
  float acc = 0.f;
  for (int basep = beg; basep < end; basep += 128){
    int cnt = min(128, end - basep);
    if (t < cnt){ uc[t] = colD[basep + t]; wm[t] = wD[basep + t]; }
    __syncthreads();
    int i = 0;
    for (; i + 4 <= cnt; i += 4){
      float a0 = __half2float(Y2h[(size_t)uc[i]*HH + t]);
      float a1 = __half2float(Y2h[(size_t)uc[i+1]*HH + t]);
      float a2 = __half2float(Y2h[(size_t)uc[i+2]*HH + t]);
      float a3 = __half2float(Y2h[(size_t)uc[i+3]*HH + t]);
      acc += wm[i]*a0 + wm[i+1]*a1 + wm[i+2]*a2 + wm[i+3]*a3;
    }
    for (; i < cnt; ++i) acc += wm[i] * __half2float(Y2h[(size_t)uc[i]*HH + t]);
    __syncthreads();
  }
  float d = fmaxf((float)degN[k], 1.f);
  meanb[(size_t)k*HH + t] = (acc - diag2[v] * Xf[(size_t)k*HH + t]) / d;
}

// degN[i] = (# rows k1 with PAT bit i set) - 1
__global__ void k_degc(const unsigned* __restrict__ PAT, int* __restrict__ degN){
  __shared__ int red[256];
  int w = blockIdx.x, t = threadIdx.x;
  int c[32];
  #pragma unroll
  for (int j = 0; j < 32; ++j) c[j] = 0;
  for (int r = t; r < KC; r += 256){
    unsigned b = PAT[(size_t)r*UPW + w];
    #pragma unroll
    for (int j = 0; j < 32; ++j) c[j] += (b >> j) & 1;
  }
  for (int j = 0; j < 32; ++j){
    red[t] = c[j]; __syncthreads();
    #pragma unroll
    for (int s = 128; s > 0; s >>= 1){ if (t < s) red[t] += red[t + s]; __syncthreads(); }
    if (t == 0) degN[w*32 + j] = red[0] - 1;
    __syncthreads();
  }
}

} // namespace

extern "C" void kernel_launch(void* const* d_in, const int* in_sizes, int n_in,
                              void* d_out, int out_size, void* d_ws, size_t ws_size,
                              hipStream_t stream){
  (void)in_sizes; (void)n_in; (void)out_size; (void)ws_size;
  const float* x      = (const float*)d_in[0];
  const int*   ei     = (const int*)d_in[1];
  const float* c0Wrel = (const float*)d_in[2];
  const float* c0brel = (const float*)d_in[3];
  const float* c0Wroot= (const float*)d_in[4];
  const float* c1Wrel = (const float*)d_in[5];
  const float* c1brel = (const float*)d_in[6];
  const float* c1Wroot= (const float*)d_in[7];
  const float* c2Wrel = (const float*)d_in[8];
  const float* c2brel = (const float*)d_in[9];
  const float* c2Wroot= (const float*)d_in[10];
  const float* c3Wrel = (const float*)d_in[11];
  const float* c3brel = (const float*)d_in[12];
  const float* c3Wroot= (const float*)d_in[13];
  const float* Wlin   = (const float*)d_in[14];
  const float* blin   = (const float*)d_in[15];
  const float* Watt   = (const float*)d_in[16];
  const float* batt   = (const float*)d_in[17];
  const float* W1     = (const float*)d_in[18];
  const float* b1     = (const float*)d_in[19];
  const float* W2     = (const float*)d_in[20];
  const float* W3     = (const float*)d_in[21];
  const float* b3     = (const float*)d_in[22];
  float* out = (float*)d_out;

  char* base = (char*)d_ws;
  size_t off = 0;
  auto carve = [&](size_t bytes) -> void* {
    void* p = base + off;
    off += (bytes + 255) & ~(size_t)255;
    return p;
  };
  float* x1    = (float*)carve((size_t)NN*HH*4);
  float* x2b   = (float*)carve((size_t)NN*HH*4);
  float* xnew  = (float*)carve((size_t)NN*HH*4);
  float* xp    = (float*)carve((size_t)KC*HH*4);
  float* x3    = (float*)carve((size_t)KC*HH*4);
  float* meanb = (float*)carve((size_t)KC*HH*4);
  __half* xh   = (__half*)carve((size_t)NN*HH*2);
  __half* x1h  = (__half*)carve((size_t)NN*HH*2);
  __half* x2bh = (__half*)carve((size_t)NN*HH*2);
  __half* mbh  = (__half*)carve((size_t)NN*HH*2);
  __half* xph  = (__half*)carve((size_t)KC*HH*2);
  __half* x3h  = (__half*)carve((size_t)KC*HH*2);
  __half* Y1h  = (__half*)carve((size_t)NN*HH*2);
  __half* Y2h  = (__half*)carve((size_t)NN*HH*2);
  __half* WH   = (__half*)carve((size_t)4*HH*HH*2);
  unsigned* UP  = (unsigned*)carve((size_t)NN*UPW*4);
  unsigned* PAT = (unsigned*)carve((size_t)KC*UPW*4);
  float* xdot  = (float*)carve(NN*4);
  float* qdot  = (float*)carve(NN*4);
  float* mmaxA = (float*)carve(NN*4);
  float* ssumA = (float*)carve(NN*4);
  float* aA    = (float*)carve(NN*4);
  float* bA    = (float*)carve(NN*4);
  float* cA    = (float*)carve(NN*4);
  float* fitA  = (float*)carve(NN*4);
  float* fitk  = (float*)carve(KC*4);
  float* wA2   = (float*)carve((HH+1)*4);
  float* wD    = (float*)carve((size_t)E2*4);
  float* diag2 = (float*)carve(NN*4);
  int* rowD = (int*)carve((NN+1)*4);
  int* rowS = (int*)carve((NN+1)*4);
  int* cntD = (int*)carve(NN*4);
  int* cntS = (int*)carve(NN*4);
  int* curD = (int*)carve(NN*4);
  int* curS = (int*)carve(NN*4);
  int* colD = (int*)carve((size_t)E2*4);
  int* dstS = (int*)carve((size_t)E2*4);
  int* mapSD= (int*)carve((size_t)E2*4);
  int2* kwS = (int2*)carve((size_t)E2*8);
  int* perm = (int*)carve(KC*4);
  int* kcol = (int*)carve(NN*4);
  int* degN = (int*)carve((size_t)UPW*32*4);

  // prep (includes zero-init of cnt/out)
  k_prep<<<2048 + 256 + 1 + 16, 256, 0, stream>>>(x, c0Wrel, c0Wroot, c1Wrel, c1Wroot,
                                                  Wlin, blin, Watt, xh, WH, wA2,
                                                  cntD, cntS, out);
  k_count<<<(E2+255)/256, 256, 0, stream>>>(ei, cntD, cntS);
  k_scan<<<1, 1024, 0, stream>>>(cntD, cntS, rowD, rowS, curD, curS);
  k_scatter<<<(E2+255)/256, 256, 0, stream>>>(ei, curD, curS, colD, dstS, mapSD);

  // conv0
  k_edge_meanH<<<NN, 128, 0, stream>>>(xh, rowD, colD, mbh);
  k_linM<<<NN/16, 256, 0, stream>>>(mbh, xh, WH, 0, c0brel, x1, x1h, out + 0,
                                    nullptr, nullptr);

  // conv1 (fused xdot)
  k_edge_meanH<<<NN, 128, 0, stream>>>(x1h, rowD, colD, mbh);
  k_linM<<<NN/16, 256, 0, stream>>>(mbh, x1h, WH, 32768, c1brel, x2b, x2bh, out + 128,
                                    Watt, xdot);

  // ASAP pool
  k_pool<<<NN, 128, 0, stream>>>(x2bh, rowD, colD, xdot, wA2, batt,
                                 W1, b1, W2, W3, b3,
                                 qdot, mmaxA, ssumA, xnew, wD, aA, bA, cA, diag2);
  k_fit<<<NN, 128, 0, stream>>>(rowD, colD, aA, bA, cA, fitA);
  k_sel<<<1, 1024, 0, stream>>>(fitA, perm, fitk, kcol);
  k_post<<<WSB + XPB, 256, 0, stream>>>(mapSD, dstS, kcol, wD, kwS,
                                        xnew, perm, fitk, xp, xph);

  // conv2 sparse chain
  k_y1<<<NN, 128, 0, stream>>>(rowS, kwS, xph, Y1h, UP, 1);
  k_y2p<<<NN + KC, 128, 0, stream>>>(rowD, colD, Y1h, Y2h, perm, UP, PAT);
  k_degc<<<UPW, 256, 0, stream>>>(PAT, degN);
  k_z<<<KC, 128, 0, stream>>>(rowD, colD, wD, perm, Y2h, xp, diag2, degN, meanb);
  k_lin2<<<(KC+15)/16, 256, 0, stream>>>(meanb, xp, c2Wrel, c2brel, c2Wroot,
                                         x3, x3h, KC, out + 256);

  // conv3 sparse chain (deg/diag2 reused)
  k_y1<<<NN, 128, 0, stream>>>(rowS, kwS, x3h, Y1h, UP, 0);
  k_y2<<<NN, 128, 0, stream>>>(rowD, colD, Y1h, Y2h);
  k_z<<<KC, 128, 0, stream>>>(rowD, colD, wD, perm, Y2h, x3, diag2, degN, meanb);
  k_lin2<<<(KC+15)/16, 256, 0, stream>>>(meanb, x3, c3Wrel, c3brel, c3Wroot,
                                         nullptr, nullptr, KC, out + 384);
}

// Round 20
// 240.349 us; speedup vs baseline: 1.5531x; 1.1222x over previous
//
#include <hip/hip_runtime.h>
#include <hip/hip_fp16.h>
#include <math.h>

namespace {

constexpr int NN = 4096;
constexpr int EE = 131072;
constexpr int E2 = EE + NN;      // 135168 pool edges (orig + self loops)
constexpr int HH = 128;
constexpr int KC = 3277;         // ceil(0.8*4096)
constexpr int UPW = 104;         // bitmap words per row (104*32 = 3328 >= KC)
constexpr int WSB = (E2 + 255) / 256;      // 528 blocks for wS part of k_post
constexpr int XPB = (KC*HH + 255) / 256;   // 1639 blocks for xpt part

typedef _Float16 f16x8 __attribute__((ext_vector_type(8)));
typedef float f32x4 __attribute__((ext_vector_type(4)));

__device__ __forceinline__ float lrelu02(float x){ return x > 0.f ? x : 0.2f * x; }

__device__ __forceinline__ float redSum128(float* red, int t, float v){
  red[t] = v; __syncthreads();
  #pragma unroll
  for (int s = 64; s > 0; s >>= 1){ if (t < s) red[t] += red[t + s]; __syncthreads(); }
  float r = red[0]; __syncthreads();
  return r;
}
__device__ __forceinline__ float redMax128(float* red, int t, float v){
  red[t] = v; __syncthreads();
  #pragma unroll
  for (int s = 64; s > 0; s >>= 1){ if (t < s) red[t] = fmaxf(red[t], red[t + s]); __syncthreads(); }
  float r = red[0]; __syncthreads();
  return r;
}

__global__ void k_count(const int* __restrict__ ei, int* cntD, int* cntS){
  int e = blockIdx.x * blockDim.x + threadIdx.x;
  if (e >= E2) return;
  int u, v;
  if (e < EE){ u = ei[e]; v = ei[EE + e]; } else { u = e - EE; v = u; }
  atomicAdd(&cntD[v], 1);
  atomicAdd(&cntS[u], 1);
}

// dual CSR scan via packed u64 wave-shuffle scan
__global__ void k_scan(const int* cntD, const int* cntS, int* rowD, int* rowS, int* curD, int* curS){
  __shared__ unsigned long long wsum[16];
  int t = threadIdx.x, lane = t & 63, wid = t >> 6;
  int d0 = cntD[t*4], d1 = cntD[t*4+1], d2 = cntD[t*4+2], d3 = cntD[t*4+3];
  int s0 = cntS[t*4], s1 = cntS[t*4+1], s2 = cntS[t*4+2], s3 = cntS[t*4+3];
  int dT = d0 + d1 + d2 + d3, sT = s0 + s1 + s2 + s3;
  unsigned long long tot = ((unsigned long long)(unsigned)dT << 32) | (unsigned)sT;
  unsigned long long x = tot;
  #pragma unroll
  for (int offs = 1; offs < 64; offs <<= 1){
    unsigned long long v = __shfl_up(x, offs);
    if (lane >= offs) x += v;
  }
  if (lane == 63) wsum[wid] = x;
  __syncthreads();
  if (t == 0){
    unsigned long long acc = 0;
    for (int i = 0; i < 16; ++i){ unsigned long long tmp = wsum[i]; wsum[i] = acc; acc += tmp; }
  }
  __syncthreads();
  unsigned long long excl = x - tot + wsum[wid];
  int eD = (int)(excl >> 32), eS = (int)(excl & 0xFFFFFFFFull);
  int r0 = eD, r1 = r0 + d0, r2 = r1 + d1, r3 = r2 + d2;
  rowD[t*4] = r0; rowD[t*4+1] = r1; rowD[t*4+2] = r2; rowD[t*4+3] = r3;
  curD[t*4] = r0; curD[t*4+1] = r1; curD[t*4+2] = r2; curD[t*4+3] = r3;
  int q0 = eS, q1 = q0 + s0, q2 = q1 + s1, q3 = q2 + s2;
  rowS[t*4] = q0; rowS[t*4+1] = q1; rowS[t*4+2] = q2; rowS[t*4+3] = q3;
  curS[t*4] = q0; curS[t*4+1] = q1; curS[t*4+2] = q2; curS[t*4+3] = q3;
  if (t == 1023){ rowD[NN] = r3 + d3; rowS[NN] = q3 + s3; }
}

__global__ void k_scatter(const int* __restrict__ ei, int* curD, int* curS,
                          int* colD, int* dstS, int* mapSD){
  int e = blockIdx.x * blockDim.x + threadIdx.x;
  if (e >= E2) return;
  int u, v;
  if (e < EE){ u = ei[e]; v = ei[EE + e]; } else { u = e - EE; v = u; }
  int p = atomicAdd(&curD[v], 1); colD[p] = u;
  int q = atomicAdd(&curS[u], 1); dstS[q] = v; mapSD[q] = p;
}

// prep: xh = f16(x); WH = all 8 conv weight matrices f16; wprep; zero-init.
__global__ void k_prep(const float* __restrict__ x,
                       const float* __restrict__ W0rel, const float* __restrict__ W0root,
                       const float* __restrict__ W1rel, const float* __restrict__ W1root,
                       const float* __restrict__ W2rel, const float* __restrict__ W2root,
                       const float* __restrict__ W3rel, const float* __restrict__ W3root,
                       const float* __restrict__ Wlin, const float* __restrict__ blin,
                       const float* __restrict__ Watt,
                       __half* __restrict__ xh, __half* __restrict__ WH, float* __restrict__ wA2,
                       int* cntD, int* cntS, float* out){
  int b = blockIdx.x;
  if (b < 2048){
    int i = b*256 + threadIdx.x;
    xh[i] = __float2half(x[i]);
  } else if (b < 2048 + 512){
    int i = (b - 2048)*256 + threadIdx.x;
    int m = i >> 14, o = i & 16383;
    const float* src;
    switch (m){
      case 0: src = W0rel; break;
      case 1: src = W0root; break;
      case 2: src = W1rel; break;
      case 3: src = W1root; break;
      case 4: src = W2rel; break;
      case 5: src = W2root; break;
      case 6: src = W3rel; break;
      default: src = W3root; break;
    }
    WH[i] = __float2half(src[o]);
  } else if (b == 2560){
    int c = threadIdx.x;
    if (c < 128){
      float s = 0.f;
      for (int hh = 0; hh < HH; ++hh) s += Watt[hh] * Wlin[hh*HH + c];
      wA2[c] = s;
      if (c == 0){
        float q = 0.f;
        for (int hh = 0; hh < HH; ++hh) q += blin[hh] * Watt[hh];
        wA2[HH] = q;
      }
    }
  } else {
    int i = (b - 2561)*256 + threadIdx.x;
    cntD[i] = 0; cntS[i] = 0;
    if (i < 512) out[i] = 0.f;
  }
}

// mean over in-neighbors, f16 rows, f16 out (f32 accumulate).
__global__ void k_edge_meanH(const __half* __restrict__ xinh, const int* __restrict__ rowD,
                             const int* __restrict__ colD, __half* __restrict__ meanbh){
  int v = blockIdx.x, t = threadIdx.x;
  int beg = rowD[v], end = rowD[v+1];
  float acc = 0.f;
  int p = beg;
  for (; p + 8 <= end; p += 8){
    int u0 = colD[p],   u1 = colD[p+1], u2 = colD[p+2], u3 = colD[p+3];
    int u4 = colD[p+4], u5 = colD[p+5], u6 = colD[p+6], u7 = colD[p+7];
    float a0 = __half2float(xinh[(size_t)u0*HH + t]);
    float a1 = __half2float(xinh[(size_t)u1*HH + t]);
    float a2 = __half2float(xinh[(size_t)u2*HH + t]);
    float a3 = __half2float(xinh[(size_t)u3*HH + t]);
    float a4 = __half2float(xinh[(size_t)u4*HH + t]);
    float a5 = __half2float(xinh[(size_t)u5*HH + t]);
    float a6 = __half2float(xinh[(size_t)u6*HH + t]);
    float a7 = __half2float(xinh[(size_t)u7*HH + t]);
    if (u0 != v) acc += a0;
    if (u1 != v) acc += a1;
    if (u2 != v) acc += a2;
    if (u3 != v) acc += a3;
    if (u4 != v) acc += a4;
    if (u5 != v) acc += a5;
    if (u6 != v) acc += a6;
    if (u7 != v) acc += a7;
  }
  for (; p < end; ++p){ int u = colD[p]; if (u != v) acc += __half2float(xinh[(size_t)u*HH + t]); }
  float dg = (float)(end - beg - 1);
  meanbh[(size_t)v*HH + t] = __float2half(acc / fmaxf(dg, 1.f));
}

// MFMA GraphConv linear; row-guarded; nullable outputs; fused colmean + optional xdot.
// NOTE: A-fragment rows may read up to 15 rows past `rows` -> buffers padded +16 rows.
__global__ void k_linM(const __half* __restrict__ mh, const __half* __restrict__ xinh,
                       const __half* __restrict__ WHh, int woff, int rows,
                       const float* __restrict__ brel,
                       float* __restrict__ xout, __half* __restrict__ xouth,
                       float* __restrict__ cmout,
                       const float* __restrict__ WattFull, float* __restrict__ xdotp){
  __shared__ float sx[16][4];
  int t = threadIdx.x, lane = t & 63, w = t >> 6;
  int r0 = blockIdx.x * 16;
  int l15 = lane & 15, lk = (lane >> 4) * 8;
  const _Float16* WH = (const _Float16*)WHh;
  const _Float16* Am = (const _Float16*)mh + (size_t)(r0 + l15)*HH + lk;
  const _Float16* Ax = (const _Float16*)xinh + (size_t)(r0 + l15)*HH + lk;
  const _Float16* Brel0 = WH + woff + (size_t)(w*32 + l15)*HH + lk;
  const _Float16* Brel1 = Brel0 + (size_t)16*HH;
  const _Float16* Broot0 = Brel0 + 16384;
  const _Float16* Broot1 = Brel1 + 16384;
  f32x4 acc0 = (f32x4)0.f, acc1 = (f32x4)0.f;
  #pragma unroll
  for (int kk = 0; kk < HH; kk += 32){
    f16x8 a = *(const f16x8*)(Am + kk);
    f16x8 b0 = *(const f16x8*)(Brel0 + kk);
    f16x8 b1 = *(const f16x8*)(Brel1 + kk);
    acc0 = __builtin_amdgcn_mfma_f32_16x16x32_f16(a, b0, acc0, 0, 0, 0);
    acc1 = __builtin_amdgcn_mfma_f32_16x16x32_f16(a, b1, acc1, 0, 0, 0);
  }
  #pragma unroll
  for (int kk = 0; kk < HH; kk += 32){
    f16x8 a = *(const f16x8*)(Ax + kk);
    f16x8 b0 = *(const f16x8*)(Broot0 + kk);
    f16x8 b1 = *(const f16x8*)(Broot1 + kk);
    acc0 = __builtin_amdgcn_mfma_f32_16x16x32_f16(a, b0, acc0, 0, 0, 0);
    acc1 = __builtin_amdgcn_mfma_f32_16x16x32_f16(a, b1, acc1, 0, 0, 0);
  }
  int rbase = (lane >> 4) * 4;
  int h0 = w*32 + l15, h1 = h0 + 16;
  float bb0 = brel[h0], bb1 = brel[h1];
  float wt0 = 0.f, wt1 = 0.f;
  if (xdotp){ wt0 = WattFull[HH + h0]; wt1 = WattFull[HH + h1]; }
  float cs0 = 0.f, cs1 = 0.f;
  #pragma unroll
  for (int r = 0; r < 4; ++r){
    int row = r0 + rbase + r;
    float v0 = fmaxf(acc0[r] + bb0, 0.f);
    float v1 = fmaxf(acc1[r] + bb1, 0.f);
    if (row < rows){
      if (xout){ xout[(size_t)row*HH + h0] = v0; xout[(size_t)row*HH + h1] = v1; }
      if (xouth){ xouth[(size_t)row*HH + h0] = __float2half(v0); xouth[(size_t)row*HH + h1] = __float2half(v1); }
      cs0 += v0; cs1 += v1;
    }
    if (xdotp){
      float ds = (row < rows) ? (v0*wt0 + v1*wt1) : 0.f;
      ds += __shfl_xor(ds, 1); ds += __shfl_xor(ds, 2);
      ds += __shfl_xor(ds, 4); ds += __shfl_xor(ds, 8);
      if (l15 == 0) sx[rbase + r][w] = ds;
    }
  }
  cs0 += __shfl_xor(cs0, 16); cs0 += __shfl_xor(cs0, 32);
  cs1 += __shfl_xor(cs1, 16); cs1 += __shfl_xor(cs1, 32);
  if (lane < 16){
    atomicAdd(&cmout[h0], cs0 / (float)rows);
    atomicAdd(&cmout[h1], cs1 / (float)rows);
  }
  if (xdotp){
    __syncthreads();
    if (t < 16 && r0 + t < rows) xdotp[r0 + t] = sx[t][0] + sx[t][1] + sx[t][2] + sx[t][3];
  }
}

// per dst node v: pool stats + x_new + wD + LEConv partials + diag2.
__global__ void k_pool(const __half* __restrict__ x2h, const int* __restrict__ rowD, const int* __restrict__ colD,
                       const float* __restrict__ xdotA, const float* __restrict__ wA2, const float* __restrict__ battp,
                       const float* __restrict__ W1, const float* __restrict__ b1,
                       const float* __restrict__ W2, const float* __restrict__ W3, const float* __restrict__ b3,
                       float* qdotA, float* mA, float* sA, float* __restrict__ xnew, float* __restrict__ wD,
                       float* aA, float* bA, float* cA, float* __restrict__ diag2){
  __shared__ float red[128];
  __shared__ float wmem[128];
  __shared__ int uc[128];
  __shared__ int srcL[1024];
  __shared__ float wL[1024];
  int v = blockIdx.x, t = threadIdx.x;
  int beg = rowD[v], end = rowD[v+1];
  float batt = battp[0];
  float mx = -3.402823466e38f;
  int p = beg;
  for (; p + 4 <= end; p += 4){
    float a0 = __half2float(x2h[(size_t)colD[p]*HH + t]);
    float a1 = __half2float(x2h[(size_t)colD[p+1]*HH + t]);
    float a2 = __half2float(x2h[(size_t)colD[p+2]*HH + t]);
    float a3 = __half2float(x2h[(size_t)colD[p+3]*HH + t]);
    mx = fmaxf(fmaxf(fmaxf(fmaxf(mx, a0), a1), a2), a3);
  }
  for (; p < end; ++p) mx = fmaxf(mx, __half2float(x2h[(size_t)colD[p]*HH + t]));
  float qd = redSum128(red, t, mx * wA2[t]) + wA2[HH];
  float lm = -3.402823466e38f;
  for (p = beg + t; p < end; p += 128) lm = fmaxf(lm, lrelu02(qd + xdotA[colD[p]] + batt));
  float mm = redMax128(red, t, lm);
  float ls = 0.f;
  for (p = beg + t; p < end; p += 128) ls += expf(lrelu02(qd + xdotA[colD[p]] + batt) - mm);
  float ss = redSum128(red, t, ls);
  float acc = 0.f;
  for (int basep = beg; basep < end; basep += 128){
    int cnt = min(128, end - basep);
    if (t < cnt){
      int u = colD[basep + t];
      uc[t] = u;
      float w = expf(lrelu02(qd + xdotA[u] + batt) - mm) / ss;
      wmem[t] = w;
      wD[basep + t] = w;
      int o = basep - beg + t;
      if (o < 1024){ srcL[o] = u; wL[o] = w; }
    }
    __syncthreads();
    int i = 0;
    for (; i + 4 <= cnt; i += 4){
      float a0 = __half2float(x2h[(size_t)uc[i]*HH + t]);
      float a1 = __half2float(x2h[(size_t)uc[i+1]*HH + t]);
      float a2 = __half2float(x2h[(size_t)uc[i+2]*HH + t]);
      float a3 = __half2float(x2h[(size_t)uc[i+3]*HH + t]);
      acc += wmem[i]*a0 + wmem[i+1]*a1 + wmem[i+2]*a2 + wmem[i+3]*a3;
    }
    for (; i < cnt; ++i) acc += wmem[i] * __half2float(x2h[(size_t)uc[i]*HH + t]);
    __syncthreads();
  }
  xnew[(size_t)v*HH + t] = acc;
  float s1 = redSum128(red, t, acc * W1[t]);
  float s2 = redSum128(red, t, acc * W2[t]);
  float s3 = redSum128(red, t, acc * W3[t]);
  int d = end - beg; if (d > 1024) d = 1024;
  float dpart = 0.f;
  for (int pp = t; pp < d; pp += 128){
    int s = srcL[pp];
    float sp = 0.f;
    for (int q = 0; q < d; ++q) if (srcL[q] == s) sp += wL[q];
    dpart += wL[pp] * sp;
  }
  float d2 = redSum128(red, t, dpart);
  if (t == 0){
    qdotA[v] = qd; mA[v] = mm; sA[v] = ss;
    aA[v] = s1 + b1[0]; bA[v] = s2; cA[v] = s3 + b3[0];
    diag2[v] = d2;
  }
}

__global__ void k_fit(const int* __restrict__ rowD, const int* __restrict__ colD,
                      const float* __restrict__ aA, const float* __restrict__ bA, const float* __restrict__ cA,
                      float* __restrict__ fitA){
  __shared__ float red[128];
  int v = blockIdx.x, t = threadIdx.x;
  int beg = rowD[v], end = rowD[v+1];
  float la = 0.f;
  for (int p = beg + t; p < end; p += 128) la += aA[colD[p]];
  float s = redSum128(red, t, la);
  if (t == 0){
    float g = s - (float)(end - beg) * bA[v] + cA[v];
    fitA[v] = 1.f / (1.f + expf(-g));
  }
}

// Exact top-K SET selection via radix-select; wave-shuffle scans.
__global__ void k_sel(const float* __restrict__ fitA, int* perm, float* fitk, int* kcol){
  __shared__ unsigned keys[NN];
  __shared__ int hist[256];
  __shared__ int sufA[257];
  __shared__ int wsum[16];
  __shared__ int bc[2];
  int t = threadIdx.x, lane = t & 63, wid = t >> 6;
  #pragma unroll
  for (int r = 0; r < 4; ++r){
    int i = t + r*1024;
    unsigned b = __float_as_uint(fitA[i]);
    keys[i] = (b & 0x80000000u) ? ~b : (b ^ 0x80000000u);
  }
  __syncthreads();
  unsigned prefix = 0;
  int kneed = KC;
  #pragma unroll
  for (int round = 0; round < 4; ++round){
    int shift = 24 - round*8;
    unsigned pmask = (round == 0) ? 0u : (0xFFFFFFFFu << (shift + 8));
    if (t < 256) hist[t] = 0;
    __syncthreads();
    #pragma unroll
    for (int r = 0; r < 4; ++r){
      unsigned kv = keys[t + r*1024];
      if ((kv & pmask) == prefix)
        atomicAdd(&hist[(kv >> shift) & 0xFF], 1);
    }
    __syncthreads();
    int x = (t < 256) ? hist[t] : 0;
    #pragma unroll
    for (int offs = 1; offs < 64; offs <<= 1){
      int v = __shfl_down(x, offs);
      if (lane + offs < 64) x += v;
    }
    if (t < 256 && lane == 0) wsum[wid] = x;
    if (t == 0) sufA[256] = 0;
    __syncthreads();
    if (t < 256){
      int add = 0;
      #pragma unroll
      for (int w2 = 1; w2 < 4; ++w2) if (wid + w2 < 4) add += wsum[wid + w2];
      sufA[t] = x + add;
    }
    __syncthreads();
    if (t < 256){
      if (sufA[t] >= kneed && sufA[t+1] < kneed){ bc[0] = t; bc[1] = kneed - sufA[t+1]; }
    }
    __syncthreads();
    prefix |= ((unsigned)bc[0]) << shift;
    kneed = bc[1];
    __syncthreads();
  }
  unsigned T = prefix;
  int need_eq = kneed;
  int cnt[4]; int tot = 0;
  #pragma unroll
  for (int r = 0; r < 4; ++r){
    unsigned kv = keys[t*4 + r];
    int g = (kv > T) ? 1 : 0;
    int e = (kv == T) ? 1 : 0;
    cnt[r] = (g << 16) | e;
    tot += cnt[r];
  }
  int x2 = tot;
  #pragma unroll
  for (int offs = 1; offs < 64; offs <<= 1){
    int v = __shfl_up(x2, offs);
    if (lane >= offs) x2 += v;
  }
  if (lane == 63) wsum[wid] = x2;
  __syncthreads();
  if (t < 16){
    int y = wsum[t];
    #pragma unroll
    for (int offs = 1; offs < 16; offs <<= 1){
      int v = __shfl_up(y, offs);
      if (t >= offs) y += v;
    }
    wsum[t] = y;
  }
  __syncthreads();
  int waveoff = (wid > 0) ? wsum[wid - 1] : 0;
  int inc = x2 + waveoff;
  int run = inc - tot;
  int gtot = wsum[15] >> 16;
  #pragma unroll
  for (int r = 0; r < 4; ++r){
    int i = t*4 + r;
    int g = cnt[r] >> 16, e = cnt[r] & 0xFFFF;
    int gpos = run >> 16, epos = run & 0xFFFF;
    int pos = -1;
    if (g) pos = gpos;
    else if (e && epos < need_eq) pos = gtot + epos;
    if (pos >= 0){ perm[pos] = i; fitk[pos] = fitA[i]; kcol[i] = pos; }
    else kcol[i] = -1;
    run += cnt[r];
  }
}

// merged: kwS packing + xph build
__global__ void k_post(const int* __restrict__ mapSD, const int* __restrict__ dstS,
                       const int* __restrict__ kcol, const float* __restrict__ wD,
                       int2* __restrict__ kwS,
                       const float* __restrict__ xnew, const int* __restrict__ perm,
                       const float* __restrict__ fitk, __half* __restrict__ xph){
  int b = blockIdx.x;
  if (b < WSB){
    int q = b*256 + threadIdx.x;
    if (q >= E2) return;
    float w = wD[mapSD[q]];
    int k = kcol[dstS[q]];
    kwS[q] = make_int2(k, __float_as_int(w));
  } else {
    int idx = (b - WSB)*256 + threadIdx.x;
    if (idx >= KC*HH) return;
    int j = idx >> 7;
    float v = xnew[(size_t)perm[j]*HH + (idx & 127)] * fitk[j];
    xph[idx] = __float2half(v);
  }
}

// Y1[n,:] = (S @ X)[n,:]; optional UP bitmap emission.
__global__ void k_y1(const int* __restrict__ rowS, const int2* __restrict__ kwS,
                     const __half* __restrict__ Xh, __half* __restrict__ Y1h,
                     unsigned* __restrict__ UP, int emitUP){
  __shared__ int kArr[128];
  __shared__ float wArr[128];
  __shared__ unsigned upw[UPW];
  int n = blockIdx.x, t = threadIdx.x;
  if (emitUP && t < UPW) upw[t] = 0u;
  int beg = rowS[n], end = rowS[n+1];
  float acc = 0.f;
  for (int basep = beg; basep < end; basep += 128){
    int cnt = min(128, end - basep);
    if (t < cnt){
      int2 kw = kwS[basep + t];
      kArr[t] = kw.x;
      wArr[t] = __int_as_float(kw.y);
      if (emitUP && kw.x >= 0) atomicOr(&upw[kw.x >> 5], 1u << (kw.x & 31));
    }
    __syncthreads();
    for (int i = 0; i < cnt; ++i){
      int k = kArr[i];
      if (k >= 0) acc += wArr[i] * __half2float(Xh[(size_t)k*HH + t]);
    }
    __syncthreads();
  }
  Y1h[(size_t)n*HH + t] = __float2half(acc);
  if (emitUP){
    __syncthreads();
    if (t < UPW) UP[(size_t)n*UPW + t] = upw[t];
  }
}

// merged: Y2 + PAT build
__global__ void k_y2p(const int* __restrict__ rowD, const int* __restrict__ colD,
                      const __half* __restrict__ Y1h, __half* __restrict__ Y2h,
                      const int* __restrict__ perm, const unsigned* __restrict__ UP,
                      unsigned* __restrict__ PAT){
  int b = blockIdx.x, t = threadIdx.x;
  if (b < NN){
    int m = b;
    int beg = rowD[m], end = rowD[m+1];
    float acc = 0.f;
    int p = beg;
    for (; p + 8 <= end; p += 8){
      float a0 = __half2float(Y1h[(size_t)colD[p]*HH + t]);
      float a1 = __half2float(Y1h[(size_t)colD[p+1]*HH + t]);
      float a2 = __half2float(Y1h[(size_t)colD[p+2]*HH + t]);
      float a3 = __half2float(Y1h[(size_t)colD[p+3]*HH + t]);
      float a4 = __half2float(Y1h[(size_t)colD[p+4]*HH + t]);
      float a5 = __half2float(Y1h[(size_t)colD[p+5]*HH + t]);
      float a6 = __half2float(Y1h[(size_t)colD[p+6]*HH + t]);
      float a7 = __half2float(Y1h[(size_t)colD[p+7]*HH + t]);
      acc += ((a0 + a1) + (a2 + a3)) + ((a4 + a5) + (a6 + a7));
    }
    for (; p < end; ++p) acc += __half2float(Y1h[(size_t)colD[p]*HH + t]);
    Y2h[(size_t)m*HH + t] = __float2half(acc);
  } else {
    int k1 = b - NN;
    if (k1 >= KC || t >= UPW) return;
    int v = perm[k1];
    int beg = rowD[v], end = rowD[v+1];
    unsigned pw = 0u;
    for (int p = beg; p < end; ++p) pw |= UP[(size_t)colD[p]*UPW + t];
    PAT[(size_t)k1*UPW + t] = pw;
  }
}

// plain Y2 (conv3)
__global__ void k_y2(const int* __restrict__ rowD, const int* __restrict__ colD,
                     const __half* __restrict__ Y1h, __half* __restrict__ Y2h){
  int m = blockIdx.x, t = threadIdx.x;
  int beg = rowD[m], end = rowD[m+1];
  float acc = 0.f;
  int p = beg;
  for (; p + 8 <= end; p += 8){
    float a0 = __half2float(Y1h[(size_t)colD[p]*HH + t]);
    float a1 = __half2float(Y1h[(size_t)colD[p+1]*HH + t]);
    float a2 = __half2float(Y1h[(size_t)colD[p+2]*HH + t]);
    float a3 = __half2float(Y1h[(size_t)colD[p+3]*HH + t]);
    float a4 = __half2float(Y1h[(size_t)colD[p+4]*HH + t]);
    float a5 = __half2float(Y1h[(size_t)colD[p+5]*HH + t]);
    float a6 = __half2float(Y1h[(size_t)colD[p+6]*HH + t]);
    float a7 = __half2float(Y1h[(size_t)colD[p+7]*HH + t]);
    acc += ((a0 + a1) + (a2 + a3)) + ((a4 + a5) + (a6 + a7));
  }
  for (; p < end; ++p) acc += __half2float(Y1h[(size_t)colD[p]*HH + t]);
  Y2h[(size_t)m*HH + t] = __float2half(acc);
}

// Z + diag correction + deg divide -> meanbh (f16); X read as f16.
__global__ void k_z(const int* __restrict__ rowD, const int* __restrict__ colD,
                    const float* __restrict__ wD, const int* __restrict__ perm,
                    const __half* __restrict__ Y2h, const __half* __restrict__ Xh,
                    const float* __restrict__ diag2, const int* __restrict__ degN,
                    __half* __restrict__ meanbh){
  __shared__ int uc[128];
  __shared__ float wm[128];
  int k = blockIdx.x, t = threadIdx.x;
  int v = perm[k];
  int beg = rowD[v], end = rowD[v+1];
  float acc = 0.f;
  for (int basep = beg; basep < end; basep += 128){
    int cnt = min(128, end - basep);
    if (t < cnt){ uc[t] = colD[basep + t]; wm[t] = wD[basep + t]; }
    __syncthreads();
    int i = 0;
    for (; i + 4 <= cnt; i += 4){
      float a0 = __half2float(Y2h[(size_t)uc[i]*HH + t]);
      float a1 = __half2float(Y2h[(size_t)uc[i+1]*HH + t]);
      float a2 = __half2float(Y2h[(size_t)uc[i+2]*HH + t]);
      float a3 = __half2float(Y2h[(size_t)uc[i+3]*HH + t]);
      acc += wm[i]*a0 + wm[i+1]*a1 + wm[i+2]*a2 + wm[i+3]*a3;
    }
    for (; i < cnt; ++i) acc += wm[i] * __half2float(Y2h[(size_t)uc[i]*HH + t]);
    __syncthreads();
  }
  float d = fmaxf((float)degN[k], 1.f);
  float xv = __half2float(Xh[(size_t)k*HH + t]);
  meanbh[(size_t)k*HH + t] = __float2half((acc - diag2[v] * xv) / d);
}

// degN[i] = (# rows k1 with PAT bit i set) - 1
__global__ void k_degc(const unsigned* __restrict__ PAT, int* __restrict__ degN){
  __shared__ int red[256];
  int w = blockIdx.x, t = threadIdx.x;
  int c[32];
  #pragma unroll
  for (int j = 0; j < 32; ++j) c[j] = 0;
  for (int r = t; r < KC; r += 256){
    unsigned b = PAT[(size_t)r*UPW + w];
    #pragma unroll
    for (int j = 0; j < 32; ++j) c[j] += (b >> j) & 1;
  }
  for (int j = 0; j < 32; ++j){
    red[t] = c[j]; __syncthreads();
    #pragma unroll
    for (int s = 128; s > 0; s >>= 1){ if (t < s) red[t] += red[t + s]; __syncthreads(); }
    if (t == 0) degN[w*32 + j] = red[0] - 1;
    __syncthreads();
  }
}

} // namespace

extern "C" void kernel_launch(void* const* d_in, const int* in_sizes, int n_in,
                              void* d_out, int out_size, void* d_ws, size_t ws_size,
                              hipStream_t stream){
  (void)in_sizes; (void)n_in; (void)out_size; (void)ws_size;
  const float* x      = (const float*)d_in[0];
  const int*   ei     = (const int*)d_in[1];
  const float* c0Wrel = (const float*)d_in[2];
  const float* c0brel = (const float*)d_in[3];
  const float* c0Wroot= (const float*)d_in[4];
  const float* c1Wrel = (const float*)d_in[5];
  const float* c1brel = (const float*)d_in[6];
  const float* c1Wroot= (const float*)d_in[7];
  const float* c2Wrel = (const float*)d_in[8];
  const float* c2brel = (const float*)d_in[9];
  const float* c2Wroot= (const float*)d_in[10];
  const float* c3Wrel = (const float*)d_in[11];
  const float* c3brel = (const float*)d_in[12];
  const float* c3Wroot= (const float*)d_in[13];
  const float* Wlin   = (const float*)d_in[14];
  const float* blin   = (const float*)d_in[15];
  const float* Watt   = (const float*)d_in[16];
  const float* batt   = (const float*)d_in[17];
  const float* W1     = (const float*)d_in[18];
  const float* b1     = (const float*)d_in[19];
  const float* W2     = (const float*)d_in[20];
  const float* W3     = (const float*)d_in[21];
  const float* b3     = (const float*)d_in[22];
  float* out = (float*)d_out;

  char* base = (char*)d_ws;
  size_t off = 0;
  auto carve = [&](size_t bytes) -> void* {
    void* p = base + off;
    off += (bytes + 255) & ~(size_t)255;
    return p;
  };
  float* xnew  = (float*)carve((size_t)NN*HH*4);
  __half* xh   = (__half*)carve((size_t)NN*HH*2);
  __half* x1h  = (__half*)carve((size_t)NN*HH*2);
  __half* x2bh = (__half*)carve((size_t)NN*HH*2);
  __half* mbh  = (__half*)carve((size_t)NN*HH*2);        // mean buffer (padded: NN >= KC+16)
  __half* xph  = (__half*)carve((size_t)(KC+16)*HH*2);   // +16 row pad for MFMA A-loads
  __half* x3h  = (__half*)carve((size_t)(KC+16)*HH*2);
  __half* Y1h  = (__half*)carve((size_t)NN*HH*2);
  __half* Y2h  = (__half*)carve((size_t)NN*HH*2);
  __half* WH   = (__half*)carve((size_t)8*HH*HH*2);
  unsigned* UP  = (unsigned*)carve((size_t)NN*UPW*4);
  unsigned* PAT = (unsigned*)carve((size_t)KC*UPW*4);
  float* xdot  = (float*)carve(NN*4);
  float* qdot  = (float*)carve(NN*4);
  float* mmaxA = (float*)carve(NN*4);
  float* ssumA = (float*)carve(NN*4);
  float* aA    = (float*)carve(NN*4);
  float* bA    = (float*)carve(NN*4);
  float* cA    = (float*)carve(NN*4);
  float* fitA  = (float*)carve(NN*4);
  float* fitk  = (float*)carve(KC*4);
  float* wA2   = (float*)carve((HH+1)*4);
  float* wD    = (float*)carve((size_t)E2*4);
  float* diag2 = (float*)carve(NN*4);
  int* rowD = (int*)carve((NN+1)*4);
  int* rowS = (int*)carve((NN+1)*4);
  int* cntD = (int*)carve(NN*4);
  int* cntS = (int*)carve(NN*4);
  int* curD = (int*)carve(NN*4);
  int* curS = (int*)carve(NN*4);
  int* colD = (int*)carve((size_t)E2*4);
  int* dstS = (int*)carve((size_t)E2*4);
  int* mapSD= (int*)carve((size_t)E2*4);
  int2* kwS = (int2*)carve((size_t)E2*8);
  int* perm = (int*)carve(KC*4);
  int* kcol = (int*)carve(NN*4);
  int* degN = (int*)carve((size_t)UPW*32*4);

  // prep (xh, 8 weight matrices, wprep, zero-init)
  k_prep<<<2048 + 512 + 1 + 16, 256, 0, stream>>>(x, c0Wrel, c0Wroot, c1Wrel, c1Wroot,
                                                  c2Wrel, c2Wroot, c3Wrel, c3Wroot,
                                                  Wlin, blin, Watt, xh, WH, wA2,
                                                  cntD, cntS, out);
  k_count<<<(E2+255)/256, 256, 0, stream>>>(ei, cntD, cntS);
  k_scan<<<1, 1024, 0, stream>>>(cntD, cntS, rowD, rowS, curD, curS);
  k_scatter<<<(E2+255)/256, 256, 0, stream>>>(ei, curD, curS, colD, dstS, mapSD);

  // conv0
  k_edge_meanH<<<NN, 128, 0, stream>>>(xh, rowD, colD, mbh);
  k_linM<<<NN/16, 256, 0, stream>>>(mbh, xh, WH, 0, NN, c0brel,
                                    nullptr, x1h, out + 0, nullptr, nullptr);

  // conv1 (fused xdot)
  k_edge_meanH<<<NN, 128, 0, stream>>>(x1h, rowD, colD, mbh);
  k_linM<<<NN/16, 256, 0, stream>>>(mbh, x1h, WH, 32768, NN, c1brel,
                                    nullptr, x2bh, out + 128, Watt, xdot);

  // ASAP pool
  k_pool<<<NN, 128, 0, stream>>>(x2bh, rowD, colD, xdot, wA2, batt,
                                 W1, b1, W2, W3, b3,
                                 qdot, mmaxA, ssumA, xnew, wD, aA, bA, cA, diag2);
  k_fit<<<NN, 128, 0, stream>>>(rowD, colD, aA, bA, cA, fitA);
  k_sel<<<1, 1024, 0, stream>>>(fitA, perm, fitk, kcol);
  k_post<<<WSB + XPB, 256, 0, stream>>>(mapSD, dstS, kcol, wD, kwS,
                                        xnew, perm, fitk, xph);

  // conv2 sparse chain (MFMA linear)
  k_y1<<<NN, 128, 0, stream>>>(rowS, kwS, xph, Y1h, UP, 1);
  k_y2p<<<NN + KC, 128, 0, stream>>>(rowD, colD, Y1h, Y2h, perm, UP, PAT);
  k_degc<<<UPW, 256, 0, stream>>>(PAT, degN);
  k_z<<<KC, 128, 0, stream>>>(rowD, colD, wD, perm, Y2h, xph, diag2, degN, mbh);
  k_linM<<<(KC+15)/16, 256, 0, stream>>>(mbh, xph, WH, 65536, KC, c2brel,
                                         nullptr, x3h, out + 256, nullptr, nullptr);

  // conv3 sparse chain (deg/diag2 reused; MFMA linear)
  k_y1<<<NN, 128, 0, stream>>>(rowS, kwS, x3h, Y1h, UP, 0);
  k_y2<<<NN, 128, 0, stream>>>(rowD, colD, Y1h, Y2h);
  k_z<<<KC, 128, 0, stream>>>(rowD, colD, wD, perm, Y2h, x3h, diag2, degN, mbh);
  k_linM<<<(KC+15)/16, 256, 0, stream>>>(mbh, x3h, WH, 98304, KC, c3brel,
                                         nullptr, nullptr, out + 384, nullptr, nullptr);
}

// Round 21
// 233.362 us; speedup vs baseline: 1.5997x; 1.0299x over previous
//
#include <hip/hip_runtime.h>
#include <hip/hip_fp16.h>
#include <math.h>

namespace {

constexpr int NN = 4096;
constexpr int EE = 131072;
constexpr int E2 = EE + NN;      // 135168 pool edges (orig + self loops)
constexpr int HH = 128;
constexpr int KC = 3277;         // ceil(0.8*4096)
constexpr int UPW = 104;         // bitmap words per row (104*32 = 3328 >= KC)
constexpr int WSB = (E2 + 255) / 256;
constexpr int XPB = (KC*HH + 255) / 256;

typedef _Float16 f16x8 __attribute__((ext_vector_type(8)));
typedef float f32x4 __attribute__((ext_vector_type(4)));

__device__ __forceinline__ float lrelu02(float x){ return x > 0.f ? x : 0.2f * x; }

__device__ __forceinline__ float redSum128(float* red, int t, float v){
  red[t] = v; __syncthreads();
  #pragma unroll
  for (int s = 64; s > 0; s >>= 1){ if (t < s) red[t] += red[t + s]; __syncthreads(); }
  float r = red[0]; __syncthreads();
  return r;
}
__device__ __forceinline__ float redMax128(float* red, int t, float v){
  red[t] = v; __syncthreads();
  #pragma unroll
  for (int s = 64; s > 0; s >>= 1){ if (t < s) red[t] = fmaxf(red[t], red[t + s]); __syncthreads(); }
  float r = red[0]; __syncthreads();
  return r;
}
__device__ __forceinline__ float waveRed64(float v){
  #pragma unroll
  for (int o = 32; o > 0; o >>= 1) v += __shfl_xor(v, o);
  return v;
}

__global__ void k_count(const int* __restrict__ ei, int* cntD, int* cntS){
  int e = blockIdx.x * blockDim.x + threadIdx.x;
  if (e >= E2) return;
  int u, v;
  if (e < EE){ u = ei[e]; v = ei[EE + e]; } else { u = e - EE; v = u; }
  atomicAdd(&cntD[v], 1);
  atomicAdd(&cntS[u], 1);
}

// dual CSR scan via packed u64 wave-shuffle scan
__global__ void k_scan(const int* cntD, const int* cntS, int* rowD, int* rowS, int* curD, int* curS){
  __shared__ unsigned long long wsum[16];
  int t = threadIdx.x, lane = t & 63, wid = t >> 6;
  int d0 = cntD[t*4], d1 = cntD[t*4+1], d2 = cntD[t*4+2], d3 = cntD[t*4+3];
  int s0 = cntS[t*4], s1 = cntS[t*4+1], s2 = cntS[t*4+2], s3 = cntS[t*4+3];
  int dT = d0 + d1 + d2 + d3, sT = s0 + s1 + s2 + s3;
  unsigned long long tot = ((unsigned long long)(unsigned)dT << 32) | (unsigned)sT;
  unsigned long long x = tot;
  #pragma unroll
  for (int offs = 1; offs < 64; offs <<= 1){
    unsigned long long v = __shfl_up(x, offs);
    if (lane >= offs) x += v;
  }
  if (lane == 63) wsum[wid] = x;
  __syncthreads();
  if (t == 0){
    unsigned long long acc = 0;
    for (int i = 0; i < 16; ++i){ unsigned long long tmp = wsum[i]; wsum[i] = acc; acc += tmp; }
  }
  __syncthreads();
  unsigned long long excl = x - tot + wsum[wid];
  int eD = (int)(excl >> 32), eS = (int)(excl & 0xFFFFFFFFull);
  int r0 = eD, r1 = r0 + d0, r2 = r1 + d1, r3 = r2 + d2;
  rowD[t*4] = r0; rowD[t*4+1] = r1; rowD[t*4+2] = r2; rowD[t*4+3] = r3;
  curD[t*4] = r0; curD[t*4+1] = r1; curD[t*4+2] = r2; curD[t*4+3] = r3;
  int q0 = eS, q1 = q0 + s0, q2 = q1 + s1, q3 = q2 + s2;
  rowS[t*4] = q0; rowS[t*4+1] = q1; rowS[t*4+2] = q2; rowS[t*4+3] = q3;
  curS[t*4] = q0; curS[t*4+1] = q1; curS[t*4+2] = q2; curS[t*4+3] = q3;
  if (t == 1023){ rowD[NN] = r3 + d3; rowS[NN] = q3 + s3; }
}

__global__ void k_scatter(const int* __restrict__ ei, int* curD, int* curS,
                          int* colD, int* dstS, int* mapSD){
  int e = blockIdx.x * blockDim.x + threadIdx.x;
  if (e >= E2) return;
  int u, v;
  if (e < EE){ u = ei[e]; v = ei[EE + e]; } else { u = e - EE; v = u; }
  int p = atomicAdd(&curD[v], 1); colD[p] = u;
  int q = atomicAdd(&curS[u], 1); dstS[q] = v; mapSD[q] = p;
}

// prep: xh = f16(x); WH = all 8 conv weight matrices f16; wprep; zero-init.
__global__ void k_prep(const float* __restrict__ x,
                       const float* __restrict__ W0rel, const float* __restrict__ W0root,
                       const float* __restrict__ W1rel, const float* __restrict__ W1root,
                       const float* __restrict__ W2rel, const float* __restrict__ W2root,
                       const float* __restrict__ W3rel, const float* __restrict__ W3root,
                       const float* __restrict__ Wlin, const float* __restrict__ blin,
                       const float* __restrict__ Watt,
                       __half* __restrict__ xh, __half* __restrict__ WH, float* __restrict__ wA2,
                       int* cntD, int* cntS, float* out){
  int b = blockIdx.x;
  if (b < 2048){
    int i = b*256 + threadIdx.x;
    xh[i] = __float2half(x[i]);
  } else if (b < 2048 + 512){
    int i = (b - 2048)*256 + threadIdx.x;
    int m = i >> 14, o = i & 16383;
    const float* src;
    switch (m){
      case 0: src = W0rel; break;
      case 1: src = W0root; break;
      case 2: src = W1rel; break;
      case 3: src = W1root; break;
      case 4: src = W2rel; break;
      case 5: src = W2root; break;
      case 6: src = W3rel; break;
      default: src = W3root; break;
    }
    WH[i] = __float2half(src[o]);
  } else if (b == 2560){
    int c = threadIdx.x;
    if (c < 128){
      float s = 0.f;
      for (int hh = 0; hh < HH; ++hh) s += Watt[hh] * Wlin[hh*HH + c];
      wA2[c] = s;
      if (c == 0){
        float q = 0.f;
        for (int hh = 0; hh < HH; ++hh) q += blin[hh] * Watt[hh];
        wA2[HH] = q;
      }
    }
  } else {
    int i = (b - 2561)*256 + threadIdx.x;
    cntD[i] = 0; cntS[i] = 0;
    if (i < 512) out[i] = 0.f;
  }
}

// mean over in-neighbors; half2 channel-pairs, 2 edge groups (128 thr).
__global__ void k_edge_meanH(const __half* __restrict__ xinh, const int* __restrict__ rowD,
                             const int* __restrict__ colD, __half* __restrict__ meanbh){
  __shared__ float2 s2[128];
  int v = blockIdx.x, t = threadIdx.x;
  int c = t & 63, g = t >> 6;
  const __half2* X2 = (const __half2*)xinh;
  int beg = rowD[v], end = rowD[v+1];
  float2 acc = make_float2(0.f, 0.f);
  int p = beg + g;
  for (; p + 6 < end; p += 8){
    int u0 = colD[p], u1 = colD[p+2], u2 = colD[p+4], u3 = colD[p+6];
    float2 f0 = __half22float2(X2[(size_t)u0*64 + c]);
    float2 f1 = __half22float2(X2[(size_t)u1*64 + c]);
    float2 f2 = __half22float2(X2[(size_t)u2*64 + c]);
    float2 f3 = __half22float2(X2[(size_t)u3*64 + c]);
    if (u0 != v){ acc.x += f0.x; acc.y += f0.y; }
    if (u1 != v){ acc.x += f1.x; acc.y += f1.y; }
    if (u2 != v){ acc.x += f2.x; acc.y += f2.y; }
    if (u3 != v){ acc.x += f3.x; acc.y += f3.y; }
  }
  for (; p < end; p += 2){
    int u = colD[p];
    float2 f = __half22float2(X2[(size_t)u*64 + c]);
    if (u != v){ acc.x += f.x; acc.y += f.y; }
  }
  s2[t] = acc; __syncthreads();
  if (t < 64){
    float dg = fmaxf((float)(end - beg - 1), 1.f);
    float2 tot = make_float2((s2[t].x + s2[t+64].x) / dg, (s2[t].y + s2[t+64].y) / dg);
    ((__half2*)meanbh)[(size_t)v*64 + t] = __floats2half2_rn(tot.x, tot.y);
  }
}

// MFMA GraphConv linear; row-guarded; nullable outputs; fused colmean + optional xdot.
__global__ void k_linM(const __half* __restrict__ mh, const __half* __restrict__ xinh,
                       const __half* __restrict__ WHh, int woff, int rows,
                       const float* __restrict__ brel,
                       float* __restrict__ xout, __half* __restrict__ xouth,
                       float* __restrict__ cmout,
                       const float* __restrict__ WattFull, float* __restrict__ xdotp){
  __shared__ float sx[16][4];
  int t = threadIdx.x, lane = t & 63, w = t >> 6;
  int r0 = blockIdx.x * 16;
  int l15 = lane & 15, lk = (lane >> 4) * 8;
  const _Float16* WH = (const _Float16*)WHh;
  const _Float16* Am = (const _Float16*)mh + (size_t)(r0 + l15)*HH + lk;
  const _Float16* Ax = (const _Float16*)xinh + (size_t)(r0 + l15)*HH + lk;
  const _Float16* Brel0 = WH + woff + (size_t)(w*32 + l15)*HH + lk;
  const _Float16* Brel1 = Brel0 + (size_t)16*HH;
  const _Float16* Broot0 = Brel0 + 16384;
  const _Float16* Broot1 = Brel1 + 16384;
  f32x4 acc0 = (f32x4)0.f, acc1 = (f32x4)0.f;
  #pragma unroll
  for (int kk = 0; kk < HH; kk += 32){
    f16x8 a = *(const f16x8*)(Am + kk);
    f16x8 b0 = *(const f16x8*)(Brel0 + kk);
    f16x8 b1 = *(const f16x8*)(Brel1 + kk);
    acc0 = __builtin_amdgcn_mfma_f32_16x16x32_f16(a, b0, acc0, 0, 0, 0);
    acc1 = __builtin_amdgcn_mfma_f32_16x16x32_f16(a, b1, acc1, 0, 0, 0);
  }
  #pragma unroll
  for (int kk = 0; kk < HH; kk += 32){
    f16x8 a = *(const f16x8*)(Ax + kk);
    f16x8 b0 = *(const f16x8*)(Broot0 + kk);
    f16x8 b1 = *(const f16x8*)(Broot1 + kk);
    acc0 = __builtin_amdgcn_mfma_f32_16x16x32_f16(a, b0, acc0, 0, 0, 0);
    acc1 = __builtin_amdgcn_mfma_f32_16x16x32_f16(a, b1, acc1, 0, 0, 0);
  }
  int rbase = (lane >> 4) * 4;
  int h0 = w*32 + l15, h1 = h0 + 16;
  float bb0 = brel[h0], bb1 = brel[h1];
  float wt0 = 0.f, wt1 = 0.f;
  if (xdotp){ wt0 = WattFull[HH + h0]; wt1 = WattFull[HH + h1]; }
  float cs0 = 0.f, cs1 = 0.f;
  #pragma unroll
  for (int r = 0; r < 4; ++r){
    int row = r0 + rbase + r;
    float v0 = fmaxf(acc0[r] + bb0, 0.f);
    float v1 = fmaxf(acc1[r] + bb1, 0.f);
    if (row < rows){
      if (xout){ xout[(size_t)row*HH + h0] = v0; xout[(size_t)row*HH + h1] = v1; }
      if (xouth){ xouth[(size_t)row*HH + h0] = __float2half(v0); xouth[(size_t)row*HH + h1] = __float2half(v1); }
      cs0 += v0; cs1 += v1;
    }
    if (xdotp){
      float ds = (row < rows) ? (v0*wt0 + v1*wt1) : 0.f;
      ds += __shfl_xor(ds, 1); ds += __shfl_xor(ds, 2);
      ds += __shfl_xor(ds, 4); ds += __shfl_xor(ds, 8);
      if (l15 == 0) sx[rbase + r][w] = ds;
    }
  }
  cs0 += __shfl_xor(cs0, 16); cs0 += __shfl_xor(cs0, 32);
  cs1 += __shfl_xor(cs1, 16); cs1 += __shfl_xor(cs1, 32);
  if (lane < 16){
    atomicAdd(&cmout[h0], cs0 / (float)rows);
    atomicAdd(&cmout[h1], cs1 / (float)rows);
  }
  if (xdotp){
    __syncthreads();
    if (t < 16 && r0 + t < rows) xdotp[r0 + t] = sx[t][0] + sx[t][1] + sx[t][2] + sx[t][3];
  }
}

// per dst node v: pool stats + x_new + wD + LEConv partials + diag2. half2 gathers.
__global__ void k_pool(const __half* __restrict__ x2h, const int* __restrict__ rowD, const int* __restrict__ colD,
                       const float* __restrict__ xdotA, const float* __restrict__ wA2, const float* __restrict__ battp,
                       const float* __restrict__ W1, const float* __restrict__ b1,
                       const float* __restrict__ W2, const float* __restrict__ W3, const float* __restrict__ b3,
                       float* qdotA, float* mA, float* sA, float* __restrict__ xnew, float* __restrict__ wD,
                       float* aA, float* bA, float* cA, float* __restrict__ diag2){
  __shared__ float red[128];
  __shared__ float2 s2[128];
  __shared__ float wmem[128];
  __shared__ int uc[128];
  __shared__ int srcL[1024];
  __shared__ float wL[1024];
  __shared__ float qs[1];
  int v = blockIdx.x, t = threadIdx.x;
  int c = t & 63, g = t >> 6;
  const __half2* X2 = (const __half2*)x2h;
  int beg = rowD[v], end = rowD[v+1];
  float batt = battp[0];
  // max phase (half2, 2 groups)
  float2 mx2 = make_float2(-3.402823466e38f, -3.402823466e38f);
  int p = beg + g;
  for (; p + 6 < end; p += 8){
    float2 f0 = __half22float2(X2[(size_t)colD[p]*64 + c]);
    float2 f1 = __half22float2(X2[(size_t)colD[p+2]*64 + c]);
    float2 f2 = __half22float2(X2[(size_t)colD[p+4]*64 + c]);
    float2 f3 = __half22float2(X2[(size_t)colD[p+6]*64 + c]);
    mx2.x = fmaxf(fmaxf(fmaxf(fmaxf(mx2.x, f0.x), f1.x), f2.x), f3.x);
    mx2.y = fmaxf(fmaxf(fmaxf(fmaxf(mx2.y, f0.y), f1.y), f2.y), f3.y);
  }
  for (; p < end; p += 2){
    float2 f = __half22float2(X2[(size_t)colD[p]*64 + c]);
    mx2.x = fmaxf(mx2.x, f.x);
    mx2.y = fmaxf(mx2.y, f.y);
  }
  s2[t] = mx2; __syncthreads();
  if (t < 64){
    float2 m2 = make_float2(fmaxf(s2[t].x, s2[t+64].x), fmaxf(s2[t].y, s2[t+64].y));
    float part = m2.x * wA2[2*t] + m2.y * wA2[2*t+1];
    part = waveRed64(part);
    if (t == 0) qs[0] = part + wA2[HH];
  }
  __syncthreads();
  float qd = qs[0];
  // edge softmax stats
  float lm = -3.402823466e38f;
  for (p = beg + t; p < end; p += 128) lm = fmaxf(lm, lrelu02(qd + xdotA[colD[p]] + batt));
  float mm = redMax128(red, t, lm);
  float ls = 0.f;
  for (p = beg + t; p < end; p += 128) ls += expf(lrelu02(qd + xdotA[colD[p]] + batt) - mm);
  float ss = redSum128(red, t, ls);
  // weighted sum (half2, 2 groups)
  float2 acc2 = make_float2(0.f, 0.f);
  for (int basep = beg; basep < end; basep += 128){
    int cnt = min(128, end - basep);
    if (t < cnt){
      int u = colD[basep + t];
      uc[t] = u;
      float w = expf(lrelu02(qd + xdotA[u] + batt) - mm) / ss;
      wmem[t] = w;
      wD[basep + t] = w;
      int o = basep - beg + t;
      if (o < 1024){ srcL[o] = u; wL[o] = w; }
    }
    __syncthreads();
    int i = g;
    for (; i + 6 < cnt; i += 8){
      float2 f0 = __half22float2(X2[(size_t)uc[i]*64 + c]);
      float2 f1 = __half22float2(X2[(size_t)uc[i+2]*64 + c]);
      float2 f2 = __half22float2(X2[(size_t)uc[i+4]*64 + c]);
      float2 f3 = __half22float2(X2[(size_t)uc[i+6]*64 + c]);
      acc2.x += wmem[i]*f0.x + wmem[i+2]*f1.x + wmem[i+4]*f2.x + wmem[i+6]*f3.x;
      acc2.y += wmem[i]*f0.y + wmem[i+2]*f1.y + wmem[i+4]*f2.y + wmem[i+6]*f3.y;
    }
    for (; i < cnt; i += 2){
      float2 f = __half22float2(X2[(size_t)uc[i]*64 + c]);
      acc2.x += wmem[i]*f.x;
      acc2.y += wmem[i]*f.y;
    }
    __syncthreads();
  }
  s2[t] = acc2; __syncthreads();
  float s1 = 0.f, sB = 0.f, sC = 0.f;
  if (t < 64){
    float2 tot = make_float2(s2[t].x + s2[t+64].x, s2[t].y + s2[t+64].y);
    *(float2*)(xnew + (size_t)v*HH + 2*t) = tot;
    float p1 = tot.x*W1[2*t] + tot.y*W1[2*t+1];
    float p2 = tot.x*W2[2*t] + tot.y*W2[2*t+1];
    float p3 = tot.x*W3[2*t] + tot.y*W3[2*t+1];
    s1 = waveRed64(p1);
    sB = waveRed64(p2);
    sC = waveRed64(p3);
  }
  // diag2: sum over same-source pairs of in-edge weights
  int d = end - beg; if (d > 1024) d = 1024;
  float dpart = 0.f;
  for (int pp = t; pp < d; pp += 128){
    int s = srcL[pp];
    float sp = 0.f;
    for (int q = 0; q < d; ++q) if (srcL[q] == s) sp += wL[q];
    dpart += wL[pp] * sp;
  }
  float d2 = redSum128(red, t, dpart);
  if (t == 0){
    qdotA[v] = qd; mA[v] = mm; sA[v] = ss;
    aA[v] = s1 + b1[0]; bA[v] = sB; cA[v] = sC + b3[0];
    diag2[v] = d2;
  }
}

__global__ void k_fit(const int* __restrict__ rowD, const int* __restrict__ colD,
                      const float* __restrict__ aA, const float* __restrict__ bA, const float* __restrict__ cA,
                      float* __restrict__ fitA){
  __shared__ float red[128];
  int v = blockIdx.x, t = threadIdx.x;
  int beg = rowD[v], end = rowD[v+1];
  float la = 0.f;
  for (int p = beg + t; p < end; p += 128) la += aA[colD[p]];
  float s = redSum128(red, t, la);
  if (t == 0){
    float g = s - (float)(end - beg) * bA[v] + cA[v];
    fitA[v] = 1.f / (1.f + expf(-g));
  }
}

// Exact top-K SET selection via radix-select; wave-shuffle scans.
__global__ void k_sel(const float* __restrict__ fitA, int* perm, float* fitk, int* kcol){
  __shared__ unsigned keys[NN];
  __shared__ int hist[256];
  __shared__ int sufA[257];
  __shared__ int wsum[16];
  __shared__ int bc[2];
  int t = threadIdx.x, lane = t & 63, wid = t >> 6;
  #pragma unroll
  for (int r = 0; r < 4; ++r){
    int i = t + r*1024;
    unsigned b = __float_as_uint(fitA[i]);
    keys[i] = (b & 0x80000000u) ? ~b : (b ^ 0x80000000u);
  }
  __syncthreads();
  unsigned prefix = 0;
  int kneed = KC;
  #pragma unroll
  for (int round = 0; round < 4; ++round){
    int shift = 24 - round*8;
    unsigned pmask = (round == 0) ? 0u : (0xFFFFFFFFu << (shift + 8));
    if (t < 256) hist[t] = 0;
    __syncthreads();
    #pragma unroll
    for (int r = 0; r < 4; ++r){
      unsigned kv = keys[t + r*1024];
      if ((kv & pmask) == prefix)
        atomicAdd(&hist[(kv >> shift) & 0xFF], 1);
    }
    __syncthreads();
    int x = (t < 256) ? hist[t] : 0;
    #pragma unroll
    for (int offs = 1; offs < 64; offs <<= 1){
      int v = __shfl_down(x, offs);
      if (lane + offs < 64) x += v;
    }
    if (t < 256 && lane == 0) wsum[wid] = x;
    if (t == 0) sufA[256] = 0;
    __syncthreads();
    if (t < 256){
      int add = 0;
      #pragma unroll
      for (int w2 = 1; w2 < 4; ++w2) if (wid + w2 < 4) add += wsum[wid + w2];
      sufA[t] = x + add;
    }
    __syncthreads();
    if (t < 256){
      if (sufA[t] >= kneed && sufA[t+1] < kneed){ bc[0] = t; bc[1] = kneed - sufA[t+1]; }
    }
    __syncthreads();
    prefix |= ((unsigned)bc[0]) << shift;
    kneed = bc[1];
    __syncthreads();
  }
  unsigned T = prefix;
  int need_eq = kneed;
  int cnt[4]; int tot = 0;
  #pragma unroll
  for (int r = 0; r < 4; ++r){
    unsigned kv = keys[t*4 + r];
    int g = (kv > T) ? 1 : 0;
    int e = (kv == T) ? 1 : 0;
    cnt[r] = (g << 16) | e;
    tot += cnt[r];
  }
  int x2 = tot;
  #pragma unroll
  for (int offs = 1; offs < 64; offs <<= 1){
    int v = __shfl_up(x2, offs);
    if (lane >= offs) x2 += v;
  }
  if (lane == 63) wsum[wid] = x2;
  __syncthreads();
  if (t < 16){
    int y = wsum[t];
    #pragma unroll
    for (int offs = 1; offs < 16; offs <<= 1){
      int v = __shfl_up(y, offs);
      if (t >= offs) y += v;
    }
    wsum[t] = y;
  }
  __syncthreads();
  int waveoff = (wid > 0) ? wsum[wid - 1] : 0;
  int inc = x2 + waveoff;
  int run = inc - tot;
  int gtot = wsum[15] >> 16;
  #pragma unroll
  for (int r = 0; r < 4; ++r){
    int i = t*4 + r;
    int g = cnt[r] >> 16, e = cnt[r] & 0xFFFF;
    int gpos = run >> 16, epos = run & 0xFFFF;
    int pos = -1;
    if (g) pos = gpos;
    else if (e && epos < need_eq) pos = gtot + epos;
    if (pos >= 0){ perm[pos] = i; fitk[pos] = fitA[i]; kcol[i] = pos; }
    else kcol[i] = -1;
    run += cnt[r];
  }
}

// merged: kwS packing + xph build
__global__ void k_post(const int* __restrict__ mapSD, const int* __restrict__ dstS,
                       const int* __restrict__ kcol, const float* __restrict__ wD,
                       int2* __restrict__ kwS,
                       const float* __restrict__ xnew, const int* __restrict__ perm,
                       const float* __restrict__ fitk, __half* __restrict__ xph){
  int b = blockIdx.x;
  if (b < WSB){
    int q = b*256 + threadIdx.x;
    if (q >= E2) return;
    float w = wD[mapSD[q]];
    int k = kcol[dstS[q]];
    kwS[q] = make_int2(k, __float_as_int(w));
  } else {
    int idx = (b - WSB)*256 + threadIdx.x;
    if (idx >= KC*HH) return;
    int j = idx >> 7;
    float v = xnew[(size_t)perm[j]*HH + (idx & 127)] * fitk[j];
    xph[idx] = __float2half(v);
  }
}

// Y1[n,:] = (S @ X)[n,:]; half2 gathers; optional UP bitmap emission.
__global__ void k_y1(const int* __restrict__ rowS, const int2* __restrict__ kwS,
                     const __half* __restrict__ Xh, __half* __restrict__ Y1h,
                     unsigned* __restrict__ UP, int emitUP){
  __shared__ int kArr[128];
  __shared__ float wArr[128];
  __shared__ float2 s2[128];
  __shared__ unsigned upw[UPW];
  int n = blockIdx.x, t = threadIdx.x;
  int c = t & 63, g = t >> 6;
  const __half2* X2 = (const __half2*)Xh;
  if (emitUP && t < UPW) upw[t] = 0u;
  int beg = rowS[n], end = rowS[n+1];
  float2 acc = make_float2(0.f, 0.f);
  for (int basep = beg; basep < end; basep += 128){
    int cnt = min(128, end - basep);
    if (t < cnt){
      int2 kw = kwS[basep + t];
      kArr[t] = kw.x;
      wArr[t] = __int_as_float(kw.y);
      if (emitUP && kw.x >= 0) atomicOr(&upw[kw.x >> 5], 1u << (kw.x & 31));
    }
    __syncthreads();
    for (int i = g; i < cnt; i += 2){
      int k = kArr[i];
      if (k >= 0){
        float2 f = __half22float2(X2[(size_t)k*64 + c]);
        acc.x += wArr[i]*f.x;
        acc.y += wArr[i]*f.y;
      }
    }
    __syncthreads();
  }
  s2[t] = acc; __syncthreads();
  if (t < 64){
    float2 tot = make_float2(s2[t].x + s2[t+64].x, s2[t].y + s2[t+64].y);
    ((__half2*)Y1h)[(size_t)n*64 + t] = __floats2half2_rn(tot.x, tot.y);
  }
  if (emitUP){
    __syncthreads();
    if (t < UPW) UP[(size_t)n*UPW + t] = upw[t];
  }
}

// merged: Y2 (half2) + PAT build
__global__ void k_y2p(const int* __restrict__ rowD, const int* __restrict__ colD,
                      const __half* __restrict__ Y1h, __half* __restrict__ Y2h,
                      const int* __restrict__ perm, const unsigned* __restrict__ UP,
                      unsigned* __restrict__ PAT){
  __shared__ float2 s2[128];
  int b = blockIdx.x, t = threadIdx.x;
  if (b < NN){
    int m = b;
    int c = t & 63, g = t >> 6;
    const __half2* Y12 = (const __half2*)Y1h;
    int beg = rowD[m], end = rowD[m+1];
    float2 acc = make_float2(0.f, 0.f);
    int p = beg + g;
    for (; p + 6 < end; p += 8){
      float2 f0 = __half22float2(Y12[(size_t)colD[p]*64 + c]);
      float2 f1 = __half22float2(Y12[(size_t)colD[p+2]*64 + c]);
      float2 f2 = __half22float2(Y12[(size_t)colD[p+4]*64 + c]);
      float2 f3 = __half22float2(Y12[(size_t)colD[p+6]*64 + c]);
      acc.x += (f0.x + f1.x) + (f2.x + f3.x);
      acc.y += (f0.y + f1.y) + (f2.y + f3.y);
    }
    for (; p < end; p += 2){
      float2 f = __half22float2(Y12[(size_t)colD[p]*64 + c]);
      acc.x += f.x; acc.y += f.y;
    }
    s2[t] = acc; __syncthreads();
    if (t < 64){
      float2 tot = make_float2(s2[t].x + s2[t+64].x, s2[t].y + s2[t+64].y);
      ((__half2*)Y2h)[(size_t)m*64 + t] = __floats2half2_rn(tot.x, tot.y);
    }
  } else {
    int k1 = b - NN;
    if (k1 >= KC || t >= UPW) return;
    int v = perm[k1];
    int beg = rowD[v], end = rowD[v+1];
    unsigned pw = 0u;
    for (int p = beg; p < end; ++p) pw |= UP[(size_t)colD[p]*UPW + t];
    PAT[(size_t)k1*UPW + t] = pw;
  }
}

// plain Y2 (conv3), half2
__global__ void k_y2(const int* __restrict__ rowD, const int* __restrict__ colD,
                     const __half* __restrict__ Y1h, __half* __restrict__ Y2h){
  __shared__ float2 s2[128];
  int m = blockIdx.x, t = threadIdx.x;
  int c = t & 63, g = t >> 6;
  const __half2* Y12 = (const __half2*)Y1h;
  int beg = rowD[m], end = rowD[m+1];
  float2 acc = make_float2(0.f, 0.f);
  int p = beg + g;
  for (; p + 6 < end; p += 8){
    float2 f0 = __half22float2(Y12[(size_t)colD[p]*64 + c]);
    float2 f1 = __half22float2(Y12[(size_t)colD[p+2]*64 + c]);
    float2 f2 = __half22float2(Y12[(size_t)colD[p+4]*64 + c]);
    float2 f3 = __half22float2(Y12[(size_t)colD[p+6]*64 + c]);
    acc.x += (f0.x + f1.x) + (f2.x + f3.x);
    acc.y += (f0.y + f1.y) + (f2.y + f3.y);
  }
  for (; p < end; p += 2){
    float2 f = __half22float2(Y12[(size_t)colD[p]*64 + c]);
    acc.x += f.x; acc.y += f.y;
  }
  s2[t] = acc; __syncthreads();
  if (t < 64){
    float2 tot = make_float2(s2[t].x + s2[t+64].x, s2[t].y + s2[t+64].y);
    ((__half2*)Y2h)[(size_t)m*64 + t] = __floats2half2_rn(tot.x, tot.y);
  }
}

// Z + diag correction + deg divide -> meanbh (f16); half2 gathers.
__global__ void k_z(const int* __restrict__ rowD, const int* __restrict__ colD,
                    const float* __restrict__ wD, const int* __restrict__ perm,
                    const __half* __restrict__ Y2h, const __half* __restrict__ Xh,
                    const float* __restrict__ diag2, const int* __restrict__ degN,
                    __half* __restrict__ meanbh){
  __shared__ int uc[128];
  __shared__ float wm[128];
  __shared__ float2 s2[128];
  int k = blockIdx.x, t = threadIdx.x;
  int c = t & 63, g = t >> 6;
  const __half2* Y22 = (const __half2*)Y2h;
  int v = perm[k];
  int beg = rowD[v], end = rowD[v+1];
  float2 acc = make_float2(0.f, 0.f);
  for (int basep = beg; basep < end; basep += 128){
    int cnt = min(128, end - basep);
    if (t < cnt){ uc[t] = colD[basep + t]; wm[t] = wD[basep + t]; }
    __syncthreads();
    int i = g;
    for (; i + 6 < cnt; i += 8){
      float2 f0 = __half22float2(Y22[(size_t)uc[i]*64 + c]);
      float2 f1 = __half22float2(Y22[(size_t)uc[i+2]*64 + c]);
      float2 f2 = __half22float2(Y22[(size_t)uc[i+4]*64 + c]);
      float2 f3 = __half22float2(Y22[(size_t)uc[i+6]*64 + c]);
      acc.x += wm[i]*f0.x + wm[i+2]*f1.x + wm[i+4]*f2.x + wm[i+6]*f3.x;
      acc.y += wm[i]*f0.y + wm[i+2]*f1.y + wm[i+4]*f2.y + wm[i+6]*f3.y;
    }
    for (; i < cnt; i += 2){
      float2 f = __half22float2(Y22[(size_t)uc[i]*64 + c]);
      acc.x += wm[i]*f.x;
      acc.y += wm[i]*f.y;
    }
    __syncthreads();
  }
  s2[t] = acc; __syncthreads();
  if (t < 64){
    float d = fmaxf((float)degN[k], 1.f);
    float dg = diag2[v];
    float2 xv = __half22float2(((const __half2*)Xh)[(size_t)k*64 + t]);
    float2 tot = make_float2((s2[t].x + s2[t+64].x - dg*xv.x) / d,
                             (s2[t].y + s2[t+64].y - dg*xv.y) / d);
    ((__half2*)meanbh)[(size_t)k*64 + t] = __floats2half2_rn(tot.x, tot.y);
  }
}

// degN[i] = (# rows k1 with PAT bit i set) - 1
__global__ void k_degc(const unsigned* __restrict__ PAT, int* __restrict__ degN){
  __shared__ int red[256];
  int w = blockIdx.x, t = threadIdx.x;
  int c[32];
  #pragma unroll
  for (int j = 0; j < 32; ++j) c[j] = 0;
  for (int r = t; r < KC; r += 256){
    unsigned b = PAT[(size_t)r*UPW + w];
    #pragma unroll
    for (int j = 0; j < 32; ++j) c[j] += (b >> j) & 1;
  }
  for (int j = 0; j < 32; ++j){
    red[t] = c[j]; __syncthreads();
    #pragma unroll
    for (int s = 128; s > 0; s >>= 1){ if (t < s) red[t] += red[t + s]; __syncthreads(); }
    if (t == 0) degN[w*32 + j] = red[0] - 1;
    __syncthreads();
  }
}

} // namespace

extern "C" void kernel_launch(void* const* d_in, const int* in_sizes, int n_in,
                              void* d_out, int out_size, void* d_ws, size_t ws_size,
                              hipStream_t stream){
  (void)in_sizes; (void)n_in; (void)out_size; (void)ws_size;
  const float* x      = (const float*)d_in[0];
  const int*   ei     = (const int*)d_in[1];
  const float* c0Wrel = (const float*)d_in[2];
  const float* c0brel = (const float*)d_in[3];
  const float* c0Wroot= (const float*)d_in[4];
  const float* c1Wrel = (const float*)d_in[5];
  const float* c1brel = (const float*)d_in[6];
  const float* c1Wroot= (const float*)d_in[7];
  const float* c2Wrel = (const float*)d_in[8];
  const float* c2brel = (const float*)d_in[9];
  const float* c2Wroot= (const float*)d_in[10];
  const float* c3Wrel = (const float*)d_in[11];
  const float* c3brel = (const float*)d_in[12];
  const float* c3Wroot= (const float*)d_in[13];
  const float* Wlin   = (const float*)d_in[14];
  const float* blin   = (const float*)d_in[15];
  const float* Watt   = (const float*)d_in[16];
  const float* batt   = (const float*)d_in[17];
  const float* W1     = (const float*)d_in[18];
  const float* b1     = (const float*)d_in[19];
  const float* W2     = (const float*)d_in[20];
  const float* W3     = (const float*)d_in[21];
  const float* b3     = (const float*)d_in[22];
  float* out = (float*)d_out;

  char* base = (char*)d_ws;
  size_t off = 0;
  auto carve = [&](size_t bytes) -> void* {
    void* p = base + off;
    off += (bytes + 255) & ~(size_t)255;
    return p;
  };
  float* xnew  = (float*)carve((size_t)NN*HH*4);
  __half* xh   = (__half*)carve((size_t)NN*HH*2);
  __half* x1h  = (__half*)carve((size_t)NN*HH*2);
  __half* x2bh = (__half*)carve((size_t)NN*HH*2);
  __half* mbh  = (__half*)carve((size_t)NN*HH*2);
  __half* xph  = (__half*)carve((size_t)(KC+16)*HH*2);
  __half* x3h  = (__half*)carve((size_t)(KC+16)*HH*2);
  __half* Y1h  = (__half*)carve((size_t)NN*HH*2);
  __half* Y2h  = (__half*)carve((size_t)NN*HH*2);
  __half* WH   = (__half*)carve((size_t)8*HH*HH*2);
  unsigned* UP  = (unsigned*)carve((size_t)NN*UPW*4);
  unsigned* PAT = (unsigned*)carve((size_t)KC*UPW*4);
  float* xdot  = (float*)carve(NN*4);
  float* qdot  = (float*)carve(NN*4);
  float* mmaxA = (float*)carve(NN*4);
  float* ssumA = (float*)carve(NN*4);
  float* aA    = (float*)carve(NN*4);
  float* bA    = (float*)carve(NN*4);
  float* cA    = (float*)carve(NN*4);
  float* fitA  = (float*)carve(NN*4);
  float* fitk  = (float*)carve(KC*4);
  float* wA2   = (float*)carve((HH+1)*4);
  float* wD    = (float*)carve((size_t)E2*4);
  float* diag2 = (float*)carve(NN*4);
  int* rowD = (int*)carve((NN+1)*4);
  int* rowS = (int*)carve((NN+1)*4);
  int* cntD = (int*)carve(NN*4);
  int* cntS = (int*)carve(NN*4);
  int* curD = (int*)carve(NN*4);
  int* curS = (int*)carve(NN*4);
  int* colD = (int*)carve((size_t)E2*4);
  int* dstS = (int*)carve((size_t)E2*4);
  int* mapSD= (int*)carve((size_t)E2*4);
  int2* kwS = (int2*)carve((size_t)E2*8);
  int* perm = (int*)carve(KC*4);
  int* kcol = (int*)carve(NN*4);
  int* degN = (int*)carve((size_t)UPW*32*4);

  // prep (xh, 8 weight matrices, wprep, zero-init)
  k_prep<<<2048 + 512 + 1 + 16, 256, 0, stream>>>(x, c0Wrel, c0Wroot, c1Wrel, c1Wroot,
                                                  c2Wrel, c2Wroot, c3Wrel, c3Wroot,
                                                  Wlin, blin, Watt, xh, WH, wA2,
                                                  cntD, cntS, out);
  k_count<<<(E2+255)/256, 256, 0, stream>>>(ei, cntD, cntS);
  k_scan<<<1, 1024, 0, stream>>>(cntD, cntS, rowD, rowS, curD, curS);
  k_scatter<<<(E2+255)/256, 256, 0, stream>>>(ei, curD, curS, colD, dstS, mapSD);

  // conv0
  k_edge_meanH<<<NN, 128, 0, stream>>>(xh, rowD, colD, mbh);
  k_linM<<<NN/16, 256, 0, stream>>>(mbh, xh, WH, 0, NN, c0brel,
                                    nullptr, x1h, out + 0, nullptr, nullptr);

  // conv1 (fused xdot)
  k_edge_meanH<<<NN, 128, 0, stream>>>(x1h, rowD, colD, mbh);
  k_linM<<<NN/16, 256, 0, stream>>>(mbh, x1h, WH, 32768, NN, c1brel,
                                    nullptr, x2bh, out + 128, Watt, xdot);

  // ASAP pool
  k_pool<<<NN, 128, 0, stream>>>(x2bh, rowD, colD, xdot, wA2, batt,
                                 W1, b1, W2, W3, b3,
                                 qdot, mmaxA, ssumA, xnew, wD, aA, bA, cA, diag2);
  k_fit<<<NN, 128, 0, stream>>>(rowD, colD, aA, bA, cA, fitA);
  k_sel<<<1, 1024, 0, stream>>>(fitA, perm, fitk, kcol);
  k_post<<<WSB + XPB, 256, 0, stream>>>(mapSD, dstS, kcol, wD, kwS,
                                        xnew, perm, fitk, xph);

  // conv2 sparse chain (MFMA linear)
  k_y1<<<NN, 128, 0, stream>>>(rowS, kwS, xph, Y1h, UP, 1);
  k_y2p<<<NN + KC, 128, 0, stream>>>(rowD, colD, Y1h, Y2h, perm, UP, PAT);
  k_degc<<<UPW, 256, 0, stream>>>(PAT, degN);
  k_z<<<KC, 128, 0, stream>>>(rowD, colD, wD, perm, Y2h, xph, diag2, degN, mbh);
  k_linM<<<(KC+15)/16, 256, 0, stream>>>(mbh, xph, WH, 65536, KC, c2brel,
                                         nullptr, x3h, out + 256, nullptr, nullptr);

  // conv3 sparse chain (deg/diag2 reused; MFMA linear)
  k_y1<<<NN, 128, 0, stream>>>(rowS, kwS, x3h, Y1h, UP, 0);
  k_y2<<<NN, 128, 0, stream>>>(rowD, colD, Y1h, Y2h);
  k_z<<<KC, 128, 0, stream>>>(rowD, colD, wD, perm, Y2h, x3h, diag2, degN, mbh);
  k_linM<<<(KC+15)/16, 256, 0, stream>>>(mbh, x3h, WH, 98304, KC, c3brel,
                                         nullptr, nullptr, out + 384, nullptr, nullptr);
}